// Round 6
// baseline (844.309 us; speedup 1.0000x reference)
//
#include <hip/hip_runtime.h>

#define N_NODES 100000
#define G_NODES 50000
#define N_EDGES 800000
#define H 64
#define F_IN 32
#define MAX_DEG 20
#define NUM_GRAPHS 128
#define LN_EPS 1e-5f
#define POOL_BLOCKS 256

// Binned CSR build parameters: 512 bins over the 4*N key space.
#define NBINS 512
#define BPB 782            // keys per bin: 782*512 = 400384 >= 400000
#define CHUNK 6250         // edges per build block: 6250*512 = 3.2M
#define MKEYS (4 * N_NODES)
#define MEDGES (4 * N_EDGES)

// ---------------- embedding: h = x @ emb_w + emb_b (wave-per-node, lane=c) ----
__global__ __launch_bounds__(256) void emb_kernel(
    const float* __restrict__ x, const float* __restrict__ w,
    const float* __restrict__ b, float* __restrict__ h, float* __restrict__ h0) {
  int node = blockIdx.x * 4 + (threadIdx.x >> 6);
  int c = threadIdx.x & 63;
  if (node >= N_NODES) return;
  float xv = (c < F_IN) ? x[node * F_IN + c] : 0.0f;
  float acc = b[c];
#pragma unroll
  for (int f = 0; f < F_IN; ++f) {
    float xf = __shfl(xv, f, 64);
    acc = fmaf(xf, w[f * H + c], acc);
  }
  int idx = node * H + c;
  h[idx] = acc;
  h0[idx] = acc;
}

// ---------------- binned CSR build (no scattered global atomics) ------------
// Entries packed 4B: (local_key<<17)|src ; local_key<782<2^10, src<100000<2^17.

__global__ __launch_bounds__(256) void p1_bincount(
    const int* __restrict__ e0, const int* __restrict__ e1,
    const int* __restrict__ e2, const int* __restrict__ e3,
    int* __restrict__ cntT) {
  __shared__ int hist[NBINS];
  int t = threadIdx.x, b = blockIdx.x;
  for (int i = t; i < NBINS; i += 256) hist[i] = 0;
  __syncthreads();
  int j = b >> 7;  // 128 blocks per edge set
  const int* ei = (j == 0) ? e0 : (j == 1) ? e1 : (j == 2) ? e2 : e3;
  int ebase = (b & 127) * CHUNK;
  for (int i = t; i < CHUNK; i += 256) {
    int dst = ei[N_EDGES + ebase + i];
    int key = j * N_NODES + dst;
    atomicAdd(&hist[key / BPB], 1);
  }
  __syncthreads();
  for (int i = t; i < NBINS; i += 256) cntT[i * NBINS + b] = hist[i];
}

__global__ __launch_bounds__(256) void p3_binscatter(
    const int* __restrict__ e0, const int* __restrict__ e1,
    const int* __restrict__ e2, const int* __restrict__ e3,
    const int* __restrict__ offT, unsigned* __restrict__ binned) {
  __shared__ int cur[NBINS];
  int t = threadIdx.x, b = blockIdx.x;
  for (int i = t; i < NBINS; i += 256) cur[i] = offT[i * NBINS + b];
  __syncthreads();
  int j = b >> 7;
  const int* ei = (j == 0) ? e0 : (j == 1) ? e1 : (j == 2) ? e2 : e3;
  int ebase = (b & 127) * CHUNK;
  for (int i = t; i < CHUNK; i += 256) {
    int src = ei[ebase + i];
    int dst = ei[N_EDGES + ebase + i];
    int key = j * N_NODES + dst;
    int bin = key / BPB;
    int pos = atomicAdd(&cur[bin], 1);
    binned[pos] = ((unsigned)(key - bin * BPB) << 17) | (unsigned)src;
  }
}

__global__ __launch_bounds__(256) void p4_deg(
    const unsigned* __restrict__ binned, const int* __restrict__ offT,
    int* __restrict__ deg4) {
  __shared__ int hist[BPB];
  int t = threadIdx.x, bin = blockIdx.x;
  for (int i = t; i < BPB; i += 256) hist[i] = 0;
  __syncthreads();
  int start = offT[bin * NBINS];
  int end = (bin == NBINS - 1) ? MEDGES : offT[(bin + 1) * NBINS];
  int kb = bin * BPB;
  for (int i = start + t; i < end; i += 256)
    atomicAdd(&hist[binned[i] >> 17], 1);
  __syncthreads();
  for (int i = t; i < BPB; i += 256)
    if (kb + i < MKEYS) deg4[kb + i] = hist[i];
}

__global__ __launch_bounds__(256) void p6_slots(
    const unsigned* __restrict__ binned, const int* __restrict__ offT,
    const int* __restrict__ S, int* __restrict__ slots) {
  __shared__ int cur[BPB];
  int t = threadIdx.x, bin = blockIdx.x;
  int kb = bin * BPB;
  for (int i = t; i < BPB; i += 256) cur[i] = (kb + i < MKEYS) ? S[kb + i] : 0;
  __syncthreads();
  int start = offT[bin * NBINS];
  int end = (bin == NBINS - 1) ? MEDGES : offT[(bin + 1) * NBINS];
  for (int i = start + t; i < end; i += 256) {
    unsigned v = binned[i];
    int pos = atomicAdd(&cur[v >> 17], 1);
    slots[pos] = (int)(v & 0x1ffffu);
  }
}

// ---------------- hierarchical exclusive scan (1024 elems/block) ------------
__global__ __launch_bounds__(256) void scan1(
    const int* __restrict__ in, int* __restrict__ S, int* __restrict__ bsum, int M) {
  int t = threadIdx.x;
  int base = blockIdx.x * 1024 + t * 4;
  int v0 = 0, v1 = 0, v2 = 0, v3 = 0;
  if (base + 3 < M) {
    int4 q = *(const int4*)(in + base);
    v0 = q.x; v1 = q.y; v2 = q.z; v3 = q.w;
  } else {
    if (base     < M) v0 = in[base];
    if (base + 1 < M) v1 = in[base + 1];
    if (base + 2 < M) v2 = in[base + 2];
    if (base + 3 < M) v3 = in[base + 3];
  }
  int s = v0 + v1 + v2 + v3;
  int incl = s;
#pragma unroll
  for (int off = 1; off < 64; off <<= 1) {
    int y = __shfl_up(incl, off, 64);
    if ((t & 63) >= off) incl += y;
  }
  __shared__ int wtot[4];
  if ((t & 63) == 63) wtot[t >> 6] = incl;
  __syncthreads();
  int wbase = 0;
  for (int w = 0; w < (t >> 6); ++w) wbase += wtot[w];
  int ex = wbase + incl - s;
  if (base < M) {
    int eo0 = ex, eo1 = ex + v0, eo2 = ex + v0 + v1, eo3 = ex + v0 + v1 + v2;
    if (base + 3 < M) {
      *(int4*)(S + base) = make_int4(eo0, eo1, eo2, eo3);
    } else {
      S[base] = eo0;
      if (base + 1 < M) S[base + 1] = eo1;
      if (base + 2 < M) S[base + 2] = eo2;
    }
  }
  if (t == 255) bsum[blockIdx.x] = wbase + incl;
}

__global__ __launch_bounds__(512) void scan2(int* __restrict__ bsum, int nb) {
  int t = threadIdx.x;
  int v = (t < nb) ? bsum[t] : 0;
  int incl = v;
#pragma unroll
  for (int off = 1; off < 64; off <<= 1) {
    int y = __shfl_up(incl, off, 64);
    if ((t & 63) >= off) incl += y;
  }
  __shared__ int wtot[8];
  if ((t & 63) == 63) wtot[t >> 6] = incl;
  __syncthreads();
  int wbase = 0;
  for (int w = 0; w < (t >> 6); ++w) wbase += wtot[w];
  if (t < nb) bsum[t] = wbase + incl - v;
}

__global__ __launch_bounds__(256) void scan3(
    int* __restrict__ S, const int* __restrict__ bsum, int M) {
  int i = blockIdx.x * 256 + threadIdx.x;
  if (i >= M) return;
  S[i] = S[i] + bsum[i >> 10];
}

// ---------------- degree-bucket lists (LDS-aggregated) ----------------------
__global__ __launch_bounds__(256) void bucket_count(
    const int* __restrict__ deg4, int* __restrict__ bcnt) {
  __shared__ int hist[21];
  int t = threadIdx.x;
  if (t < 21) hist[t] = 0;
  __syncthreads();
  int node = blockIdx.x * 256 + t;
  int j = blockIdx.y;
  if (node < N_NODES) {
    int d = deg4[j * N_NODES + node];
    int b = d < MAX_DEG ? d : MAX_DEG;
    atomicAdd(&hist[b], 1);
  }
  __syncthreads();
  if (t < 21 && hist[t]) atomicAdd(&bcnt[j * 21 + t], hist[t]);
}

__global__ __launch_bounds__(128) void bucket_scan(
    const int* __restrict__ bcnt, int* __restrict__ boff, int* __restrict__ bcur) {
  int t = threadIdx.x;
  int v = (t < 84) ? bcnt[t] : 0;
  int incl = v;
#pragma unroll
  for (int off = 1; off < 64; off <<= 1) {
    int y = __shfl_up(incl, off, 64);
    if ((t & 63) >= off) incl += y;
  }
  __shared__ int wt[2];
  if ((t & 63) == 63) wt[t >> 6] = incl;
  __syncthreads();
  int wbase = (t >> 6) ? wt[0] : 0;
  if (t < 84) {
    int ex = wbase + incl - v;
    boff[t] = ex;
    bcur[t] = ex;
  }
}

__global__ __launch_bounds__(256) void bucket_fill(
    const int* __restrict__ deg4, int* __restrict__ bcur, int* __restrict__ blist) {
  __shared__ int hist[21];
  __shared__ int base[21];
  int t = threadIdx.x;
  if (t < 21) hist[t] = 0;
  __syncthreads();
  int node = blockIdx.x * 256 + t;
  int j = blockIdx.y;
  int b = 0, lpos = 0;
  bool valid = (node < N_NODES);
  if (valid) {
    int d = deg4[j * N_NODES + node];
    b = d < MAX_DEG ? d : MAX_DEG;
    lpos = atomicAdd(&hist[b], 1);
  }
  __syncthreads();
  if (t < 21 && hist[t]) base[t] = atomicAdd(&bcur[j * 21 + t], hist[t]);
  __syncthreads();
  if (valid) blist[base[b] + lpos] = node;
}

// ---------------- fused conv: gather + dual GEMV, ping-pong h ----------------
// Reads hin (self + neighbors), writes EVERY node to hout -> no in-place race.
// Bucket b: all nodes same clamped degree; b==20 nodes use actual deg[node].
__global__ __launch_bounds__(256) void conv_kernel(
    const float* __restrict__ hin, float* __restrict__ hout,
    const int* __restrict__ S, const int* __restrict__ deg,
    const int* __restrict__ slots,
    const int* __restrict__ blist, const int* __restrict__ bcnt,
    const int* __restrict__ boff, const float* __restrict__ wl,
    const float* __restrict__ bl, const float* __restrict__ wr,
    int jb21, int do_relu) {
  int b = blockIdx.y;
  int cnt = bcnt[jb21 + b];
  int start = blockIdx.x * 64;
  if (start >= cnt) return;
  int nIn = min(64, cnt - start);
  const int* lst = blist + boff[jb21 + b] + start;

  int tid = threadIdx.x;
  int qw = tid >> 6, lane = tid & 63;
  __shared__ float hsL[64 * 65];
  __shared__ float hcL[64 * 65];
  __shared__ int nodeS[64];

  // load+gather phase: wave qw stages rows [qw*16, +16); lane = channel.
  // node (thus dg) is wave-uniform per row -> no divergence.
  for (int r = qw * 16; r < qw * 16 + 16; ++r) {
    int node = (r < nIn) ? lst[r] : -1;
    if (lane == 0) nodeS[r] = node;
    float hv = 0.f, sv = 0.f;
    if (node >= 0) {
      hv = hin[node * H + lane];
      if (b) {
        int off = S[node];
        int dg = deg[node];
        float s0 = 0.f, s1 = 0.f, s2 = 0.f, s3 = 0.f;
        int e = 0;
        for (; e + 4 <= dg; e += 4) {
          int a0 = slots[off + e];
          int a1 = slots[off + e + 1];
          int a2 = slots[off + e + 2];
          int a3 = slots[off + e + 3];
          s0 += hin[a0 * H + lane];
          s1 += hin[a1 * H + lane];
          s2 += hin[a2 * H + lane];
          s3 += hin[a3 * H + lane];
        }
        for (; e < dg; ++e) s0 += hin[slots[off + e] * H + lane];
        sv = (s0 + s1) + (s2 + s3);
      }
    }
    hcL[lane * 65 + r] = hv;
    hsL[lane * 65 + r] = sv;
  }
  __syncthreads();

  if (b) {
    // compute: lane = node (column), wave qw owns channels [qw*16, +16)
    int qs = __builtin_amdgcn_readfirstlane(qw);
    const float* __restrict__ WL = wl + ((size_t)b << 12) + (qs << 4);
    const float* __restrict__ WR = wr + ((size_t)b << 12) + (qs << 4);
    const float* __restrict__ BL = bl + (b << 6) + (qs << 4);
    float acc[16];
#pragma unroll
    for (int k = 0; k < 16; ++k) acc[k] = BL[k];
#pragma unroll 4
    for (int f = 0; f < 64; ++f) {
      float hsf = hsL[f * 65 + lane];
      float hcf = hcL[f * 65 + lane];
#pragma unroll
      for (int k = 0; k < 16; ++k) acc[k] = fmaf(hsf, WL[f * H + k], acc[k]);
#pragma unroll
      for (int k = 0; k < 16; ++k) acc[k] = fmaf(hcf, WR[f * H + k], acc[k]);
    }
    if (do_relu) {
#pragma unroll
      for (int k = 0; k < 16; ++k) acc[k] = fmaxf(acc[k], 0.f);
    }
    __syncthreads();
#pragma unroll
    for (int k = 0; k < 16; ++k) hsL[(qw * 16 + k) * 65 + lane] = acc[k];
    __syncthreads();
    for (int r = qw * 16; r < qw * 16 + 16; ++r) {
      if (r < nIn) hout[nodeS[r] * H + lane] = hsL[lane * 65 + r];
    }
  } else {
    // deg==0: keep h (masking), ReLU still applies when j<3
    for (int r = qw * 16; r < qw * 16 + 16; ++r) {
      if (r < nIn) {
        float v = hcL[lane * 65 + r];
        if (do_relu) v = fmaxf(v, 0.f);
        hout[nodeS[r] * H + lane] = v;
      }
    }
  }
}

// ---------------- layernorm + residual ----------------
__global__ __launch_bounds__(256) void ln_kernel(
    float* __restrict__ h, const float* __restrict__ h0,
    const float* __restrict__ g, const float* __restrict__ b) {
  int node = blockIdx.x * 4 + (threadIdx.x >> 6);
  int c = threadIdx.x & 63;
  if (node >= N_NODES) return;
  int idx = node * H + c;
  float v = h[idx];
  float s = v;
#pragma unroll
  for (int off = 32; off > 0; off >>= 1) s += __shfl_xor(s, off, 64);
  float mu = s * (1.0f / H);
  float dv = v - mu;
  float q = dv * dv;
#pragma unroll
  for (int off = 32; off > 0; off >>= 1) q += __shfl_xor(q, off, 64);
  float inv = rsqrtf(q * (1.0f / H) + LN_EPS);
  h[idx] = dv * inv * g[c] + b[c] + h0[idx];
}

// ---------------- pool: LDS-aggregated, 256 blocks (R5: 64 blocks = 2.7% occ) --
__global__ __launch_bounds__(256) void pool_kernel(
    const float* __restrict__ h, const int* __restrict__ batch,
    float* __restrict__ pooled) {
  __shared__ float sm[NUM_GRAPHS * H];  // 32 KB
  int t = threadIdx.x;
  for (int i = t; i < NUM_GRAPHS * H; i += 256) sm[i] = 0.f;
  __syncthreads();
  int lane = t & 63, w = t >> 6;
  const int per = (G_NODES + POOL_BLOCKS - 1) / POOL_BLOCKS;
  int start = blockIdx.x * per;
  int end = min(start + per, G_NODES);
  for (int node = start + w; node < end; node += 4) {
    int g = batch[node];
    atomicAdd(&sm[g * H + lane], h[node * H + lane]);
  }
  __syncthreads();
  for (int i = t; i < NUM_GRAPHS * H; i += 256) {
    float v = sm[i];
    if (v != 0.f) atomicAdd(&pooled[i], v);
  }
}

__global__ __launch_bounds__(64) void out_kernel(
    const float* __restrict__ pooled, const float* __restrict__ w,
    const float* __restrict__ b, float* __restrict__ out) {
  int gph = blockIdx.x;
  int c = threadIdx.x;
  float v = pooled[gph * H + c] * w[c];
#pragma unroll
  for (int off = 32; off > 0; off >>= 1) v += __shfl_xor(v, off, 64);
  if (c == 0) out[gph] = v + b[0];
}

extern "C" void kernel_launch(void* const* d_in, const int* in_sizes, int n_in,
                              void* d_out, int out_size, void* d_ws, size_t ws_size,
                              hipStream_t stream) {
  const float* x       = (const float*)d_in[0];
  const int*   ei_edge = (const int*)d_in[1];
  const int*   ei_sub  = (const int*)d_in[2];
  const int*   ei_ns   = (const int*)d_in[3];
  const int*   ei_sn   = (const int*)d_in[4];
  const int*   batch   = (const int*)d_in[7];
  const float* emb_w   = (const float*)d_in[8];
  const float* emb_b   = (const float*)d_in[9];
  const float* conv_wl = (const float*)d_in[10];
  const float* conv_bl = (const float*)d_in[11];
  const float* conv_wr = (const float*)d_in[12];
  const float* ln_g    = (const float*)d_in[13];
  const float* ln_b    = (const float*)d_in[14];
  const float* out_w   = (const float*)d_in[15];
  const float* out_b   = (const float*)d_in[16];
  float* out = (float*)d_out;

  const size_t HB = (size_t)N_NODES * H * sizeof(float);  // 25.6 MB
  char* ws = (char*)d_ws;
  float* hA     = (float*)(ws);            // ping
  float* h0     = (float*)(ws + HB);
  float* hB     = (float*)(ws + 2 * HB);   // pong (was hsum)
  // Build-phase overlays (dead once emb_kernel runs):
  unsigned* binned = (unsigned*)(ws);                            // 12.8 MB on hA
  int*   cntT   = (int*)(ws + HB);                               // 1 MB on h0
  int*   offT   = (int*)(ws + HB + 0x100000);                    // 1 MB
  int*   bsumA  = (int*)(ws + HB + 0x300000);                    // 2 KB
  // Persistent:
  int*   deg4   = (int*)(ws + 3 * HB);                           // 1.6 MB
  int*   S      = (int*)(ws + 78400000);                         // 1.6 MB
  int*   slots  = (int*)(ws + 80000000);                         // 12.8 MB
  int*   bcnt   = (int*)(ws + 92800000);
  int*   boff   = (int*)(ws + 92800512);
  int*   bcur   = (int*)(ws + 92801024);
  int*   blist  = (int*)(ws + 92801536);                         // 1.6 MB
  float* pooled = (float*)(ws + 94401536);                       // 32 KB

  const int* e0 = ei_edge, *e1 = ei_ns, *e2 = ei_sub, *e3 = ei_sn;
  const int MC = NBINS * NBINS;
  const int NB_MC = MC / 1024;              // 256
  const int NB_MK = (MKEYS + 1023) / 1024;  // 391

  hipMemsetAsync(bcnt, 0, 512, stream);

  // --- binned CSR build ---
  p1_bincount<<<NBINS, 256, 0, stream>>>(e0, e1, e2, e3, cntT);
  scan1<<<NB_MC, 256, 0, stream>>>(cntT, offT, bsumA, MC);
  scan2<<<1, 512, 0, stream>>>(bsumA, NB_MC);
  scan3<<<MC / 256, 256, 0, stream>>>(offT, bsumA, MC);
  p3_binscatter<<<NBINS, 256, 0, stream>>>(e0, e1, e2, e3, offT, binned);
  p4_deg<<<NBINS, 256, 0, stream>>>(binned, offT, deg4);
  scan1<<<NB_MK, 256, 0, stream>>>(deg4, S, bsumA, MKEYS);
  scan2<<<1, 512, 0, stream>>>(bsumA, NB_MK);
  scan3<<<(MKEYS + 255) / 256, 256, 0, stream>>>(S, bsumA, MKEYS);
  p6_slots<<<NBINS, 256, 0, stream>>>(binned, offT, S, slots);

  bucket_count<<<dim3((N_NODES + 255) / 256, 4), 256, 0, stream>>>(deg4, bcnt);
  bucket_scan<<<1, 128, 0, stream>>>(bcnt, boff, bcur);
  bucket_fill<<<dim3((N_NODES + 255) / 256, 4), 256, 0, stream>>>(deg4, bcur, blist);

  // --- network (h ping-pongs A->B->A->B->A; 4 convs end in A) ---
  emb_kernel<<<(N_NODES + 3) / 4, 256, 0, stream>>>(x, emb_w, emb_b, hA, h0);

  const int TNB = (N_NODES + 63) / 64;  // 1563
  float* hin = hA, *hout = hB;
  for (int j = 0; j < 4; ++j) {
    conv_kernel<<<dim3(TNB, 21), 256, 0, stream>>>(
        hin, hout, S + j * N_NODES, deg4 + j * N_NODES, slots,
        blist, bcnt, boff,
        conv_wl + (size_t)j * 21 * H * H,
        conv_bl + (size_t)j * 21 * H,
        conv_wr + (size_t)j * 21 * H * H,
        j * 21, j < 3 ? 1 : 0);
    float* tmp = hin; hin = hout; hout = tmp;
  }
  // hin now points at the buffer holding conv-4 output (hA)

  ln_kernel<<<(N_NODES + 3) / 4, 256, 0, stream>>>(hin, h0, ln_g, ln_b);

  hipMemsetAsync(pooled, 0, NUM_GRAPHS * H * sizeof(float), stream);
  pool_kernel<<<POOL_BLOCKS, 256, 0, stream>>>(hin, batch, pooled);
  out_kernel<<<NUM_GRAPHS, 64, 0, stream>>>(pooled, out_w, out_b, out);
}

// Round 7
// 694.409 us; speedup vs baseline: 1.2159x; 1.2159x over previous
//
#include <hip/hip_runtime.h>

#define N_NODES 100000
#define G_NODES 50000
#define N_EDGES 800000
#define H 64
#define F_IN 32
#define MAX_DEG 20
#define NUM_GRAPHS 128
#define LN_EPS 1e-5f
#define POOL_BLOCKS 256

// Binned CSR build parameters: 512 bins over the 4*N key space.
#define NBINS 512
#define BPB 782            // keys per bin: 782*512 = 400384 >= 400000
#define CHUNK 6250         // edges per build block: 6250*512 = 3.2M
#define MKEYS (4 * N_NODES)
#define MEDGES (4 * N_EDGES)

// bf16 helpers (RNE), no header dependency
static __device__ __forceinline__ unsigned short f2b(float f) {
  unsigned u = __float_as_uint(f);
  return (unsigned short)((u + 0x7fffu + ((u >> 16) & 1u)) >> 16);
}
static __device__ __forceinline__ float b2f(unsigned short b) {
  return __uint_as_float(((unsigned)b) << 16);
}

// ---------------- embedding: h = x @ emb_w + emb_b ----------------
__global__ __launch_bounds__(256) void emb_kernel(
    const float* __restrict__ x, const float* __restrict__ w,
    const float* __restrict__ b, float* __restrict__ h,
    float* __restrict__ h0, unsigned short* __restrict__ hb) {
  int node = blockIdx.x * 4 + (threadIdx.x >> 6);
  int c = threadIdx.x & 63;
  if (node >= N_NODES) return;
  float xv = (c < F_IN) ? x[node * F_IN + c] : 0.0f;
  float acc = b[c];
#pragma unroll
  for (int f = 0; f < F_IN; ++f) {
    float xf = __shfl(xv, f, 64);
    acc = fmaf(xf, w[f * H + c], acc);
  }
  int idx = node * H + c;
  h[idx] = acc;
  h0[idx] = acc;
  hb[idx] = f2b(acc);
}

// ---------------- binned CSR build (no scattered global atomics) ------------
// Entries packed 4B: (local_key<<17)|src ; local_key<782<2^10, src<100000<2^17.

__global__ __launch_bounds__(256) void p1_bincount(
    const int* __restrict__ e0, const int* __restrict__ e1,
    const int* __restrict__ e2, const int* __restrict__ e3,
    int* __restrict__ cntT) {
  __shared__ int hist[NBINS];
  int t = threadIdx.x, b = blockIdx.x;
  for (int i = t; i < NBINS; i += 256) hist[i] = 0;
  __syncthreads();
  int j = b >> 7;  // 128 blocks per edge set
  const int* ei = (j == 0) ? e0 : (j == 1) ? e1 : (j == 2) ? e2 : e3;
  int ebase = (b & 127) * CHUNK;
  for (int i = t; i < CHUNK; i += 256) {
    int dst = ei[N_EDGES + ebase + i];
    int key = j * N_NODES + dst;
    atomicAdd(&hist[key / BPB], 1);
  }
  __syncthreads();
  for (int i = t; i < NBINS; i += 256) cntT[i * NBINS + b] = hist[i];
}

__global__ __launch_bounds__(256) void p3_binscatter(
    const int* __restrict__ e0, const int* __restrict__ e1,
    const int* __restrict__ e2, const int* __restrict__ e3,
    const int* __restrict__ offT, unsigned* __restrict__ binned) {
  __shared__ int cur[NBINS];
  int t = threadIdx.x, b = blockIdx.x;
  for (int i = t; i < NBINS; i += 256) cur[i] = offT[i * NBINS + b];
  __syncthreads();
  int j = b >> 7;
  const int* ei = (j == 0) ? e0 : (j == 1) ? e1 : (j == 2) ? e2 : e3;
  int ebase = (b & 127) * CHUNK;
  for (int i = t; i < CHUNK; i += 256) {
    int src = ei[ebase + i];
    int dst = ei[N_EDGES + ebase + i];
    int key = j * N_NODES + dst;
    int bin = key / BPB;
    int pos = atomicAdd(&cur[bin], 1);
    binned[pos] = ((unsigned)(key - bin * BPB) << 17) | (unsigned)src;
  }
}

__global__ __launch_bounds__(256) void p4_deg(
    const unsigned* __restrict__ binned, const int* __restrict__ offT,
    int* __restrict__ deg4) {
  __shared__ int hist[BPB];
  int t = threadIdx.x, bin = blockIdx.x;
  for (int i = t; i < BPB; i += 256) hist[i] = 0;
  __syncthreads();
  int start = offT[bin * NBINS];
  int end = (bin == NBINS - 1) ? MEDGES : offT[(bin + 1) * NBINS];
  int kb = bin * BPB;
  for (int i = start + t; i < end; i += 256)
    atomicAdd(&hist[binned[i] >> 17], 1);
  __syncthreads();
  for (int i = t; i < BPB; i += 256)
    if (kb + i < MKEYS) deg4[kb + i] = hist[i];
}

__global__ __launch_bounds__(256) void p6_slots(
    const unsigned* __restrict__ binned, const int* __restrict__ offT,
    const int* __restrict__ S, int* __restrict__ slots) {
  __shared__ int cur[BPB];
  int t = threadIdx.x, bin = blockIdx.x;
  int kb = bin * BPB;
  for (int i = t; i < BPB; i += 256) cur[i] = (kb + i < MKEYS) ? S[kb + i] : 0;
  __syncthreads();
  int start = offT[bin * NBINS];
  int end = (bin == NBINS - 1) ? MEDGES : offT[(bin + 1) * NBINS];
  for (int i = start + t; i < end; i += 256) {
    unsigned v = binned[i];
    int pos = atomicAdd(&cur[v >> 17], 1);
    slots[pos] = (int)(v & 0x1ffffu);
  }
}

// ---------------- hierarchical exclusive scan (1024 elems/block) ------------
__global__ __launch_bounds__(256) void scan1(
    const int* __restrict__ in, int* __restrict__ S, int* __restrict__ bsum, int M) {
  int t = threadIdx.x;
  int base = blockIdx.x * 1024 + t * 4;
  int v0 = 0, v1 = 0, v2 = 0, v3 = 0;
  if (base + 3 < M) {
    int4 q = *(const int4*)(in + base);
    v0 = q.x; v1 = q.y; v2 = q.z; v3 = q.w;
  } else {
    if (base     < M) v0 = in[base];
    if (base + 1 < M) v1 = in[base + 1];
    if (base + 2 < M) v2 = in[base + 2];
    if (base + 3 < M) v3 = in[base + 3];
  }
  int s = v0 + v1 + v2 + v3;
  int incl = s;
#pragma unroll
  for (int off = 1; off < 64; off <<= 1) {
    int y = __shfl_up(incl, off, 64);
    if ((t & 63) >= off) incl += y;
  }
  __shared__ int wtot[4];
  if ((t & 63) == 63) wtot[t >> 6] = incl;
  __syncthreads();
  int wbase = 0;
  for (int w = 0; w < (t >> 6); ++w) wbase += wtot[w];
  int ex = wbase + incl - s;
  if (base < M) {
    int eo0 = ex, eo1 = ex + v0, eo2 = ex + v0 + v1, eo3 = ex + v0 + v1 + v2;
    if (base + 3 < M) {
      *(int4*)(S + base) = make_int4(eo0, eo1, eo2, eo3);
    } else {
      S[base] = eo0;
      if (base + 1 < M) S[base + 1] = eo1;
      if (base + 2 < M) S[base + 2] = eo2;
    }
  }
  if (t == 255) bsum[blockIdx.x] = wbase + incl;
}

__global__ __launch_bounds__(512) void scan2(int* __restrict__ bsum, int nb) {
  int t = threadIdx.x;
  int v = (t < nb) ? bsum[t] : 0;
  int incl = v;
#pragma unroll
  for (int off = 1; off < 64; off <<= 1) {
    int y = __shfl_up(incl, off, 64);
    if ((t & 63) >= off) incl += y;
  }
  __shared__ int wtot[8];
  if ((t & 63) == 63) wtot[t >> 6] = incl;
  __syncthreads();
  int wbase = 0;
  for (int w = 0; w < (t >> 6); ++w) wbase += wtot[w];
  if (t < nb) bsum[t] = wbase + incl - v;
}

__global__ __launch_bounds__(256) void scan3(
    int* __restrict__ S, const int* __restrict__ bsum, int M) {
  int i = blockIdx.x * 256 + threadIdx.x;
  if (i >= M) return;
  S[i] = S[i] + bsum[i >> 10];
}

// ---------------- degree-bucket lists (LDS-aggregated) ----------------------
__global__ __launch_bounds__(256) void bucket_count(
    const int* __restrict__ deg4, int* __restrict__ bcnt) {
  __shared__ int hist[21];
  int t = threadIdx.x;
  if (t < 21) hist[t] = 0;
  __syncthreads();
  int node = blockIdx.x * 256 + t;
  int j = blockIdx.y;
  if (node < N_NODES) {
    int d = deg4[j * N_NODES + node];
    int b = d < MAX_DEG ? d : MAX_DEG;
    atomicAdd(&hist[b], 1);
  }
  __syncthreads();
  if (t < 21 && hist[t]) atomicAdd(&bcnt[j * 21 + t], hist[t]);
}

__global__ __launch_bounds__(128) void bucket_scan(
    const int* __restrict__ bcnt, int* __restrict__ boff, int* __restrict__ bcur) {
  int t = threadIdx.x;
  int v = (t < 84) ? bcnt[t] : 0;
  int incl = v;
#pragma unroll
  for (int off = 1; off < 64; off <<= 1) {
    int y = __shfl_up(incl, off, 64);
    if ((t & 63) >= off) incl += y;
  }
  __shared__ int wt[2];
  if ((t & 63) == 63) wt[t >> 6] = incl;
  __syncthreads();
  int wbase = (t >> 6) ? wt[0] : 0;
  if (t < 84) {
    int ex = wbase + incl - v;
    boff[t] = ex;
    bcur[t] = ex;
  }
}

__global__ __launch_bounds__(256) void bucket_fill(
    const int* __restrict__ deg4, int* __restrict__ bcur, int* __restrict__ blist) {
  __shared__ int hist[21];
  __shared__ int base[21];
  int t = threadIdx.x;
  if (t < 21) hist[t] = 0;
  __syncthreads();
  int node = blockIdx.x * 256 + t;
  int j = blockIdx.y;
  int b = 0, lpos = 0;
  bool valid = (node < N_NODES);
  if (valid) {
    int d = deg4[j * N_NODES + node];
    b = d < MAX_DEG ? d : MAX_DEG;
    lpos = atomicAdd(&hist[b], 1);
  }
  __syncthreads();
  if (t < 21 && hist[t]) base[t] = atomicAdd(&bcur[j * 21 + t], hist[t]);
  __syncthreads();
  if (valid) blist[base[b] + lpos] = node;
}

// ---------------- gather: hsum[i] = sum_{j->i} hb16[j], bf16 rows -----------
// bf16 halves both logical bytes and the XCD-duplicated footprint (R6 lesson:
// random-row fetch scales with footprint x 8 non-coherent L2s).
__global__ __launch_bounds__(256) void gather_kernel(
    const int* __restrict__ S, const int* __restrict__ deg,
    const int* __restrict__ slots, const unsigned short* __restrict__ hb,
    unsigned short* __restrict__ hsum) {
  int node = blockIdx.x * 4 + (threadIdx.x >> 6);
  int c = threadIdx.x & 63;
  if (node >= N_NODES) return;
  int off = S[node];
  int dg = deg[node];
  float s0 = 0.f, s1 = 0.f, s2 = 0.f, s3 = 0.f;
  int e = 0;
  for (; e + 4 <= dg; e += 4) {
    int a0 = slots[off + e];
    int a1 = slots[off + e + 1];
    int a2 = slots[off + e + 2];
    int a3 = slots[off + e + 3];
    s0 += b2f(hb[a0 * H + c]);
    s1 += b2f(hb[a1 * H + c]);
    s2 += b2f(hb[a2 * H + c]);
    s3 += b2f(hb[a3 * H + c]);
  }
  for (; e < dg; ++e) s0 += b2f(hb[slots[off + e] * H + c]);
  hsum[node * H + c] = f2b((s0 + s1) + (s2 + s3));
}

// ---------------- bucketed transform (in-place h: each node in exactly 1 tile)
__global__ __launch_bounds__(256) void transform_kernel(
    float* __restrict__ h, unsigned short* __restrict__ hb,
    const unsigned short* __restrict__ hsum,
    const int* __restrict__ blist, const int* __restrict__ bcnt,
    const int* __restrict__ boff, const float* __restrict__ wl,
    const float* __restrict__ bl, const float* __restrict__ wr,
    int jb21, int do_relu) {
  int b = blockIdx.y;
  int cnt = bcnt[jb21 + b];
  int start = blockIdx.x * 64;
  if (start >= cnt) return;
  int nIn = min(64, cnt - start);
  const int* lst = blist + boff[jb21 + b] + start;

  int tid = threadIdx.x;
  int qw = tid >> 6, lane = tid & 63;
  __shared__ float hsL[64 * 65];
  __shared__ float hcL[64 * 65];
  __shared__ int nodeS[64];

  for (int r = qw * 16; r < qw * 16 + 16; ++r) {
    int node = (r < nIn) ? lst[r] : -1;
    if (lane == 0) nodeS[r] = node;
    float hv = 0.f, sv = 0.f;
    if (node >= 0) {
      hv = h[node * H + lane];                // fp32: exact self/mask path
      if (b) sv = b2f(hsum[node * H + lane]); // bf16 neighbor sum
    }
    hcL[lane * 65 + r] = hv;
    hsL[lane * 65 + r] = sv;
  }
  __syncthreads();

  if (b) {
    int qs = __builtin_amdgcn_readfirstlane(qw);
    const float* __restrict__ WL = wl + ((size_t)b << 12) + (qs << 4);
    const float* __restrict__ WR = wr + ((size_t)b << 12) + (qs << 4);
    const float* __restrict__ BL = bl + (b << 6) + (qs << 4);
    float acc[16];
#pragma unroll
    for (int k = 0; k < 16; ++k) acc[k] = BL[k];
#pragma unroll 4
    for (int f = 0; f < 64; ++f) {
      float hsf = hsL[f * 65 + lane];
      float hcf = hcL[f * 65 + lane];
#pragma unroll
      for (int k = 0; k < 16; ++k) acc[k] = fmaf(hsf, WL[f * H + k], acc[k]);
#pragma unroll
      for (int k = 0; k < 16; ++k) acc[k] = fmaf(hcf, WR[f * H + k], acc[k]);
    }
    if (do_relu) {
#pragma unroll
      for (int k = 0; k < 16; ++k) acc[k] = fmaxf(acc[k], 0.f);
    }
    __syncthreads();
#pragma unroll
    for (int k = 0; k < 16; ++k) hsL[(qw * 16 + k) * 65 + lane] = acc[k];
    __syncthreads();
    for (int r = qw * 16; r < qw * 16 + 16; ++r) {
      if (r < nIn) {
        float v = hsL[lane * 65 + r];
        int idx = nodeS[r] * H + lane;
        h[idx] = v;
        hb[idx] = f2b(v);
      }
    }
  } else {
    for (int r = qw * 16; r < qw * 16 + 16; ++r) {
      if (r < nIn) {
        float v = hcL[lane * 65 + r];
        if (do_relu) v = fmaxf(v, 0.f);
        int idx = nodeS[r] * H + lane;
        h[idx] = v;
        hb[idx] = f2b(v);
      }
    }
  }
}

// ---------------- layernorm + residual ----------------
__global__ __launch_bounds__(256) void ln_kernel(
    float* __restrict__ h, const float* __restrict__ h0,
    const float* __restrict__ g, const float* __restrict__ b) {
  int node = blockIdx.x * 4 + (threadIdx.x >> 6);
  int c = threadIdx.x & 63;
  if (node >= N_NODES) return;
  int idx = node * H + c;
  float v = h[idx];
  float s = v;
#pragma unroll
  for (int off = 32; off > 0; off >>= 1) s += __shfl_xor(s, off, 64);
  float mu = s * (1.0f / H);
  float dv = v - mu;
  float q = dv * dv;
#pragma unroll
  for (int off = 32; off > 0; off >>= 1) q += __shfl_xor(q, off, 64);
  float inv = rsqrtf(q * (1.0f / H) + LN_EPS);
  h[idx] = dv * inv * g[c] + b[c] + h0[idx];
}

// ---------------- pool: LDS-aggregated, 256 blocks ----------------
__global__ __launch_bounds__(256) void pool_kernel(
    const float* __restrict__ h, const int* __restrict__ batch,
    float* __restrict__ pooled) {
  __shared__ float sm[NUM_GRAPHS * H];  // 32 KB
  int t = threadIdx.x;
  for (int i = t; i < NUM_GRAPHS * H; i += 256) sm[i] = 0.f;
  __syncthreads();
  int lane = t & 63, w = t >> 6;
  const int per = (G_NODES + POOL_BLOCKS - 1) / POOL_BLOCKS;
  int start = blockIdx.x * per;
  int end = min(start + per, G_NODES);
  for (int node = start + w; node < end; node += 4) {
    int g = batch[node];
    atomicAdd(&sm[g * H + lane], h[node * H + lane]);
  }
  __syncthreads();
  for (int i = t; i < NUM_GRAPHS * H; i += 256) {
    float v = sm[i];
    if (v != 0.f) atomicAdd(&pooled[i], v);
  }
}

__global__ __launch_bounds__(64) void out_kernel(
    const float* __restrict__ pooled, const float* __restrict__ w,
    const float* __restrict__ b, float* __restrict__ out) {
  int gph = blockIdx.x;
  int c = threadIdx.x;
  float v = pooled[gph * H + c] * w[c];
#pragma unroll
  for (int off = 32; off > 0; off >>= 1) v += __shfl_xor(v, off, 64);
  if (c == 0) out[gph] = v + b[0];
}

extern "C" void kernel_launch(void* const* d_in, const int* in_sizes, int n_in,
                              void* d_out, int out_size, void* d_ws, size_t ws_size,
                              hipStream_t stream) {
  const float* x       = (const float*)d_in[0];
  const int*   ei_edge = (const int*)d_in[1];
  const int*   ei_sub  = (const int*)d_in[2];
  const int*   ei_ns   = (const int*)d_in[3];
  const int*   ei_sn   = (const int*)d_in[4];
  const int*   batch   = (const int*)d_in[7];
  const float* emb_w   = (const float*)d_in[8];
  const float* emb_b   = (const float*)d_in[9];
  const float* conv_wl = (const float*)d_in[10];
  const float* conv_bl = (const float*)d_in[11];
  const float* conv_wr = (const float*)d_in[12];
  const float* ln_g    = (const float*)d_in[13];
  const float* ln_b    = (const float*)d_in[14];
  const float* out_w   = (const float*)d_in[15];
  const float* out_b   = (const float*)d_in[16];
  float* out = (float*)d_out;

  const size_t HB = (size_t)N_NODES * H * sizeof(float);   // 25.6 MB
  const size_t HB2 = (size_t)N_NODES * H * sizeof(short);  // 12.8 MB
  char* ws = (char*)d_ws;
  float* h      = (float*)(ws);
  float* h0     = (float*)(ws + HB);
  unsigned short* hsum = (unsigned short*)(ws + 2 * HB);        // 12.8 MB
  unsigned short* hb16 = (unsigned short*)(ws + 2 * HB + HB2);  // 12.8 MB
  // Build-phase overlays (dead once emb_kernel runs):
  unsigned* binned = (unsigned*)(ws);                            // 12.8 MB on h
  int*   cntT   = (int*)(ws + HB);                               // 1 MB on h0
  int*   offT   = (int*)(ws + HB + 0x100000);                    // 1 MB
  int*   bsumA  = (int*)(ws + HB + 0x300000);                    // 2 KB
  // Persistent:
  int*   deg4   = (int*)(ws + 3 * HB);                           // 1.6 MB
  int*   S      = (int*)(ws + 78400000);                         // 1.6 MB
  int*   slots  = (int*)(ws + 80000000);                         // 12.8 MB
  int*   bcnt   = (int*)(ws + 92800000);
  int*   boff   = (int*)(ws + 92800512);
  int*   bcur   = (int*)(ws + 92801024);
  int*   blist  = (int*)(ws + 92801536);                         // 1.6 MB
  float* pooled = (float*)(ws + 94401536);                       // 32 KB

  const int* e0 = ei_edge, *e1 = ei_ns, *e2 = ei_sub, *e3 = ei_sn;
  const int MC = NBINS * NBINS;
  const int NB_MC = MC / 1024;              // 256
  const int NB_MK = (MKEYS + 1023) / 1024;  // 391

  hipMemsetAsync(bcnt, 0, 512, stream);

  // --- binned CSR build ---
  p1_bincount<<<NBINS, 256, 0, stream>>>(e0, e1, e2, e3, cntT);
  scan1<<<NB_MC, 256, 0, stream>>>(cntT, offT, bsumA, MC);
  scan2<<<1, 512, 0, stream>>>(bsumA, NB_MC);
  scan3<<<MC / 256, 256, 0, stream>>>(offT, bsumA, MC);
  p3_binscatter<<<NBINS, 256, 0, stream>>>(e0, e1, e2, e3, offT, binned);
  p4_deg<<<NBINS, 256, 0, stream>>>(binned, offT, deg4);
  scan1<<<NB_MK, 256, 0, stream>>>(deg4, S, bsumA, MKEYS);
  scan2<<<1, 512, 0, stream>>>(bsumA, NB_MK);
  scan3<<<(MKEYS + 255) / 256, 256, 0, stream>>>(S, bsumA, MKEYS);
  p6_slots<<<NBINS, 256, 0, stream>>>(binned, offT, S, slots);

  bucket_count<<<dim3((N_NODES + 255) / 256, 4), 256, 0, stream>>>(deg4, bcnt);
  bucket_scan<<<1, 128, 0, stream>>>(bcnt, boff, bcur);
  bucket_fill<<<dim3((N_NODES + 255) / 256, 4), 256, 0, stream>>>(deg4, bcur, blist);

  // --- network ---
  emb_kernel<<<(N_NODES + 3) / 4, 256, 0, stream>>>(x, emb_w, emb_b, h, h0, hb16);

  const int TNB = (N_NODES + 63) / 64;  // 1563
  for (int j = 0; j < 4; ++j) {
    gather_kernel<<<(N_NODES + 3) / 4, 256, 0, stream>>>(
        S + j * N_NODES, deg4 + j * N_NODES, slots, hb16, hsum);
    transform_kernel<<<dim3(TNB, 21), 256, 0, stream>>>(
        h, hb16, hsum, blist, bcnt, boff,
        conv_wl + (size_t)j * 21 * H * H,
        conv_bl + (size_t)j * 21 * H,
        conv_wr + (size_t)j * 21 * H * H,
        j * 21, j < 3 ? 1 : 0);
  }

  ln_kernel<<<(N_NODES + 3) / 4, 256, 0, stream>>>(h, h0, ln_g, ln_b);

  hipMemsetAsync(pooled, 0, NUM_GRAPHS * H * sizeof(float), stream);
  pool_kernel<<<POOL_BLOCKS, 256, 0, stream>>>(h, batch, pooled);
  out_kernel<<<NUM_GRAPHS, 64, 0, stream>>>(pooled, out_w, out_b, out);
}

// Round 8
// 657.939 us; speedup vs baseline: 1.2833x; 1.0554x over previous
//
#include <hip/hip_runtime.h>

#define N_NODES 100000
#define G_NODES 50000
#define N_EDGES 800000
#define H 64
#define F_IN 32
#define MAX_DEG 20
#define NUM_GRAPHS 128
#define LN_EPS 1e-5f
#define POOL_BLOCKS 256
#define MAX_TILES 1600

// Binned CSR build parameters: 512 bins over the 4*N key space.
#define NBINS 512
#define BPB 782            // keys per bin: 782*512 = 400384 >= 400000
#define CHUNK 6250         // edges per build block: 6250*512 = 3.2M
#define MKEYS (4 * N_NODES)
#define MEDGES (4 * N_EDGES)

typedef __attribute__((ext_vector_type(8))) short short8;
typedef __attribute__((ext_vector_type(4))) float float4v;

// bf16 helpers (RNE), no header dependency
static __device__ __forceinline__ unsigned short f2b(float f) {
  unsigned u = __float_as_uint(f);
  return (unsigned short)((u + 0x7fffu + ((u >> 16) & 1u)) >> 16);
}
static __device__ __forceinline__ float b2f(unsigned short b) {
  return __uint_as_float(((unsigned)b) << 16);
}

// ---------------- embedding: h = x @ emb_w + emb_b ----------------
__global__ __launch_bounds__(256) void emb_kernel(
    const float* __restrict__ x, const float* __restrict__ w,
    const float* __restrict__ b, float* __restrict__ h,
    float* __restrict__ h0, unsigned short* __restrict__ hb) {
  int node = blockIdx.x * 4 + (threadIdx.x >> 6);
  int c = threadIdx.x & 63;
  if (node >= N_NODES) return;
  float xv = (c < F_IN) ? x[node * F_IN + c] : 0.0f;
  float acc = b[c];
#pragma unroll
  for (int f = 0; f < F_IN; ++f) {
    float xf = __shfl(xv, f, 64);
    acc = fmaf(xf, w[f * H + c], acc);
  }
  int idx = node * H + c;
  h[idx] = acc;
  h0[idx] = acc;
  hb[idx] = f2b(acc);
}

// ---------------- weight preconvert: wbt[jb][ch][k] bf16, k = [WL | WR] ----
__global__ __launch_bounds__(256) void wconv_kernel(
    const float* __restrict__ wl, const float* __restrict__ wr,
    unsigned short* __restrict__ wbt) {
  int i = blockIdx.x * 256 + threadIdx.x;  // 84*64*128 = 688128
  if (i >= 84 * 64 * 128) return;
  int k = i & 127;
  int ch = (i >> 7) & 63;
  int jb = i >> 13;
  float v = (k < 64) ? wl[jb * 4096 + k * 64 + ch]
                     : wr[jb * 4096 + (k - 64) * 64 + ch];
  wbt[i] = f2b(v);
}

// ---------------- binned CSR build (no scattered global atomics) ------------
__global__ __launch_bounds__(256) void p1_bincount(
    const int* __restrict__ e0, const int* __restrict__ e1,
    const int* __restrict__ e2, const int* __restrict__ e3,
    int* __restrict__ cntT) {
  __shared__ int hist[NBINS];
  int t = threadIdx.x, b = blockIdx.x;
  for (int i = t; i < NBINS; i += 256) hist[i] = 0;
  __syncthreads();
  int j = b >> 7;
  const int* ei = (j == 0) ? e0 : (j == 1) ? e1 : (j == 2) ? e2 : e3;
  int ebase = (b & 127) * CHUNK;
  for (int i = t; i < CHUNK; i += 256) {
    int dst = ei[N_EDGES + ebase + i];
    int key = j * N_NODES + dst;
    atomicAdd(&hist[key / BPB], 1);
  }
  __syncthreads();
  for (int i = t; i < NBINS; i += 256) cntT[i * NBINS + b] = hist[i];
}

__global__ __launch_bounds__(256) void p3_binscatter(
    const int* __restrict__ e0, const int* __restrict__ e1,
    const int* __restrict__ e2, const int* __restrict__ e3,
    const int* __restrict__ offT, unsigned* __restrict__ binned) {
  __shared__ int cur[NBINS];
  int t = threadIdx.x, b = blockIdx.x;
  for (int i = t; i < NBINS; i += 256) cur[i] = offT[i * NBINS + b];
  __syncthreads();
  int j = b >> 7;
  const int* ei = (j == 0) ? e0 : (j == 1) ? e1 : (j == 2) ? e2 : e3;
  int ebase = (b & 127) * CHUNK;
  for (int i = t; i < CHUNK; i += 256) {
    int src = ei[ebase + i];
    int dst = ei[N_EDGES + ebase + i];
    int key = j * N_NODES + dst;
    int bin = key / BPB;
    int pos = atomicAdd(&cur[bin], 1);
    binned[pos] = ((unsigned)(key - bin * BPB) << 17) | (unsigned)src;
  }
}

__global__ __launch_bounds__(256) void p4_deg(
    const unsigned* __restrict__ binned, const int* __restrict__ offT,
    int* __restrict__ deg4) {
  __shared__ int hist[BPB];
  int t = threadIdx.x, bin = blockIdx.x;
  for (int i = t; i < BPB; i += 256) hist[i] = 0;
  __syncthreads();
  int start = offT[bin * NBINS];
  int end = (bin == NBINS - 1) ? MEDGES : offT[(bin + 1) * NBINS];
  int kb = bin * BPB;
  for (int i = start + t; i < end; i += 256)
    atomicAdd(&hist[binned[i] >> 17], 1);
  __syncthreads();
  for (int i = t; i < BPB; i += 256)
    if (kb + i < MKEYS) deg4[kb + i] = hist[i];
}

__global__ __launch_bounds__(256) void p6_slots(
    const unsigned* __restrict__ binned, const int* __restrict__ offT,
    const int* __restrict__ S, int* __restrict__ slots) {
  __shared__ int cur[BPB];
  int t = threadIdx.x, bin = blockIdx.x;
  int kb = bin * BPB;
  for (int i = t; i < BPB; i += 256) cur[i] = (kb + i < MKEYS) ? S[kb + i] : 0;
  __syncthreads();
  int start = offT[bin * NBINS];
  int end = (bin == NBINS - 1) ? MEDGES : offT[(bin + 1) * NBINS];
  for (int i = start + t; i < end; i += 256) {
    unsigned v = binned[i];
    int pos = atomicAdd(&cur[v >> 17], 1);
    slots[pos] = (int)(v & 0x1ffffu);
  }
}

// ---------------- hierarchical exclusive scan (1024 elems/block) ------------
__global__ __launch_bounds__(256) void scan1(
    const int* __restrict__ in, int* __restrict__ S, int* __restrict__ bsum, int M) {
  int t = threadIdx.x;
  int base = blockIdx.x * 1024 + t * 4;
  int v0 = 0, v1 = 0, v2 = 0, v3 = 0;
  if (base + 3 < M) {
    int4 q = *(const int4*)(in + base);
    v0 = q.x; v1 = q.y; v2 = q.z; v3 = q.w;
  } else {
    if (base     < M) v0 = in[base];
    if (base + 1 < M) v1 = in[base + 1];
    if (base + 2 < M) v2 = in[base + 2];
    if (base + 3 < M) v3 = in[base + 3];
  }
  int s = v0 + v1 + v2 + v3;
  int incl = s;
#pragma unroll
  for (int off = 1; off < 64; off <<= 1) {
    int y = __shfl_up(incl, off, 64);
    if ((t & 63) >= off) incl += y;
  }
  __shared__ int wtot[4];
  if ((t & 63) == 63) wtot[t >> 6] = incl;
  __syncthreads();
  int wbase = 0;
  for (int w = 0; w < (t >> 6); ++w) wbase += wtot[w];
  int ex = wbase + incl - s;
  if (base < M) {
    int eo0 = ex, eo1 = ex + v0, eo2 = ex + v0 + v1, eo3 = ex + v0 + v1 + v2;
    if (base + 3 < M) {
      *(int4*)(S + base) = make_int4(eo0, eo1, eo2, eo3);
    } else {
      S[base] = eo0;
      if (base + 1 < M) S[base + 1] = eo1;
      if (base + 2 < M) S[base + 2] = eo2;
    }
  }
  if (t == 255) bsum[blockIdx.x] = wbase + incl;
}

__global__ __launch_bounds__(512) void scan2(int* __restrict__ bsum, int nb) {
  int t = threadIdx.x;
  int v = (t < nb) ? bsum[t] : 0;
  int incl = v;
#pragma unroll
  for (int off = 1; off < 64; off <<= 1) {
    int y = __shfl_up(incl, off, 64);
    if ((t & 63) >= off) incl += y;
  }
  __shared__ int wtot[8];
  if ((t & 63) == 63) wtot[t >> 6] = incl;
  __syncthreads();
  int wbase = 0;
  for (int w = 0; w < (t >> 6); ++w) wbase += wtot[w];
  if (t < nb) bsum[t] = wbase + incl - v;
}

__global__ __launch_bounds__(256) void scan3(
    int* __restrict__ S, const int* __restrict__ bsum, int M) {
  int i = blockIdx.x * 256 + threadIdx.x;
  if (i >= M) return;
  S[i] = S[i] + bsum[i >> 10];
}

// ---------------- degree-bucket lists (LDS-aggregated) ----------------------
__global__ __launch_bounds__(256) void bucket_count(
    const int* __restrict__ deg4, int* __restrict__ bcnt) {
  __shared__ int hist[21];
  int t = threadIdx.x;
  if (t < 21) hist[t] = 0;
  __syncthreads();
  int node = blockIdx.x * 256 + t;
  int j = blockIdx.y;
  if (node < N_NODES) {
    int d = deg4[j * N_NODES + node];
    int b = d < MAX_DEG ? d : MAX_DEG;
    atomicAdd(&hist[b], 1);
  }
  __syncthreads();
  if (t < 21 && hist[t]) atomicAdd(&bcnt[j * 21 + t], hist[t]);
}

__global__ __launch_bounds__(128) void bucket_scan(
    const int* __restrict__ bcnt, int* __restrict__ boff, int* __restrict__ bcur) {
  int t = threadIdx.x;
  int v = (t < 84) ? bcnt[t] : 0;
  int incl = v;
#pragma unroll
  for (int off = 1; off < 64; off <<= 1) {
    int y = __shfl_up(incl, off, 64);
    if ((t & 63) >= off) incl += y;
  }
  __shared__ int wt[2];
  if ((t & 63) == 63) wt[t >> 6] = incl;
  __syncthreads();
  int wbase = (t >> 6) ? wt[0] : 0;
  if (t < 84) {
    int ex = wbase + incl - v;
    boff[t] = ex;
    bcur[t] = ex;
  }
}

__global__ __launch_bounds__(256) void bucket_fill(
    const int* __restrict__ deg4, int* __restrict__ bcur, int* __restrict__ blist) {
  __shared__ int hist[21];
  __shared__ int base[21];
  int t = threadIdx.x;
  if (t < 21) hist[t] = 0;
  __syncthreads();
  int node = blockIdx.x * 256 + t;
  int j = blockIdx.y;
  int b = 0, lpos = 0;
  bool valid = (node < N_NODES);
  if (valid) {
    int d = deg4[j * N_NODES + node];
    b = d < MAX_DEG ? d : MAX_DEG;
    lpos = atomicAdd(&hist[b], 1);
  }
  __syncthreads();
  if (t < 21 && hist[t]) base[t] = atomicAdd(&bcur[j * 21 + t], hist[t]);
  __syncthreads();
  if (valid) blist[base[b] + lpos] = node;
}

// ---------------- tile descriptors: flat grid, no empty-block dispatch ------
// desc = (blist_pos << 12) | (bucket << 7) | nIn
__global__ __launch_bounds__(64) void tile_build(
    const int* __restrict__ bcnt, const int* __restrict__ boff,
    int* __restrict__ tdesc, int* __restrict__ ntiles) {
  int j = threadIdx.x;
  if (j >= 4) return;
  int t = 0;
  for (int b = 0; b < 21; ++b) {
    int cnt = bcnt[j * 21 + b], off = boff[j * 21 + b];
    for (int s = 0; s < cnt; s += 64) {
      int nIn = min(64, cnt - s);
      tdesc[j * MAX_TILES + t] = ((off + s) << 12) | (b << 7) | nIn;
      ++t;
    }
  }
  ntiles[j] = t;
}

// ---------------- gather: hsum[i] = sum_{j->i} hb16[j], bf16 rows -----------
__global__ __launch_bounds__(256) void gather_kernel(
    const int* __restrict__ S, const int* __restrict__ deg,
    const int* __restrict__ slots, const unsigned short* __restrict__ hb,
    unsigned short* __restrict__ hsum) {
  int node = blockIdx.x * 4 + (threadIdx.x >> 6);
  int c = threadIdx.x & 63;
  if (node >= N_NODES) return;
  int off = S[node];
  int dg = deg[node];
  float s0 = 0.f, s1 = 0.f, s2 = 0.f, s3 = 0.f;
  int e = 0;
  for (; e + 4 <= dg; e += 4) {
    int a0 = slots[off + e];
    int a1 = slots[off + e + 1];
    int a2 = slots[off + e + 2];
    int a3 = slots[off + e + 3];
    s0 += b2f(hb[a0 * H + c]);
    s1 += b2f(hb[a1 * H + c]);
    s2 += b2f(hb[a2 * H + c]);
    s3 += b2f(hb[a3 * H + c]);
  }
  for (; e < dg; ++e) s0 += b2f(hb[slots[off + e] * H + c]);
  hsum[node * H + c] = f2b((s0 + s1) + (s2 + s3));
}

// ---------------- MFMA transform: [64 x 128] @ [128 x 64] per tile ----------
// A = [hsum | hb] bf16 from LDS (stride 136 breaks pow2 banks); B = wbt bf16
// [ch][k] so B-frags are 16B contiguous; C/D fp32, transposed out via LDS.
__global__ __launch_bounds__(256) void transform_kernel(
    float* __restrict__ h, unsigned short* __restrict__ hb,
    const unsigned short* __restrict__ hsum,
    const int* __restrict__ blist, const int* __restrict__ tdesc,
    const int* __restrict__ ntiles, const unsigned short* __restrict__ wbt,
    const float* __restrict__ bl, int j, int do_relu) {
  if ((int)blockIdx.x >= ntiles[j]) return;
  int d = tdesc[j * MAX_TILES + blockIdx.x];
  int nIn = d & 127;
  int b = (d >> 7) & 31;
  const int* lst = blist + (d >> 12);

  int tid = threadIdx.x;
  int qw = tid >> 6, lane = tid & 63;

  if (b == 0) {
    // deg==0 masking: keep fp32 h exactly; ReLU still applies when j<3
    for (int r = qw * 16; r < qw * 16 + 16; ++r) {
      if (r < nIn) {
        int node = lst[r];
        float v = h[node * H + lane];
        if (do_relu) v = fmaxf(v, 0.f);
        h[node * H + lane] = v;
        hb[node * H + lane] = f2b(v);
      }
    }
    return;
  }

  __shared__ unsigned short aL[64 * 136];  // 17408 B; reused as fp32[64*68] out
  __shared__ int nodeS[64];

  // stage: row r = node, k<64 = hsum, k>=64 = self (raw bf16 bit copies)
  for (int r = qw * 16; r < qw * 16 + 16; ++r) {
    int node = (r < nIn) ? lst[r] : -1;
    if (lane == 0) nodeS[r] = node;
    unsigned short sv = 0, hv = 0;
    if (node >= 0) {
      sv = hsum[node * H + lane];
      hv = hb[node * H + lane];
    }
    aL[r * 136 + lane] = sv;
    aL[r * 136 + 64 + lane] = hv;
  }
  __syncthreads();

  int m = lane & 15, quad = lane >> 4;
  const unsigned short* wbase = wbt + (size_t)(j * 21 + b) * 64 * 128;
  float4v acc[4];
#pragma unroll
  for (int t = 0; t < 4; ++t) {
    float bv = bl[b * 64 + t * 16 + m];
    acc[t] = (float4v){bv, bv, bv, bv};
  }
#pragma unroll
  for (int ks = 0; ks < 4; ++ks) {
    short8 a = *(const short8*)&aL[(qw * 16 + m) * 136 + ks * 32 + quad * 8];
#pragma unroll
    for (int t = 0; t < 4; ++t) {
      short8 bf = *(const short8*)&wbase[(t * 16 + m) * 128 + ks * 32 + quad * 8];
      acc[t] = __builtin_amdgcn_mfma_f32_16x16x32_bf16(a, bf, acc[t], 0, 0, 0);
    }
  }
  if (do_relu) {
#pragma unroll
    for (int t = 0; t < 4; ++t)
#pragma unroll
      for (int r = 0; r < 4; ++r) acc[t][r] = fmaxf(acc[t][r], 0.f);
  }
  __syncthreads();  // all aL reads done before reuse as fp32 out tile
  float* outF = (float*)aL;
#pragma unroll
  for (int t = 0; t < 4; ++t)
#pragma unroll
    for (int r = 0; r < 4; ++r)
      outF[(qw * 16 + quad * 4 + r) * 68 + t * 16 + m] = acc[t][r];
  __syncthreads();
  for (int r = qw * 16; r < qw * 16 + 16; ++r) {
    if (r < nIn) {
      int node = nodeS[r];
      float v = outF[r * 68 + lane];
      h[node * H + lane] = v;
      hb[node * H + lane] = f2b(v);
    }
  }
}

// ---------------- layernorm + residual ----------------
__global__ __launch_bounds__(256) void ln_kernel(
    float* __restrict__ h, const float* __restrict__ h0,
    const float* __restrict__ g, const float* __restrict__ b) {
  int node = blockIdx.x * 4 + (threadIdx.x >> 6);
  int c = threadIdx.x & 63;
  if (node >= N_NODES) return;
  int idx = node * H + c;
  float v = h[idx];
  float s = v;
#pragma unroll
  for (int off = 32; off > 0; off >>= 1) s += __shfl_xor(s, off, 64);
  float mu = s * (1.0f / H);
  float dv = v - mu;
  float q = dv * dv;
#pragma unroll
  for (int off = 32; off > 0; off >>= 1) q += __shfl_xor(q, off, 64);
  float inv = rsqrtf(q * (1.0f / H) + LN_EPS);
  h[idx] = dv * inv * g[c] + b[c] + h0[idx];
}

// ---------------- pool: LDS-aggregated, 256 blocks ----------------
__global__ __launch_bounds__(256) void pool_kernel(
    const float* __restrict__ h, const int* __restrict__ batch,
    float* __restrict__ pooled) {
  __shared__ float sm[NUM_GRAPHS * H];  // 32 KB
  int t = threadIdx.x;
  for (int i = t; i < NUM_GRAPHS * H; i += 256) sm[i] = 0.f;
  __syncthreads();
  int lane = t & 63, w = t >> 6;
  const int per = (G_NODES + POOL_BLOCKS - 1) / POOL_BLOCKS;
  int start = blockIdx.x * per;
  int end = min(start + per, G_NODES);
  for (int node = start + w; node < end; node += 4) {
    int g = batch[node];
    atomicAdd(&sm[g * H + lane], h[node * H + lane]);
  }
  __syncthreads();
  for (int i = t; i < NUM_GRAPHS * H; i += 256) {
    float v = sm[i];
    if (v != 0.f) atomicAdd(&pooled[i], v);
  }
}

__global__ __launch_bounds__(64) void out_kernel(
    const float* __restrict__ pooled, const float* __restrict__ w,
    const float* __restrict__ b, float* __restrict__ out) {
  int gph = blockIdx.x;
  int c = threadIdx.x;
  float v = pooled[gph * H + c] * w[c];
#pragma unroll
  for (int off = 32; off > 0; off >>= 1) v += __shfl_xor(v, off, 64);
  if (c == 0) out[gph] = v + b[0];
}

extern "C" void kernel_launch(void* const* d_in, const int* in_sizes, int n_in,
                              void* d_out, int out_size, void* d_ws, size_t ws_size,
                              hipStream_t stream) {
  const float* x       = (const float*)d_in[0];
  const int*   ei_edge = (const int*)d_in[1];
  const int*   ei_sub  = (const int*)d_in[2];
  const int*   ei_ns   = (const int*)d_in[3];
  const int*   ei_sn   = (const int*)d_in[4];
  const int*   batch   = (const int*)d_in[7];
  const float* emb_w   = (const float*)d_in[8];
  const float* emb_b   = (const float*)d_in[9];
  const float* conv_wl = (const float*)d_in[10];
  const float* conv_bl = (const float*)d_in[11];
  const float* conv_wr = (const float*)d_in[12];
  const float* ln_g    = (const float*)d_in[13];
  const float* ln_b    = (const float*)d_in[14];
  const float* out_w   = (const float*)d_in[15];
  const float* out_b   = (const float*)d_in[16];
  float* out = (float*)d_out;

  const size_t HB = (size_t)N_NODES * H * sizeof(float);   // 25.6 MB
  const size_t HB2 = (size_t)N_NODES * H * sizeof(short);  // 12.8 MB
  char* ws = (char*)d_ws;
  float* h      = (float*)(ws);
  float* h0     = (float*)(ws + HB);
  unsigned short* hsum = (unsigned short*)(ws + 2 * HB);        // 12.8 MB
  unsigned short* hb16 = (unsigned short*)(ws + 2 * HB + HB2);  // 12.8 MB
  // Build-phase overlays (dead once emb_kernel runs):
  unsigned* binned = (unsigned*)(ws);                            // 12.8 MB on h
  int*   cntT   = (int*)(ws + HB);                               // 1 MB on h0
  int*   offT   = (int*)(ws + HB + 0x100000);                    // 1 MB
  int*   bsumA  = (int*)(ws + HB + 0x300000);                    // 2 KB
  // Persistent:
  int*   deg4   = (int*)(ws + 3 * HB);                           // 1.6 MB
  int*   S      = (int*)(ws + 78400000);                         // 1.6 MB
  int*   slots  = (int*)(ws + 80000000);                         // 12.8 MB
  int*   bcnt   = (int*)(ws + 92800000);
  int*   boff   = (int*)(ws + 92800512);
  int*   bcur   = (int*)(ws + 92801024);
  int*   blist  = (int*)(ws + 92801536);                         // 1.6 MB
  float* pooled = (float*)(ws + 94401536);                       // 32 KB
  unsigned short* wbt = (unsigned short*)(ws + 94434304);        // 1.38 MB
  int*   tdesc  = (int*)(ws + 95810560);                         // 25.6 KB
  int*   ntiles = (int*)(ws + 95836160);                         // 16 B

  const int* e0 = ei_edge, *e1 = ei_ns, *e2 = ei_sub, *e3 = ei_sn;
  const int MC = NBINS * NBINS;
  const int NB_MC = MC / 1024;              // 256
  const int NB_MK = (MKEYS + 1023) / 1024;  // 391

  hipMemsetAsync(bcnt, 0, 512, stream);

  // --- binned CSR build ---
  p1_bincount<<<NBINS, 256, 0, stream>>>(e0, e1, e2, e3, cntT);
  scan1<<<NB_MC, 256, 0, stream>>>(cntT, offT, bsumA, MC);
  scan2<<<1, 512, 0, stream>>>(bsumA, NB_MC);
  scan3<<<MC / 256, 256, 0, stream>>>(offT, bsumA, MC);
  p3_binscatter<<<NBINS, 256, 0, stream>>>(e0, e1, e2, e3, offT, binned);
  p4_deg<<<NBINS, 256, 0, stream>>>(binned, offT, deg4);
  scan1<<<NB_MK, 256, 0, stream>>>(deg4, S, bsumA, MKEYS);
  scan2<<<1, 512, 0, stream>>>(bsumA, NB_MK);
  scan3<<<(MKEYS + 255) / 256, 256, 0, stream>>>(S, bsumA, MKEYS);
  p6_slots<<<NBINS, 256, 0, stream>>>(binned, offT, S, slots);

  bucket_count<<<dim3((N_NODES + 255) / 256, 4), 256, 0, stream>>>(deg4, bcnt);
  bucket_scan<<<1, 128, 0, stream>>>(bcnt, boff, bcur);
  bucket_fill<<<dim3((N_NODES + 255) / 256, 4), 256, 0, stream>>>(deg4, bcur, blist);
  tile_build<<<1, 64, 0, stream>>>(bcnt, boff, tdesc, ntiles);
  wconv_kernel<<<(84 * 64 * 128 + 255) / 256, 256, 0, stream>>>(conv_wl, conv_wr, wbt);

  // --- network ---
  emb_kernel<<<(N_NODES + 3) / 4, 256, 0, stream>>>(x, emb_w, emb_b, h, h0, hb16);

  for (int j = 0; j < 4; ++j) {
    gather_kernel<<<(N_NODES + 3) / 4, 256, 0, stream>>>(
        S + j * N_NODES, deg4 + j * N_NODES, slots, hb16, hsum);
    transform_kernel<<<MAX_TILES, 256, 0, stream>>>(
        h, hb16, hsum, blist, tdesc, ntiles, wbt,
        conv_bl + (size_t)j * 21 * H, j, j < 3 ? 1 : 0);
  }

  ln_kernel<<<(N_NODES + 3) / 4, 256, 0, stream>>>(h, h0, ln_g, ln_b);

  hipMemsetAsync(pooled, 0, NUM_GRAPHS * H * sizeof(float), stream);
  pool_kernel<<<POOL_BLOCKS, 256, 0, stream>>>(h, batch, pooled);
  out_kernel<<<NUM_GRAPHS, 64, 0, stream>>>(pooled, out_w, out_b, out);
}

// Round 9
// 622.775 us; speedup vs baseline: 1.3557x; 1.0565x over previous
//
#include <hip/hip_runtime.h>

#define N_NODES 100000
#define G_NODES 50000
#define N_EDGES 800000
#define H 64
#define F_IN 32
#define MAX_DEG 20
#define NUM_GRAPHS 128
#define LN_EPS 1e-5f
#define POOL_BLOCKS 256
#define MAX_TILES 1600

// Binned CSR build parameters: 512 bins over the 4*N key space.
#define NBINS 512
#define BPB 782            // keys per bin: 782*512 = 400384 >= 400000
#define CHUNK 6250         // edges per build block: 6250*512 = 3.2M
#define MKEYS (4 * N_NODES)
#define MEDGES (4 * N_EDGES)

typedef __attribute__((ext_vector_type(8))) short short8;
typedef __attribute__((ext_vector_type(4))) float float4v;

// bf16 helpers (RNE), no header dependency
static __device__ __forceinline__ unsigned short f2b(float f) {
  unsigned u = __float_as_uint(f);
  return (unsigned short)((u + 0x7fffu + ((u >> 16) & 1u)) >> 16);
}
static __device__ __forceinline__ float b2f(unsigned short b) {
  return __uint_as_float(((unsigned)b) << 16);
}

// ---------------- embedding: h = x @ emb_w + emb_b ----------------
__global__ __launch_bounds__(256) void emb_kernel(
    const float* __restrict__ x, const float* __restrict__ w,
    const float* __restrict__ b, float* __restrict__ h,
    float* __restrict__ h0, unsigned short* __restrict__ hb) {
  int node = blockIdx.x * 4 + (threadIdx.x >> 6);
  int c = threadIdx.x & 63;
  if (node >= N_NODES) return;
  float xv = (c < F_IN) ? x[node * F_IN + c] : 0.0f;
  float acc = b[c];
#pragma unroll
  for (int f = 0; f < F_IN; ++f) {
    float xf = __shfl(xv, f, 64);
    acc = fmaf(xf, w[f * H + c], acc);
  }
  int idx = node * H + c;
  h[idx] = acc;
  h0[idx] = acc;
  hb[idx] = f2b(acc);
}

// ---------------- weight preconvert: wbt[jb][ch][k] bf16, k = [WL | WR] ----
__global__ __launch_bounds__(256) void wconv_kernel(
    const float* __restrict__ wl, const float* __restrict__ wr,
    unsigned short* __restrict__ wbt) {
  int i = blockIdx.x * 256 + threadIdx.x;  // 84*64*128 = 688128
  if (i >= 84 * 64 * 128) return;
  int k = i & 127;
  int ch = (i >> 7) & 63;
  int jb = i >> 13;
  float v = (k < 64) ? wl[jb * 4096 + k * 64 + ch]
                     : wr[jb * 4096 + (k - 64) * 64 + ch];
  wbt[i] = f2b(v);
}

// ---------------- binned CSR build (no scattered global atomics) ------------
__global__ __launch_bounds__(256) void p1_bincount(
    const int* __restrict__ e0, const int* __restrict__ e1,
    const int* __restrict__ e2, const int* __restrict__ e3,
    int* __restrict__ cntT) {
  __shared__ int hist[NBINS];
  int t = threadIdx.x, b = blockIdx.x;
  for (int i = t; i < NBINS; i += 256) hist[i] = 0;
  __syncthreads();
  int j = b >> 7;
  const int* ei = (j == 0) ? e0 : (j == 1) ? e1 : (j == 2) ? e2 : e3;
  int ebase = (b & 127) * CHUNK;
  for (int i = t; i < CHUNK; i += 256) {
    int dst = ei[N_EDGES + ebase + i];
    int key = j * N_NODES + dst;
    atomicAdd(&hist[key / BPB], 1);
  }
  __syncthreads();
  for (int i = t; i < NBINS; i += 256) cntT[i * NBINS + b] = hist[i];
}

__global__ __launch_bounds__(256) void p3_binscatter(
    const int* __restrict__ e0, const int* __restrict__ e1,
    const int* __restrict__ e2, const int* __restrict__ e3,
    const int* __restrict__ offT, unsigned* __restrict__ binned) {
  __shared__ int cur[NBINS];
  int t = threadIdx.x, b = blockIdx.x;
  for (int i = t; i < NBINS; i += 256) cur[i] = offT[i * NBINS + b];
  __syncthreads();
  int j = b >> 7;
  const int* ei = (j == 0) ? e0 : (j == 1) ? e1 : (j == 2) ? e2 : e3;
  int ebase = (b & 127) * CHUNK;
  for (int i = t; i < CHUNK; i += 256) {
    int src = ei[ebase + i];
    int dst = ei[N_EDGES + ebase + i];
    int key = j * N_NODES + dst;
    int bin = key / BPB;
    int pos = atomicAdd(&cur[bin], 1);
    binned[pos] = ((unsigned)(key - bin * BPB) << 17) | (unsigned)src;
  }
}

__global__ __launch_bounds__(256) void p4_deg(
    const unsigned* __restrict__ binned, const int* __restrict__ offT,
    int* __restrict__ deg4) {
  __shared__ int hist[BPB];
  int t = threadIdx.x, bin = blockIdx.x;
  for (int i = t; i < BPB; i += 256) hist[i] = 0;
  __syncthreads();
  int start = offT[bin * NBINS];
  int end = (bin == NBINS - 1) ? MEDGES : offT[(bin + 1) * NBINS];
  int kb = bin * BPB;
  for (int i = start + t; i < end; i += 256)
    atomicAdd(&hist[binned[i] >> 17], 1);
  __syncthreads();
  for (int i = t; i < BPB; i += 256)
    if (kb + i < MKEYS) deg4[kb + i] = hist[i];
}

__global__ __launch_bounds__(256) void p6_slots(
    const unsigned* __restrict__ binned, const int* __restrict__ offT,
    const int* __restrict__ S, int* __restrict__ slots) {
  __shared__ int cur[BPB];
  int t = threadIdx.x, bin = blockIdx.x;
  int kb = bin * BPB;
  for (int i = t; i < BPB; i += 256) cur[i] = (kb + i < MKEYS) ? S[kb + i] : 0;
  __syncthreads();
  int start = offT[bin * NBINS];
  int end = (bin == NBINS - 1) ? MEDGES : offT[(bin + 1) * NBINS];
  for (int i = start + t; i < end; i += 256) {
    unsigned v = binned[i];
    int pos = atomicAdd(&cur[v >> 17], 1);
    slots[pos] = (int)(v & 0x1ffffu);
  }
}

// ---------------- hierarchical exclusive scan (1024 elems/block) ------------
__global__ __launch_bounds__(256) void scan1(
    const int* __restrict__ in, int* __restrict__ S, int* __restrict__ bsum, int M) {
  int t = threadIdx.x;
  int base = blockIdx.x * 1024 + t * 4;
  int v0 = 0, v1 = 0, v2 = 0, v3 = 0;
  if (base + 3 < M) {
    int4 q = *(const int4*)(in + base);
    v0 = q.x; v1 = q.y; v2 = q.z; v3 = q.w;
  } else {
    if (base     < M) v0 = in[base];
    if (base + 1 < M) v1 = in[base + 1];
    if (base + 2 < M) v2 = in[base + 2];
    if (base + 3 < M) v3 = in[base + 3];
  }
  int s = v0 + v1 + v2 + v3;
  int incl = s;
#pragma unroll
  for (int off = 1; off < 64; off <<= 1) {
    int y = __shfl_up(incl, off, 64);
    if ((t & 63) >= off) incl += y;
  }
  __shared__ int wtot[4];
  if ((t & 63) == 63) wtot[t >> 6] = incl;
  __syncthreads();
  int wbase = 0;
  for (int w = 0; w < (t >> 6); ++w) wbase += wtot[w];
  int ex = wbase + incl - s;
  if (base < M) {
    int eo0 = ex, eo1 = ex + v0, eo2 = ex + v0 + v1, eo3 = ex + v0 + v1 + v2;
    if (base + 3 < M) {
      *(int4*)(S + base) = make_int4(eo0, eo1, eo2, eo3);
    } else {
      S[base] = eo0;
      if (base + 1 < M) S[base + 1] = eo1;
      if (base + 2 < M) S[base + 2] = eo2;
    }
  }
  if (t == 255) bsum[blockIdx.x] = wbase + incl;
}

__global__ __launch_bounds__(512) void scan2(int* __restrict__ bsum, int nb) {
  int t = threadIdx.x;
  int v = (t < nb) ? bsum[t] : 0;
  int incl = v;
#pragma unroll
  for (int off = 1; off < 64; off <<= 1) {
    int y = __shfl_up(incl, off, 64);
    if ((t & 63) >= off) incl += y;
  }
  __shared__ int wtot[8];
  if ((t & 63) == 63) wtot[t >> 6] = incl;
  __syncthreads();
  int wbase = 0;
  for (int w = 0; w < (t >> 6); ++w) wbase += wtot[w];
  if (t < nb) bsum[t] = wbase + incl - v;
}

__global__ __launch_bounds__(256) void scan3(
    int* __restrict__ S, const int* __restrict__ bsum, int M) {
  int i = blockIdx.x * 256 + threadIdx.x;
  if (i >= M) return;
  S[i] = S[i] + bsum[i >> 10];
}

// ---------------- degree-bucket lists (LDS-aggregated) ----------------------
__global__ __launch_bounds__(256) void bucket_count(
    const int* __restrict__ deg4, int* __restrict__ bcnt) {
  __shared__ int hist[21];
  int t = threadIdx.x;
  if (t < 21) hist[t] = 0;
  __syncthreads();
  int node = blockIdx.x * 256 + t;
  int j = blockIdx.y;
  if (node < N_NODES) {
    int d = deg4[j * N_NODES + node];
    int b = d < MAX_DEG ? d : MAX_DEG;
    atomicAdd(&hist[b], 1);
  }
  __syncthreads();
  if (t < 21 && hist[t]) atomicAdd(&bcnt[j * 21 + t], hist[t]);
}

__global__ __launch_bounds__(128) void bucket_scan(
    const int* __restrict__ bcnt, int* __restrict__ boff, int* __restrict__ bcur) {
  int t = threadIdx.x;
  int v = (t < 84) ? bcnt[t] : 0;
  int incl = v;
#pragma unroll
  for (int off = 1; off < 64; off <<= 1) {
    int y = __shfl_up(incl, off, 64);
    if ((t & 63) >= off) incl += y;
  }
  __shared__ int wt[2];
  if ((t & 63) == 63) wt[t >> 6] = incl;
  __syncthreads();
  int wbase = (t >> 6) ? wt[0] : 0;
  if (t < 84) {
    int ex = wbase + incl - v;
    boff[t] = ex;
    bcur[t] = ex;
  }
}

__global__ __launch_bounds__(256) void bucket_fill(
    const int* __restrict__ deg4, int* __restrict__ bcur, int* __restrict__ blist) {
  __shared__ int hist[21];
  __shared__ int base[21];
  int t = threadIdx.x;
  if (t < 21) hist[t] = 0;
  __syncthreads();
  int node = blockIdx.x * 256 + t;
  int j = blockIdx.y;
  int b = 0, lpos = 0;
  bool valid = (node < N_NODES);
  if (valid) {
    int d = deg4[j * N_NODES + node];
    b = d < MAX_DEG ? d : MAX_DEG;
    lpos = atomicAdd(&hist[b], 1);
  }
  __syncthreads();
  if (t < 21 && hist[t]) base[t] = atomicAdd(&bcur[j * 21 + t], hist[t]);
  __syncthreads();
  if (valid) blist[base[b] + lpos] = node;
}

// ---------------- tile descriptors (R8: 4-thread serial build was 54.7us) ---
// tile_count: per-bucket tile counts + segmented prefix -> toff, ntiles.
__global__ __launch_bounds__(128) void tile_count(
    const int* __restrict__ bcnt, int* __restrict__ toff, int* __restrict__ ntiles) {
  __shared__ int nt[84];
  int t = threadIdx.x;
  if (t < 84) nt[t] = (bcnt[t] + 63) >> 6;
  __syncthreads();
  if (t < 4) {
    int acc = 0;
    for (int b = 0; b < 21; ++b) {
      toff[t * 21 + b] = acc;
      acc += nt[t * 21 + b];
    }
    ntiles[t] = acc;
  }
}

// tile_fill: one block per (j,b); descriptors written in parallel, coalesced.
// desc = (blist_pos << 12) | (bucket << 7) | nIn
__global__ __launch_bounds__(256) void tile_fill(
    const int* __restrict__ bcnt, const int* __restrict__ boff,
    const int* __restrict__ toff, int* __restrict__ tdesc) {
  int jb = blockIdx.x;           // 0..83
  int j = jb / 21, b = jb % 21;
  int cnt = bcnt[jb];
  int off = boff[jb];
  int tb = toff[jb];
  int nt = (cnt + 63) >> 6;
  for (int i = threadIdx.x; i < nt; i += 256) {
    int s = i << 6;
    int nIn = min(64, cnt - s);
    tdesc[j * MAX_TILES + tb + i] = ((off + s) << 12) | (b << 7) | nIn;
  }
}

// ---------------- gather: hsum[i] = sum_{j->i} hb16[j], bf16 rows -----------
__global__ __launch_bounds__(256) void gather_kernel(
    const int* __restrict__ S, const int* __restrict__ deg,
    const int* __restrict__ slots, const unsigned short* __restrict__ hb,
    unsigned short* __restrict__ hsum) {
  int node = blockIdx.x * 4 + (threadIdx.x >> 6);
  int c = threadIdx.x & 63;
  if (node >= N_NODES) return;
  int off = S[node];
  int dg = deg[node];
  float s0 = 0.f, s1 = 0.f, s2 = 0.f, s3 = 0.f;
  int e = 0;
  for (; e + 4 <= dg; e += 4) {
    int a0 = slots[off + e];
    int a1 = slots[off + e + 1];
    int a2 = slots[off + e + 2];
    int a3 = slots[off + e + 3];
    s0 += b2f(hb[a0 * H + c]);
    s1 += b2f(hb[a1 * H + c]);
    s2 += b2f(hb[a2 * H + c]);
    s3 += b2f(hb[a3 * H + c]);
  }
  for (; e < dg; ++e) s0 += b2f(hb[slots[off + e] * H + c]);
  hsum[node * H + c] = f2b((s0 + s1) + (s2 + s3));
}

// ---------------- MFMA transform: [64 x 128] @ [128 x 64] per tile ----------
__global__ __launch_bounds__(256) void transform_kernel(
    float* __restrict__ h, unsigned short* __restrict__ hb,
    const unsigned short* __restrict__ hsum,
    const int* __restrict__ blist, const int* __restrict__ tdesc,
    const int* __restrict__ ntiles, const unsigned short* __restrict__ wbt,
    const float* __restrict__ bl, int j, int do_relu) {
  if ((int)blockIdx.x >= ntiles[j]) return;
  int d = tdesc[j * MAX_TILES + blockIdx.x];
  int nIn = d & 127;
  int b = (d >> 7) & 31;
  const int* lst = blist + (d >> 12);

  int tid = threadIdx.x;
  int qw = tid >> 6, lane = tid & 63;

  if (b == 0) {
    for (int r = qw * 16; r < qw * 16 + 16; ++r) {
      if (r < nIn) {
        int node = lst[r];
        float v = h[node * H + lane];
        if (do_relu) v = fmaxf(v, 0.f);
        h[node * H + lane] = v;
        hb[node * H + lane] = f2b(v);
      }
    }
    return;
  }

  __shared__ unsigned short aL[64 * 136];  // 17408 B; reused as fp32[64*68] out
  __shared__ int nodeS[64];

  for (int r = qw * 16; r < qw * 16 + 16; ++r) {
    int node = (r < nIn) ? lst[r] : -1;
    if (lane == 0) nodeS[r] = node;
    unsigned short sv = 0, hv = 0;
    if (node >= 0) {
      sv = hsum[node * H + lane];
      hv = hb[node * H + lane];
    }
    aL[r * 136 + lane] = sv;
    aL[r * 136 + 64 + lane] = hv;
  }
  __syncthreads();

  int m = lane & 15, quad = lane >> 4;
  const unsigned short* wbase = wbt + (size_t)(j * 21 + b) * 64 * 128;
  float4v acc[4];
#pragma unroll
  for (int t = 0; t < 4; ++t) {
    float bv = bl[b * 64 + t * 16 + m];
    acc[t] = (float4v){bv, bv, bv, bv};
  }
#pragma unroll
  for (int ks = 0; ks < 4; ++ks) {
    short8 a = *(const short8*)&aL[(qw * 16 + m) * 136 + ks * 32 + quad * 8];
#pragma unroll
    for (int t = 0; t < 4; ++t) {
      short8 bf = *(const short8*)&wbase[(t * 16 + m) * 128 + ks * 32 + quad * 8];
      acc[t] = __builtin_amdgcn_mfma_f32_16x16x32_bf16(a, bf, acc[t], 0, 0, 0);
    }
  }
  if (do_relu) {
#pragma unroll
    for (int t = 0; t < 4; ++t)
#pragma unroll
      for (int r = 0; r < 4; ++r) acc[t][r] = fmaxf(acc[t][r], 0.f);
  }
  __syncthreads();
  float* outF = (float*)aL;
#pragma unroll
  for (int t = 0; t < 4; ++t)
#pragma unroll
    for (int r = 0; r < 4; ++r)
      outF[(qw * 16 + quad * 4 + r) * 68 + t * 16 + m] = acc[t][r];
  __syncthreads();
  for (int r = qw * 16; r < qw * 16 + 16; ++r) {
    if (r < nIn) {
      int node = nodeS[r];
      float v = outF[r * 68 + lane];
      h[node * H + lane] = v;
      hb[node * H + lane] = f2b(v);
    }
  }
}

// ---------------- layernorm + residual ----------------
__global__ __launch_bounds__(256) void ln_kernel(
    float* __restrict__ h, const float* __restrict__ h0,
    const float* __restrict__ g, const float* __restrict__ b) {
  int node = blockIdx.x * 4 + (threadIdx.x >> 6);
  int c = threadIdx.x & 63;
  if (node >= N_NODES) return;
  int idx = node * H + c;
  float v = h[idx];
  float s = v;
#pragma unroll
  for (int off = 32; off > 0; off >>= 1) s += __shfl_xor(s, off, 64);
  float mu = s * (1.0f / H);
  float dv = v - mu;
  float q = dv * dv;
#pragma unroll
  for (int off = 32; off > 0; off >>= 1) q += __shfl_xor(q, off, 64);
  float inv = rsqrtf(q * (1.0f / H) + LN_EPS);
  h[idx] = dv * inv * g[c] + b[c] + h0[idx];
}

// ---------------- pool: LDS-aggregated, 256 blocks ----------------
__global__ __launch_bounds__(256) void pool_kernel(
    const float* __restrict__ h, const int* __restrict__ batch,
    float* __restrict__ pooled) {
  __shared__ float sm[NUM_GRAPHS * H];  // 32 KB
  int t = threadIdx.x;
  for (int i = t; i < NUM_GRAPHS * H; i += 256) sm[i] = 0.f;
  __syncthreads();
  int lane = t & 63, w = t >> 6;
  const int per = (G_NODES + POOL_BLOCKS - 1) / POOL_BLOCKS;
  int start = blockIdx.x * per;
  int end = min(start + per, G_NODES);
  for (int node = start + w; node < end; node += 4) {
    int g = batch[node];
    atomicAdd(&sm[g * H + lane], h[node * H + lane]);
  }
  __syncthreads();
  for (int i = t; i < NUM_GRAPHS * H; i += 256) {
    float v = sm[i];
    if (v != 0.f) atomicAdd(&pooled[i], v);
  }
}

__global__ __launch_bounds__(64) void out_kernel(
    const float* __restrict__ pooled, const float* __restrict__ w,
    const float* __restrict__ b, float* __restrict__ out) {
  int gph = blockIdx.x;
  int c = threadIdx.x;
  float v = pooled[gph * H + c] * w[c];
#pragma unroll
  for (int off = 32; off > 0; off >>= 1) v += __shfl_xor(v, off, 64);
  if (c == 0) out[gph] = v + b[0];
}

extern "C" void kernel_launch(void* const* d_in, const int* in_sizes, int n_in,
                              void* d_out, int out_size, void* d_ws, size_t ws_size,
                              hipStream_t stream) {
  const float* x       = (const float*)d_in[0];
  const int*   ei_edge = (const int*)d_in[1];
  const int*   ei_sub  = (const int*)d_in[2];
  const int*   ei_ns   = (const int*)d_in[3];
  const int*   ei_sn   = (const int*)d_in[4];
  const int*   batch   = (const int*)d_in[7];
  const float* emb_w   = (const float*)d_in[8];
  const float* emb_b   = (const float*)d_in[9];
  const float* conv_wl = (const float*)d_in[10];
  const float* conv_bl = (const float*)d_in[11];
  const float* conv_wr = (const float*)d_in[12];
  const float* ln_g    = (const float*)d_in[13];
  const float* ln_b    = (const float*)d_in[14];
  const float* out_w   = (const float*)d_in[15];
  const float* out_b   = (const float*)d_in[16];
  float* out = (float*)d_out;

  const size_t HB = (size_t)N_NODES * H * sizeof(float);   // 25.6 MB
  const size_t HB2 = (size_t)N_NODES * H * sizeof(short);  // 12.8 MB
  char* ws = (char*)d_ws;
  float* h      = (float*)(ws);
  float* h0     = (float*)(ws + HB);
  unsigned short* hsum = (unsigned short*)(ws + 2 * HB);        // 12.8 MB
  unsigned short* hb16 = (unsigned short*)(ws + 2 * HB + HB2);  // 12.8 MB
  // Build-phase overlays (dead once emb_kernel runs):
  unsigned* binned = (unsigned*)(ws);                            // 12.8 MB on h
  int*   cntT   = (int*)(ws + HB);                               // 1 MB on h0
  int*   offT   = (int*)(ws + HB + 0x100000);                    // 1 MB
  int*   bsumA  = (int*)(ws + HB + 0x300000);                    // 2 KB
  // Persistent:
  int*   deg4   = (int*)(ws + 3 * HB);                           // 1.6 MB
  int*   S      = (int*)(ws + 78400000);                         // 1.6 MB
  int*   slots  = (int*)(ws + 80000000);                         // 12.8 MB
  int*   bcnt   = (int*)(ws + 92800000);
  int*   boff   = (int*)(ws + 92800512);
  int*   bcur   = (int*)(ws + 92801024);
  int*   blist  = (int*)(ws + 92801536);                         // 1.6 MB
  float* pooled = (float*)(ws + 94401536);                       // 32 KB
  unsigned short* wbt = (unsigned short*)(ws + 94434304);        // 1.38 MB
  int*   tdesc  = (int*)(ws + 95810560);                         // 25.6 KB
  int*   ntiles = (int*)(ws + 95836160);                         // 16 B
  int*   toff   = (int*)(ws + 95836224);                         // 336 B

  const int* e0 = ei_edge, *e1 = ei_ns, *e2 = ei_sub, *e3 = ei_sn;
  const int MC = NBINS * NBINS;
  const int NB_MC = MC / 1024;              // 256
  const int NB_MK = (MKEYS + 1023) / 1024;  // 391

  hipMemsetAsync(bcnt, 0, 512, stream);

  // --- binned CSR build ---
  p1_bincount<<<NBINS, 256, 0, stream>>>(e0, e1, e2, e3, cntT);
  scan1<<<NB_MC, 256, 0, stream>>>(cntT, offT, bsumA, MC);
  scan2<<<1, 512, 0, stream>>>(bsumA, NB_MC);
  scan3<<<MC / 256, 256, 0, stream>>>(offT, bsumA, MC);
  p3_binscatter<<<NBINS, 256, 0, stream>>>(e0, e1, e2, e3, offT, binned);
  p4_deg<<<NBINS, 256, 0, stream>>>(binned, offT, deg4);
  scan1<<<NB_MK, 256, 0, stream>>>(deg4, S, bsumA, MKEYS);
  scan2<<<1, 512, 0, stream>>>(bsumA, NB_MK);
  scan3<<<(MKEYS + 255) / 256, 256, 0, stream>>>(S, bsumA, MKEYS);
  p6_slots<<<NBINS, 256, 0, stream>>>(binned, offT, S, slots);

  bucket_count<<<dim3((N_NODES + 255) / 256, 4), 256, 0, stream>>>(deg4, bcnt);
  bucket_scan<<<1, 128, 0, stream>>>(bcnt, boff, bcur);
  bucket_fill<<<dim3((N_NODES + 255) / 256, 4), 256, 0, stream>>>(deg4, bcur, blist);
  tile_count<<<1, 128, 0, stream>>>(bcnt, toff, ntiles);
  tile_fill<<<84, 256, 0, stream>>>(bcnt, boff, toff, tdesc);
  wconv_kernel<<<(84 * 64 * 128 + 255) / 256, 256, 0, stream>>>(conv_wl, conv_wr, wbt);

  // --- network ---
  emb_kernel<<<(N_NODES + 3) / 4, 256, 0, stream>>>(x, emb_w, emb_b, h, h0, hb16);

  for (int j = 0; j < 4; ++j) {
    gather_kernel<<<(N_NODES + 3) / 4, 256, 0, stream>>>(
        S + j * N_NODES, deg4 + j * N_NODES, slots, hb16, hsum);
    transform_kernel<<<MAX_TILES, 256, 0, stream>>>(
        h, hb16, hsum, blist, tdesc, ntiles, wbt,
        conv_bl + (size_t)j * 21 * H, j, j < 3 ? 1 : 0);
  }

  ln_kernel<<<(N_NODES + 3) / 4, 256, 0, stream>>>(h, h0, ln_g, ln_b);

  hipMemsetAsync(pooled, 0, NUM_GRAPHS * H * sizeof(float), stream);
  pool_kernel<<<POOL_BLOCKS, 256, 0, stream>>>(h, batch, pooled);
  out_kernel<<<NUM_GRAPHS, 64, 0, stream>>>(pooled, out_w, out_b, out);
}

// Round 10
// 575.419 us; speedup vs baseline: 1.4673x; 1.0823x over previous
//
#include <hip/hip_runtime.h>

#define N_NODES 100000
#define G_NODES 50000
#define N_EDGES 800000
#define H 64
#define F_IN 32
#define MAX_DEG 20
#define NUM_GRAPHS 128
#define LN_EPS 1e-5f
#define POOL_BLOCKS 256
#define MAX_TILES 1600

// Binned CSR build parameters: 512 bins over the 4*N key space.
#define NBINS 512
#define BPB 782            // keys per bin: 782*512 = 400384 >= 400000
#define CHUNK 6250         // edges per build block: 6250*512 = 3.2M
#define MKEYS (4 * N_NODES)
#define MEDGES (4 * N_EDGES)

typedef __attribute__((ext_vector_type(8))) short short8;
typedef __attribute__((ext_vector_type(4))) float float4v;

// bf16 helpers (RNE), no header dependency
static __device__ __forceinline__ unsigned short f2b(float f) {
  unsigned u = __float_as_uint(f);
  return (unsigned short)((u + 0x7fffu + ((u >> 16) & 1u)) >> 16);
}
static __device__ __forceinline__ float b2f(unsigned short b) {
  return __uint_as_float(((unsigned)b) << 16);
}

// ---------------- embedding: ab self-half = bf16(x @ emb_w + emb_b), h0 fp32 --
__global__ __launch_bounds__(256) void emb_kernel(
    const float* __restrict__ x, const float* __restrict__ w,
    const float* __restrict__ b, float* __restrict__ h0,
    unsigned short* __restrict__ ab) {
  int node = blockIdx.x * 4 + (threadIdx.x >> 6);
  int c = threadIdx.x & 63;
  if (node >= N_NODES) return;
  float xv = (c < F_IN) ? x[node * F_IN + c] : 0.0f;
  float acc = b[c];
#pragma unroll
  for (int f = 0; f < F_IN; ++f) {
    float xf = __shfl(xv, f, 64);
    acc = fmaf(xf, w[f * H + c], acc);
  }
  h0[node * H + c] = acc;
  ab[node * 128 + 64 + c] = f2b(acc);
}

// ---------------- weight preconvert: wbt[jb][ch][k] bf16, k = [WL | WR] ----
__global__ __launch_bounds__(256) void wconv_kernel(
    const float* __restrict__ wl, const float* __restrict__ wr,
    unsigned short* __restrict__ wbt) {
  int i = blockIdx.x * 256 + threadIdx.x;  // 84*64*128 = 688128
  if (i >= 84 * 64 * 128) return;
  int k = i & 127;
  int ch = (i >> 7) & 63;
  int jb = i >> 13;
  float v = (k < 64) ? wl[jb * 4096 + k * 64 + ch]
                     : wr[jb * 4096 + (k - 64) * 64 + ch];
  wbt[i] = f2b(v);
}

// ---------------- binned CSR build (no scattered global atomics) ------------
__global__ __launch_bounds__(256) void p1_bincount(
    const int* __restrict__ e0, const int* __restrict__ e1,
    const int* __restrict__ e2, const int* __restrict__ e3,
    int* __restrict__ cntT) {
  __shared__ int hist[NBINS];
  int t = threadIdx.x, b = blockIdx.x;
  for (int i = t; i < NBINS; i += 256) hist[i] = 0;
  __syncthreads();
  int j = b >> 7;
  const int* ei = (j == 0) ? e0 : (j == 1) ? e1 : (j == 2) ? e2 : e3;
  int ebase = (b & 127) * CHUNK;
  for (int i = t; i < CHUNK; i += 256) {
    int dst = ei[N_EDGES + ebase + i];
    int key = j * N_NODES + dst;
    atomicAdd(&hist[key / BPB], 1);
  }
  __syncthreads();
  for (int i = t; i < NBINS; i += 256) cntT[i * NBINS + b] = hist[i];
}

__global__ __launch_bounds__(256) void p3_binscatter(
    const int* __restrict__ e0, const int* __restrict__ e1,
    const int* __restrict__ e2, const int* __restrict__ e3,
    const int* __restrict__ offT, unsigned* __restrict__ binned) {
  __shared__ int cur[NBINS];
  int t = threadIdx.x, b = blockIdx.x;
  for (int i = t; i < NBINS; i += 256) cur[i] = offT[i * NBINS + b];
  __syncthreads();
  int j = b >> 7;
  const int* ei = (j == 0) ? e0 : (j == 1) ? e1 : (j == 2) ? e2 : e3;
  int ebase = (b & 127) * CHUNK;
  for (int i = t; i < CHUNK; i += 256) {
    int src = ei[ebase + i];
    int dst = ei[N_EDGES + ebase + i];
    int key = j * N_NODES + dst;
    int bin = key / BPB;
    int pos = atomicAdd(&cur[bin], 1);
    binned[pos] = ((unsigned)(key - bin * BPB) << 17) | (unsigned)src;
  }
}

__global__ __launch_bounds__(256) void p4_deg(
    const unsigned* __restrict__ binned, const int* __restrict__ offT,
    int* __restrict__ deg4) {
  __shared__ int hist[BPB];
  int t = threadIdx.x, bin = blockIdx.x;
  for (int i = t; i < BPB; i += 256) hist[i] = 0;
  __syncthreads();
  int start = offT[bin * NBINS];
  int end = (bin == NBINS - 1) ? MEDGES : offT[(bin + 1) * NBINS];
  int kb = bin * BPB;
  for (int i = start + t; i < end; i += 256)
    atomicAdd(&hist[binned[i] >> 17], 1);
  __syncthreads();
  for (int i = t; i < BPB; i += 256)
    if (kb + i < MKEYS) deg4[kb + i] = hist[i];
}

__global__ __launch_bounds__(256) void p6_slots(
    const unsigned* __restrict__ binned, const int* __restrict__ offT,
    const int* __restrict__ S, int* __restrict__ slots) {
  __shared__ int cur[BPB];
  int t = threadIdx.x, bin = blockIdx.x;
  int kb = bin * BPB;
  for (int i = t; i < BPB; i += 256) cur[i] = (kb + i < MKEYS) ? S[kb + i] : 0;
  __syncthreads();
  int start = offT[bin * NBINS];
  int end = (bin == NBINS - 1) ? MEDGES : offT[(bin + 1) * NBINS];
  for (int i = start + t; i < end; i += 256) {
    unsigned v = binned[i];
    int pos = atomicAdd(&cur[v >> 17], 1);
    slots[pos] = (int)(v & 0x1ffffu);
  }
}

// ---------------- hierarchical exclusive scan (1024 elems/block) ------------
__global__ __launch_bounds__(256) void scan1(
    const int* __restrict__ in, int* __restrict__ S, int* __restrict__ bsum, int M) {
  int t = threadIdx.x;
  int base = blockIdx.x * 1024 + t * 4;
  int v0 = 0, v1 = 0, v2 = 0, v3 = 0;
  if (base + 3 < M) {
    int4 q = *(const int4*)(in + base);
    v0 = q.x; v1 = q.y; v2 = q.z; v3 = q.w;
  } else {
    if (base     < M) v0 = in[base];
    if (base + 1 < M) v1 = in[base + 1];
    if (base + 2 < M) v2 = in[base + 2];
    if (base + 3 < M) v3 = in[base + 3];
  }
  int s = v0 + v1 + v2 + v3;
  int incl = s;
#pragma unroll
  for (int off = 1; off < 64; off <<= 1) {
    int y = __shfl_up(incl, off, 64);
    if ((t & 63) >= off) incl += y;
  }
  __shared__ int wtot[4];
  if ((t & 63) == 63) wtot[t >> 6] = incl;
  __syncthreads();
  int wbase = 0;
  for (int w = 0; w < (t >> 6); ++w) wbase += wtot[w];
  int ex = wbase + incl - s;
  if (base < M) {
    int eo0 = ex, eo1 = ex + v0, eo2 = ex + v0 + v1, eo3 = ex + v0 + v1 + v2;
    if (base + 3 < M) {
      *(int4*)(S + base) = make_int4(eo0, eo1, eo2, eo3);
    } else {
      S[base] = eo0;
      if (base + 1 < M) S[base + 1] = eo1;
      if (base + 2 < M) S[base + 2] = eo2;
    }
  }
  if (t == 255) bsum[blockIdx.x] = wbase + incl;
}

__global__ __launch_bounds__(512) void scan2(int* __restrict__ bsum, int nb) {
  int t = threadIdx.x;
  int v = (t < nb) ? bsum[t] : 0;
  int incl = v;
#pragma unroll
  for (int off = 1; off < 64; off <<= 1) {
    int y = __shfl_up(incl, off, 64);
    if ((t & 63) >= off) incl += y;
  }
  __shared__ int wtot[8];
  if ((t & 63) == 63) wtot[t >> 6] = incl;
  __syncthreads();
  int wbase = 0;
  for (int w = 0; w < (t >> 6); ++w) wbase += wtot[w];
  if (t < nb) bsum[t] = wbase + incl - v;
}

__global__ __launch_bounds__(256) void scan3(
    int* __restrict__ S, const int* __restrict__ bsum, int M) {
  int i = blockIdx.x * 256 + threadIdx.x;
  if (i >= M) return;
  S[i] = S[i] + bsum[i >> 10];
}

// ---------------- degree-bucket lists (LDS-aggregated) ----------------------
__global__ __launch_bounds__(256) void bucket_count(
    const int* __restrict__ deg4, int* __restrict__ bcnt) {
  __shared__ int hist[21];
  int t = threadIdx.x;
  if (t < 21) hist[t] = 0;
  __syncthreads();
  int node = blockIdx.x * 256 + t;
  int j = blockIdx.y;
  if (node < N_NODES) {
    int d = deg4[j * N_NODES + node];
    int b = d < MAX_DEG ? d : MAX_DEG;
    atomicAdd(&hist[b], 1);
  }
  __syncthreads();
  if (t < 21 && hist[t]) atomicAdd(&bcnt[j * 21 + t], hist[t]);
}

// scan 84 bucket counts -> boff/bcur, AND per-set tile offsets -> toff/ntiles
__global__ __launch_bounds__(128) void bucket_scan(
    const int* __restrict__ bcnt, int* __restrict__ boff, int* __restrict__ bcur,
    int* __restrict__ toff, int* __restrict__ ntiles) {
  int t = threadIdx.x;
  int v = (t < 84) ? bcnt[t] : 0;
  int incl = v;
#pragma unroll
  for (int off = 1; off < 64; off <<= 1) {
    int y = __shfl_up(incl, off, 64);
    if ((t & 63) >= off) incl += y;
  }
  __shared__ int wt[2];
  __shared__ int nt[84];
  if ((t & 63) == 63) wt[t >> 6] = incl;
  if (t < 84) nt[t] = (v + 63) >> 6;
  __syncthreads();
  int wbase = (t >> 6) ? wt[0] : 0;
  if (t < 84) {
    int ex = wbase + incl - v;
    boff[t] = ex;
    bcur[t] = ex;
  }
  if (t < 4) {
    int acc = 0;
    for (int bb = 0; bb < 21; ++bb) {
      toff[t * 21 + bb] = acc;
      acc += nt[t * 21 + bb];
    }
    ntiles[t] = acc;
  }
}

__global__ __launch_bounds__(256) void bucket_fill(
    const int* __restrict__ deg4, int* __restrict__ bcur, int* __restrict__ blist) {
  __shared__ int hist[21];
  __shared__ int base[21];
  int t = threadIdx.x;
  if (t < 21) hist[t] = 0;
  __syncthreads();
  int node = blockIdx.x * 256 + t;
  int j = blockIdx.y;
  int b = 0, lpos = 0;
  bool valid = (node < N_NODES);
  if (valid) {
    int d = deg4[j * N_NODES + node];
    b = d < MAX_DEG ? d : MAX_DEG;
    lpos = atomicAdd(&hist[b], 1);
  }
  __syncthreads();
  if (t < 21 && hist[t]) base[t] = atomicAdd(&bcur[j * 21 + t], hist[t]);
  __syncthreads();
  if (valid) blist[base[b] + lpos] = node;
}

// tile_fill: one block per (j,b); desc = (blist_pos << 12) | (bucket << 7) | nIn
__global__ __launch_bounds__(256) void tile_fill(
    const int* __restrict__ bcnt, const int* __restrict__ boff,
    const int* __restrict__ toff, int* __restrict__ tdesc) {
  int jb = blockIdx.x;           // 0..83
  int j = jb / 21, b = jb % 21;
  int cnt = bcnt[jb];
  int off = boff[jb];
  int tb = toff[jb];
  int nt = (cnt + 63) >> 6;
  for (int i = threadIdx.x; i < nt; i += 256) {
    int s = i << 6;
    int nIn = min(64, cnt - s);
    tdesc[j * MAX_TILES + tb + i] = ((off + s) << 12) | (b << 7) | nIn;
  }
}

// ---------------- gather: ab hsum-half = sum of neighbor self-halves --------
// Dual-edge: half-wave (32 lanes) per edge parity, lane loads ushort2 (2 ch).
// One VMEM inst covers 2 edge-rows; 4-deep unroll = 8 edges in flight.
__global__ __launch_bounds__(256) void gather_kernel(
    const int* __restrict__ S, const int* __restrict__ deg,
    const int* __restrict__ slots, unsigned short* __restrict__ ab) {
  int node = blockIdx.x * 4 + (threadIdx.x >> 6);
  int lane = threadIdx.x & 63;
  if (node >= N_NODES) return;
  int half = lane >> 5, cl = lane & 31;
  int off = S[node];
  int dg = deg[node];
  float a0s = 0.f, a0t = 0.f, a1s = 0.f, a1t = 0.f;
  float a2s = 0.f, a2t = 0.f, a3s = 0.f, a3t = 0.f;
  int e = half;
  for (; e + 6 < dg; e += 8) {
    int n0 = slots[off + e];
    int n1 = slots[off + e + 2];
    int n2 = slots[off + e + 4];
    int n3 = slots[off + e + 6];
    unsigned p0 = *(const unsigned*)&ab[n0 * 128 + 64 + 2 * cl];
    unsigned p1 = *(const unsigned*)&ab[n1 * 128 + 64 + 2 * cl];
    unsigned p2 = *(const unsigned*)&ab[n2 * 128 + 64 + 2 * cl];
    unsigned p3 = *(const unsigned*)&ab[n3 * 128 + 64 + 2 * cl];
    a0s += b2f((unsigned short)p0); a0t += b2f((unsigned short)(p0 >> 16));
    a1s += b2f((unsigned short)p1); a1t += b2f((unsigned short)(p1 >> 16));
    a2s += b2f((unsigned short)p2); a2t += b2f((unsigned short)(p2 >> 16));
    a3s += b2f((unsigned short)p3); a3t += b2f((unsigned short)(p3 >> 16));
  }
  for (; e < dg; e += 2) {
    unsigned p0 = *(const unsigned*)&ab[slots[off + e] * 128 + 64 + 2 * cl];
    a0s += b2f((unsigned short)p0); a0t += b2f((unsigned short)(p0 >> 16));
  }
  float s0 = (a0s + a1s) + (a2s + a3s);
  float s1 = (a0t + a1t) + (a2t + a3t);
  s0 += __shfl_xor(s0, 32, 64);
  s1 += __shfl_xor(s1, 32, 64);
  if (half == 0) {
    unsigned o = (unsigned)f2b(s0) | ((unsigned)f2b(s1) << 16);
    *(unsigned*)&ab[node * 128 + 2 * cl] = o;
  }
}

// ---------------- MFMA transform: [64 x 128] @ [128 x 64] per tile ----------
// A-row = ab[node][0:128] (one uint/lane = 256B staging load). j<3: write bf16
// self-half only; j==3 (last): write fp32 h only (for LN+pool).
__global__ __launch_bounds__(256) void transform_kernel(
    float* __restrict__ h, unsigned short* __restrict__ ab,
    const int* __restrict__ blist, const int* __restrict__ tdesc,
    const int* __restrict__ ntiles, const unsigned short* __restrict__ wbt,
    const float* __restrict__ bl, int j, int do_relu, int last) {
  if ((int)blockIdx.x >= ntiles[j]) return;
  int d = tdesc[j * MAX_TILES + blockIdx.x];
  int nIn = d & 127;
  int b = (d >> 7) & 31;
  const int* lst = blist + (d >> 12);

  int tid = threadIdx.x;
  int qw = tid >> 6, lane = tid & 63;

  if (b == 0) {
    // deg==0 masking: carry self value (bf16-rounded); ReLU when j<3
    for (int r = qw * 16; r < qw * 16 + 16; ++r) {
      if (r < nIn) {
        int node = lst[r];
        float v = b2f(ab[node * 128 + 64 + lane]);
        if (do_relu) v = fmaxf(v, 0.f);
        if (last) h[node * H + lane] = v;
        else ab[node * 128 + 64 + lane] = f2b(v);
      }
    }
    return;
  }

  __shared__ unsigned short aL[64 * 136];  // 17408 B; reused as fp32[64*68]
  __shared__ int nodeS[64];

  for (int r = qw * 16; r < qw * 16 + 16; ++r) {
    int node = (r < nIn) ? lst[r] : -1;
    if (lane == 0) nodeS[r] = node;
    unsigned q = 0;
    if (node >= 0) q = *(const unsigned*)&ab[node * 128 + 2 * lane];
    *(unsigned*)&aL[r * 136 + 2 * lane] = q;
  }
  __syncthreads();

  int m = lane & 15, quad = lane >> 4;
  const unsigned short* wbase = wbt + (size_t)(j * 21 + b) * 64 * 128;
  float4v acc[4];
#pragma unroll
  for (int t = 0; t < 4; ++t) {
    float bv = bl[b * 64 + t * 16 + m];
    acc[t] = (float4v){bv, bv, bv, bv};
  }
#pragma unroll
  for (int ks = 0; ks < 4; ++ks) {
    short8 a = *(const short8*)&aL[(qw * 16 + m) * 136 + ks * 32 + quad * 8];
#pragma unroll
    for (int t = 0; t < 4; ++t) {
      short8 bf = *(const short8*)&wbase[(t * 16 + m) * 128 + ks * 32 + quad * 8];
      acc[t] = __builtin_amdgcn_mfma_f32_16x16x32_bf16(a, bf, acc[t], 0, 0, 0);
    }
  }
  if (do_relu) {
#pragma unroll
    for (int t = 0; t < 4; ++t)
#pragma unroll
      for (int r = 0; r < 4; ++r) acc[t][r] = fmaxf(acc[t][r], 0.f);
  }
  __syncthreads();
  float* outF = (float*)aL;
#pragma unroll
  for (int t = 0; t < 4; ++t)
#pragma unroll
    for (int r = 0; r < 4; ++r)
      outF[(qw * 16 + quad * 4 + r) * 68 + t * 16 + m] = acc[t][r];
  __syncthreads();
  if (last) {
    for (int r = qw * 16; r < qw * 16 + 16; ++r)
      if (r < nIn) h[nodeS[r] * H + lane] = outF[r * 68 + lane];
  } else {
    for (int r = qw * 16; r < qw * 16 + 16; ++r)
      if (r < nIn) ab[nodeS[r] * 128 + 64 + lane] = f2b(outF[r * 68 + lane]);
  }
}

// ---------------- fused layernorm + residual + ground-node pool -------------
// LN output is only consumed by the ground-node pooling -> process only
// nodes < G_NODES, never materialize post-LN h.
__global__ __launch_bounds__(256) void ln_pool_kernel(
    const float* __restrict__ h, const float* __restrict__ h0,
    const float* __restrict__ g, const float* __restrict__ b,
    const int* __restrict__ batch, float* __restrict__ pooled) {
  __shared__ float sm[NUM_GRAPHS * H];  // 32 KB
  int t = threadIdx.x;
  for (int i = t; i < NUM_GRAPHS * H; i += 256) sm[i] = 0.f;
  __syncthreads();
  int lane = t & 63, w = t >> 6;
  const int per = (G_NODES + POOL_BLOCKS - 1) / POOL_BLOCKS;
  int start = blockIdx.x * per;
  int end = min(start + per, G_NODES);
  for (int node = start + w; node < end; node += 4) {
    int idx = node * H + lane;
    float v = h[idx];
    float s = v;
#pragma unroll
    for (int off = 32; off > 0; off >>= 1) s += __shfl_xor(s, off, 64);
    float mu = s * (1.0f / H);
    float dv = v - mu;
    float q = dv * dv;
#pragma unroll
    for (int off = 32; off > 0; off >>= 1) q += __shfl_xor(q, off, 64);
    float inv = rsqrtf(q * (1.0f / H) + LN_EPS);
    float r = dv * inv * g[lane] + b[lane] + h0[idx];
    atomicAdd(&sm[batch[node] * H + lane], r);
  }
  __syncthreads();
  for (int i = t; i < NUM_GRAPHS * H; i += 256) {
    float v = sm[i];
    if (v != 0.f) atomicAdd(&pooled[i], v);
  }
}

__global__ __launch_bounds__(64) void out_kernel(
    const float* __restrict__ pooled, const float* __restrict__ w,
    const float* __restrict__ b, float* __restrict__ out) {
  int gph = blockIdx.x;
  int c = threadIdx.x;
  float v = pooled[gph * H + c] * w[c];
#pragma unroll
  for (int off = 32; off > 0; off >>= 1) v += __shfl_xor(v, off, 64);
  if (c == 0) out[gph] = v + b[0];
}

extern "C" void kernel_launch(void* const* d_in, const int* in_sizes, int n_in,
                              void* d_out, int out_size, void* d_ws, size_t ws_size,
                              hipStream_t stream) {
  const float* x       = (const float*)d_in[0];
  const int*   ei_edge = (const int*)d_in[1];
  const int*   ei_sub  = (const int*)d_in[2];
  const int*   ei_ns   = (const int*)d_in[3];
  const int*   ei_sn   = (const int*)d_in[4];
  const int*   batch   = (const int*)d_in[7];
  const float* emb_w   = (const float*)d_in[8];
  const float* emb_b   = (const float*)d_in[9];
  const float* conv_wl = (const float*)d_in[10];
  const float* conv_bl = (const float*)d_in[11];
  const float* conv_wr = (const float*)d_in[12];
  const float* ln_g    = (const float*)d_in[13];
  const float* ln_b    = (const float*)d_in[14];
  const float* out_w   = (const float*)d_in[15];
  const float* out_b   = (const float*)d_in[16];
  float* out = (float*)d_out;

  const size_t HB = (size_t)N_NODES * H * sizeof(float);   // 25.6 MB
  char* ws = (char*)d_ws;
  float* h      = (float*)(ws);                        // fp32, written at j==3
  float* h0     = (float*)(ws + HB);                   // fp32 residual
  unsigned short* ab = (unsigned short*)(ws + 2 * HB); // [node][128] bf16 25.6MB
  // Build-phase overlays (dead once emb/gather run):
  unsigned* binned = (unsigned*)(ws);                            // 12.8 MB on h
  int*   cntT   = (int*)(ws + HB);                               // 1 MB on h0
  int*   offT   = (int*)(ws + HB + 0x100000);                    // 1 MB
  int*   bsumA  = (int*)(ws + HB + 0x300000);                    // 2 KB
  // Persistent:
  int*   deg4   = (int*)(ws + 3 * HB);                           // 1.6 MB
  int*   S      = (int*)(ws + 78400000);                         // 1.6 MB
  int*   slots  = (int*)(ws + 80000000);                         // 12.8 MB
  int*   bcnt   = (int*)(ws + 92800000);
  int*   boff   = (int*)(ws + 92800512);
  int*   bcur   = (int*)(ws + 92801024);
  int*   blist  = (int*)(ws + 92801536);                         // 1.6 MB
  float* pooled = (float*)(ws + 94401536);                       // 32 KB
  unsigned short* wbt = (unsigned short*)(ws + 94434304);        // 1.38 MB
  int*   tdesc  = (int*)(ws + 95810560);                         // 25.6 KB
  int*   ntiles = (int*)(ws + 95836160);                         // 16 B
  int*   toff   = (int*)(ws + 95836224);                         // 336 B

  const int* e0 = ei_edge, *e1 = ei_ns, *e2 = ei_sub, *e3 = ei_sn;
  const int MC = NBINS * NBINS;
  const int NB_MC = MC / 1024;              // 256
  const int NB_MK = (MKEYS + 1023) / 1024;  // 391

  hipMemsetAsync(bcnt, 0, 512, stream);

  // --- binned CSR build ---
  p1_bincount<<<NBINS, 256, 0, stream>>>(e0, e1, e2, e3, cntT);
  scan1<<<NB_MC, 256, 0, stream>>>(cntT, offT, bsumA, MC);
  scan2<<<1, 512, 0, stream>>>(bsumA, NB_MC);
  scan3<<<MC / 256, 256, 0, stream>>>(offT, bsumA, MC);
  p3_binscatter<<<NBINS, 256, 0, stream>>>(e0, e1, e2, e3, offT, binned);
  p4_deg<<<NBINS, 256, 0, stream>>>(binned, offT, deg4);
  scan1<<<NB_MK, 256, 0, stream>>>(deg4, S, bsumA, MKEYS);
  scan2<<<1, 512, 0, stream>>>(bsumA, NB_MK);
  scan3<<<(MKEYS + 255) / 256, 256, 0, stream>>>(S, bsumA, MKEYS);
  p6_slots<<<NBINS, 256, 0, stream>>>(binned, offT, S, slots);

  bucket_count<<<dim3((N_NODES + 255) / 256, 4), 256, 0, stream>>>(deg4, bcnt);
  bucket_scan<<<1, 128, 0, stream>>>(bcnt, boff, bcur, toff, ntiles);
  bucket_fill<<<dim3((N_NODES + 255) / 256, 4), 256, 0, stream>>>(deg4, bcur, blist);
  tile_fill<<<84, 256, 0, stream>>>(bcnt, boff, toff, tdesc);
  wconv_kernel<<<(84 * 64 * 128 + 255) / 256, 256, 0, stream>>>(conv_wl, conv_wr, wbt);

  // --- network ---
  emb_kernel<<<(N_NODES + 3) / 4, 256, 0, stream>>>(x, emb_w, emb_b, h0, ab);

  for (int j = 0; j < 4; ++j) {
    gather_kernel<<<(N_NODES + 3) / 4, 256, 0, stream>>>(
        S + j * N_NODES, deg4 + j * N_NODES, slots, ab);
    transform_kernel<<<MAX_TILES, 256, 0, stream>>>(
        h, ab, blist, tdesc, ntiles, wbt,
        conv_bl + (size_t)j * 21 * H, j, j < 3 ? 1 : 0, j == 3 ? 1 : 0);
  }

  hipMemsetAsync(pooled, 0, NUM_GRAPHS * H * sizeof(float), stream);
  ln_pool_kernel<<<POOL_BLOCKS, 256, 0, stream>>>(h, h0, ln_g, ln_b, batch, pooled);
  out_kernel<<<NUM_GRAPHS, 64, 0, stream>>>(pooled, out_w, out_b, out);
}

// Round 11
// 530.542 us; speedup vs baseline: 1.5914x; 1.0846x over previous
//
#include <hip/hip_runtime.h>

#define N_NODES 100000
#define G_NODES 50000
#define N_EDGES 800000
#define H 64
#define F_IN 32
#define MAX_DEG 20
#define NUM_GRAPHS 128
#define LN_EPS 1e-5f
#define POOL_BLOCKS 256
#define MAX_TILES 1600

// Binned CSR build parameters: 512 bins over the 4*N key space.
#define NBINS 512
#define BPB 782            // keys per bin: 782*512 = 400384 >= 400000
#define CHUNK 6250         // edges per build block: 6250*512 = 3.2M
#define MKEYS (4 * N_NODES)
#define MEDGES (4 * N_EDGES)

typedef __attribute__((ext_vector_type(8))) short short8;
typedef __attribute__((ext_vector_type(4))) float float4v;

// bf16 helpers (RNE), no header dependency
static __device__ __forceinline__ unsigned short f2b(float f) {
  unsigned u = __float_as_uint(f);
  return (unsigned short)((u + 0x7fffu + ((u >> 16) & 1u)) >> 16);
}
static __device__ __forceinline__ float b2f(unsigned short b) {
  return __uint_as_float(((unsigned)b) << 16);
}

// ---------------- embedding: ab self-half = bf16(x @ emb_w + emb_b), h0 fp32 --
__global__ __launch_bounds__(256) void emb_kernel(
    const float* __restrict__ x, const float* __restrict__ w,
    const float* __restrict__ b, float* __restrict__ h0,
    unsigned short* __restrict__ ab) {
  int node = blockIdx.x * 4 + (threadIdx.x >> 6);
  int c = threadIdx.x & 63;
  if (node >= N_NODES) return;
  float xv = (c < F_IN) ? x[node * F_IN + c] : 0.0f;
  float acc = b[c];
#pragma unroll
  for (int f = 0; f < F_IN; ++f) {
    float xf = __shfl(xv, f, 64);
    acc = fmaf(xf, w[f * H + c], acc);
  }
  h0[node * H + c] = acc;
  ab[node * 128 + 64 + c] = f2b(acc);
}

// ---------------- weight preconvert: wbt[jb][ch][k] bf16, k = [WL | WR] ----
__global__ __launch_bounds__(256) void wconv_kernel(
    const float* __restrict__ wl, const float* __restrict__ wr,
    unsigned short* __restrict__ wbt) {
  int i = blockIdx.x * 256 + threadIdx.x;  // 84*64*128 = 688128
  if (i >= 84 * 64 * 128) return;
  int k = i & 127;
  int ch = (i >> 7) & 63;
  int jb = i >> 13;
  float v = (k < 64) ? wl[jb * 4096 + k * 64 + ch]
                     : wr[jb * 4096 + (k - 64) * 64 + ch];
  wbt[i] = f2b(v);
}

// ---------------- binned CSR build (no scattered global atomics) ------------
__global__ __launch_bounds__(256) void p1_bincount(
    const int* __restrict__ e0, const int* __restrict__ e1,
    const int* __restrict__ e2, const int* __restrict__ e3,
    int* __restrict__ cntT) {
  __shared__ int hist[NBINS];
  int t = threadIdx.x, b = blockIdx.x;
  for (int i = t; i < NBINS; i += 256) hist[i] = 0;
  __syncthreads();
  int j = b >> 7;
  const int* ei = (j == 0) ? e0 : (j == 1) ? e1 : (j == 2) ? e2 : e3;
  int ebase = (b & 127) * CHUNK;
  for (int i = t; i < CHUNK; i += 256) {
    int dst = ei[N_EDGES + ebase + i];
    int key = j * N_NODES + dst;
    atomicAdd(&hist[key / BPB], 1);
  }
  __syncthreads();
  for (int i = t; i < NBINS; i += 256) cntT[i * NBINS + b] = hist[i];
}

__global__ __launch_bounds__(256) void p3_binscatter(
    const int* __restrict__ e0, const int* __restrict__ e1,
    const int* __restrict__ e2, const int* __restrict__ e3,
    const int* __restrict__ offT, unsigned* __restrict__ binned) {
  __shared__ int cur[NBINS];
  int t = threadIdx.x, b = blockIdx.x;
  for (int i = t; i < NBINS; i += 256) cur[i] = offT[i * NBINS + b];
  __syncthreads();
  int j = b >> 7;
  const int* ei = (j == 0) ? e0 : (j == 1) ? e1 : (j == 2) ? e2 : e3;
  int ebase = (b & 127) * CHUNK;
  for (int i = t; i < CHUNK; i += 256) {
    int src = ei[ebase + i];
    int dst = ei[N_EDGES + ebase + i];
    int key = j * N_NODES + dst;
    int bin = key / BPB;
    int pos = atomicAdd(&cur[bin], 1);
    binned[pos] = ((unsigned)(key - bin * BPB) << 17) | (unsigned)src;
  }
}

__global__ __launch_bounds__(256) void p4_deg(
    const unsigned* __restrict__ binned, const int* __restrict__ offT,
    int* __restrict__ deg4) {
  __shared__ int hist[BPB];
  int t = threadIdx.x, bin = blockIdx.x;
  for (int i = t; i < BPB; i += 256) hist[i] = 0;
  __syncthreads();
  int start = offT[bin * NBINS];
  int end = (bin == NBINS - 1) ? MEDGES : offT[(bin + 1) * NBINS];
  int kb = bin * BPB;
  for (int i = start + t; i < end; i += 256)
    atomicAdd(&hist[binned[i] >> 17], 1);
  __syncthreads();
  for (int i = t; i < BPB; i += 256)
    if (kb + i < MKEYS) deg4[kb + i] = hist[i];
}

__global__ __launch_bounds__(256) void p6_slots(
    const unsigned* __restrict__ binned, const int* __restrict__ offT,
    const int* __restrict__ S, int* __restrict__ slots) {
  __shared__ int cur[BPB];
  int t = threadIdx.x, bin = blockIdx.x;
  int kb = bin * BPB;
  for (int i = t; i < BPB; i += 256) cur[i] = (kb + i < MKEYS) ? S[kb + i] : 0;
  __syncthreads();
  int start = offT[bin * NBINS];
  int end = (bin == NBINS - 1) ? MEDGES : offT[(bin + 1) * NBINS];
  for (int i = start + t; i < end; i += 256) {
    unsigned v = binned[i];
    int pos = atomicAdd(&cur[v >> 17], 1);
    slots[pos] = (int)(v & 0x1ffffu);
  }
}

// ---------------- hierarchical exclusive scan (1024 elems/block) ------------
__global__ __launch_bounds__(256) void scan1(
    const int* __restrict__ in, int* __restrict__ S, int* __restrict__ bsum, int M) {
  int t = threadIdx.x;
  int base = blockIdx.x * 1024 + t * 4;
  int v0 = 0, v1 = 0, v2 = 0, v3 = 0;
  if (base + 3 < M) {
    int4 q = *(const int4*)(in + base);
    v0 = q.x; v1 = q.y; v2 = q.z; v3 = q.w;
  } else {
    if (base     < M) v0 = in[base];
    if (base + 1 < M) v1 = in[base + 1];
    if (base + 2 < M) v2 = in[base + 2];
    if (base + 3 < M) v3 = in[base + 3];
  }
  int s = v0 + v1 + v2 + v3;
  int incl = s;
#pragma unroll
  for (int off = 1; off < 64; off <<= 1) {
    int y = __shfl_up(incl, off, 64);
    if ((t & 63) >= off) incl += y;
  }
  __shared__ int wtot[4];
  if ((t & 63) == 63) wtot[t >> 6] = incl;
  __syncthreads();
  int wbase = 0;
  for (int w = 0; w < (t >> 6); ++w) wbase += wtot[w];
  int ex = wbase + incl - s;
  if (base < M) {
    int eo0 = ex, eo1 = ex + v0, eo2 = ex + v0 + v1, eo3 = ex + v0 + v1 + v2;
    if (base + 3 < M) {
      *(int4*)(S + base) = make_int4(eo0, eo1, eo2, eo3);
    } else {
      S[base] = eo0;
      if (base + 1 < M) S[base + 1] = eo1;
      if (base + 2 < M) S[base + 2] = eo2;
    }
  }
  if (t == 255) bsum[blockIdx.x] = wbase + incl;
}

__global__ __launch_bounds__(512) void scan2(int* __restrict__ bsum, int nb) {
  int t = threadIdx.x;
  int v = (t < nb) ? bsum[t] : 0;
  int incl = v;
#pragma unroll
  for (int off = 1; off < 64; off <<= 1) {
    int y = __shfl_up(incl, off, 64);
    if ((t & 63) >= off) incl += y;
  }
  __shared__ int wtot[8];
  if ((t & 63) == 63) wtot[t >> 6] = incl;
  __syncthreads();
  int wbase = 0;
  for (int w = 0; w < (t >> 6); ++w) wbase += wtot[w];
  if (t < nb) bsum[t] = wbase + incl - v;
}

__global__ __launch_bounds__(256) void scan3(
    int* __restrict__ S, const int* __restrict__ bsum, int M) {
  int i = blockIdx.x * 256 + threadIdx.x;
  if (i >= M) return;
  S[i] = S[i] + bsum[i >> 10];
}

// ---------------- degree-bucket lists (LDS-aggregated) ----------------------
__global__ __launch_bounds__(256) void bucket_count(
    const int* __restrict__ deg4, int* __restrict__ bcnt) {
  __shared__ int hist[21];
  int t = threadIdx.x;
  if (t < 21) hist[t] = 0;
  __syncthreads();
  int node = blockIdx.x * 256 + t;
  int j = blockIdx.y;
  if (node < N_NODES) {
    int d = deg4[j * N_NODES + node];
    int b = d < MAX_DEG ? d : MAX_DEG;
    atomicAdd(&hist[b], 1);
  }
  __syncthreads();
  if (t < 21 && hist[t]) atomicAdd(&bcnt[j * 21 + t], hist[t]);
}

// scan 84 bucket counts -> boff/bcur, AND per-set tile offsets -> toff/ntiles
__global__ __launch_bounds__(128) void bucket_scan(
    const int* __restrict__ bcnt, int* __restrict__ boff, int* __restrict__ bcur,
    int* __restrict__ toff, int* __restrict__ ntiles) {
  int t = threadIdx.x;
  int v = (t < 84) ? bcnt[t] : 0;
  int incl = v;
#pragma unroll
  for (int off = 1; off < 64; off <<= 1) {
    int y = __shfl_up(incl, off, 64);
    if ((t & 63) >= off) incl += y;
  }
  __shared__ int wt[2];
  __shared__ int nt[84];
  if ((t & 63) == 63) wt[t >> 6] = incl;
  if (t < 84) nt[t] = (v + 63) >> 6;
  __syncthreads();
  int wbase = (t >> 6) ? wt[0] : 0;
  if (t < 84) {
    int ex = wbase + incl - v;
    boff[t] = ex;
    bcur[t] = ex;
  }
  if (t < 4) {
    int acc = 0;
    for (int bb = 0; bb < 21; ++bb) {
      toff[t * 21 + bb] = acc;
      acc += nt[t * 21 + bb];
    }
    ntiles[t] = acc;
  }
}

__global__ __launch_bounds__(256) void bucket_fill(
    const int* __restrict__ deg4, int* __restrict__ bcur, int* __restrict__ blist) {
  __shared__ int hist[21];
  __shared__ int base[21];
  int t = threadIdx.x;
  if (t < 21) hist[t] = 0;
  __syncthreads();
  int node = blockIdx.x * 256 + t;
  int j = blockIdx.y;
  int b = 0, lpos = 0;
  bool valid = (node < N_NODES);
  if (valid) {
    int d = deg4[j * N_NODES + node];
    b = d < MAX_DEG ? d : MAX_DEG;
    lpos = atomicAdd(&hist[b], 1);
  }
  __syncthreads();
  if (t < 21 && hist[t]) base[t] = atomicAdd(&bcur[j * 21 + t], hist[t]);
  __syncthreads();
  if (valid) blist[base[b] + lpos] = node;
}

// tile_fill: one block per (j,b); desc = (blist_pos << 12) | (bucket << 7) | nIn
__global__ __launch_bounds__(256) void tile_fill(
    const int* __restrict__ bcnt, const int* __restrict__ boff,
    const int* __restrict__ toff, int* __restrict__ tdesc) {
  int jb = blockIdx.x;           // 0..83
  int j = jb / 21, b = jb % 21;
  int cnt = bcnt[jb];
  int off = boff[jb];
  int tb = toff[jb];
  int nt = (cnt + 63) >> 6;
  for (int i = threadIdx.x; i < nt; i += 256) {
    int s = i << 6;
    int nIn = min(64, cnt - s);
    tdesc[j * MAX_TILES + tb + i] = ((off + s) << 12) | (b << 7) | nIn;
  }
}

// ---------------- gather: ab hsum-half = sum of neighbor self-halves --------
// Quad-edge: quarter-wave (16 lanes) per edge parity, lane loads uint2 (4 ch).
// One wave VMEM inst covers 4 edge-rows (512B); 2-deep unroll = 8 in flight.
__global__ __launch_bounds__(256) void gather_kernel(
    const int* __restrict__ S, const int* __restrict__ deg,
    const int* __restrict__ slots, unsigned short* __restrict__ ab) {
  int node = blockIdx.x * 4 + (threadIdx.x >> 6);
  int lane = threadIdx.x & 63;
  if (node >= N_NODES) return;
  int q = lane >> 4, cl = lane & 15;  // channels [4*cl, 4*cl+4)
  int off = S[node];
  int dg = deg[node];
  float c0 = 0.f, c1 = 0.f, c2 = 0.f, c3 = 0.f;
  int e = q;
  for (; e + 4 < dg; e += 8) {
    int n0 = slots[off + e];
    int n1 = slots[off + e + 4];
    uint2 p0 = *(const uint2*)&ab[n0 * 128 + 64 + 4 * cl];
    uint2 p1 = *(const uint2*)&ab[n1 * 128 + 64 + 4 * cl];
    c0 += b2f((unsigned short)p0.x) + b2f((unsigned short)p1.x);
    c1 += b2f((unsigned short)(p0.x >> 16)) + b2f((unsigned short)(p1.x >> 16));
    c2 += b2f((unsigned short)p0.y) + b2f((unsigned short)p1.y);
    c3 += b2f((unsigned short)(p0.y >> 16)) + b2f((unsigned short)(p1.y >> 16));
  }
  for (; e < dg; e += 4) {
    uint2 p0 = *(const uint2*)&ab[slots[off + e] * 128 + 64 + 4 * cl];
    c0 += b2f((unsigned short)p0.x);
    c1 += b2f((unsigned short)(p0.x >> 16));
    c2 += b2f((unsigned short)p0.y);
    c3 += b2f((unsigned short)(p0.y >> 16));
  }
  // sum the 4 edge-parity quarters (lanes cl, cl+16, cl+32, cl+48)
  c0 += __shfl_xor(c0, 16, 64); c0 += __shfl_xor(c0, 32, 64);
  c1 += __shfl_xor(c1, 16, 64); c1 += __shfl_xor(c1, 32, 64);
  c2 += __shfl_xor(c2, 16, 64); c2 += __shfl_xor(c2, 32, 64);
  c3 += __shfl_xor(c3, 16, 64); c3 += __shfl_xor(c3, 32, 64);
  if (q == 0) {
    uint2 o;
    o.x = (unsigned)f2b(c0) | ((unsigned)f2b(c1) << 16);
    o.y = (unsigned)f2b(c2) | ((unsigned)f2b(c3) << 16);
    *(uint2*)&ab[node * 128 + 4 * cl] = o;
  }
}

// ---------------- MFMA transform: [64 x 128] @ [128 x 64] per tile ----------
// A-row = ab[node][0:128] (one uint/lane = 256B staging load). j<3: write bf16
// self-half only; j==3 (last): write fp32 h only (for LN+pool).
__global__ __launch_bounds__(256) void transform_kernel(
    float* __restrict__ h, unsigned short* __restrict__ ab,
    const int* __restrict__ blist, const int* __restrict__ tdesc,
    const int* __restrict__ ntiles, const unsigned short* __restrict__ wbt,
    const float* __restrict__ bl, int j, int do_relu, int last) {
  if ((int)blockIdx.x >= ntiles[j]) return;
  int d = tdesc[j * MAX_TILES + blockIdx.x];
  int nIn = d & 127;
  int b = (d >> 7) & 31;
  const int* lst = blist + (d >> 12);

  int tid = threadIdx.x;
  int qw = tid >> 6, lane = tid & 63;

  if (b == 0) {
    // deg==0 masking: carry self value (bf16-rounded); ReLU when j<3
    for (int r = qw * 16; r < qw * 16 + 16; ++r) {
      if (r < nIn) {
        int node = lst[r];
        float v = b2f(ab[node * 128 + 64 + lane]);
        if (do_relu) v = fmaxf(v, 0.f);
        if (last) h[node * H + lane] = v;
        else ab[node * 128 + 64 + lane] = f2b(v);
      }
    }
    return;
  }

  __shared__ unsigned short aL[64 * 136];  // 17408 B; reused as fp32[64*68]
  __shared__ int nodeS[64];

  for (int r = qw * 16; r < qw * 16 + 16; ++r) {
    int node = (r < nIn) ? lst[r] : -1;
    if (lane == 0) nodeS[r] = node;
    unsigned q = 0;
    if (node >= 0) q = *(const unsigned*)&ab[node * 128 + 2 * lane];
    *(unsigned*)&aL[r * 136 + 2 * lane] = q;
  }
  __syncthreads();

  int m = lane & 15, quad = lane >> 4;
  const unsigned short* wbase = wbt + (size_t)(j * 21 + b) * 64 * 128;
  float4v acc[4];
#pragma unroll
  for (int t = 0; t < 4; ++t) {
    float bv = bl[b * 64 + t * 16 + m];
    acc[t] = (float4v){bv, bv, bv, bv};
  }
#pragma unroll
  for (int ks = 0; ks < 4; ++ks) {
    short8 a = *(const short8*)&aL[(qw * 16 + m) * 136 + ks * 32 + quad * 8];
#pragma unroll
    for (int t = 0; t < 4; ++t) {
      short8 bf = *(const short8*)&wbase[(t * 16 + m) * 128 + ks * 32 + quad * 8];
      acc[t] = __builtin_amdgcn_mfma_f32_16x16x32_bf16(a, bf, acc[t], 0, 0, 0);
    }
  }
  if (do_relu) {
#pragma unroll
    for (int t = 0; t < 4; ++t)
#pragma unroll
      for (int r = 0; r < 4; ++r) acc[t][r] = fmaxf(acc[t][r], 0.f);
  }
  __syncthreads();
  float* outF = (float*)aL;
#pragma unroll
  for (int t = 0; t < 4; ++t)
#pragma unroll
    for (int r = 0; r < 4; ++r)
      outF[(qw * 16 + quad * 4 + r) * 68 + t * 16 + m] = acc[t][r];
  __syncthreads();
  if (last) {
    for (int r = qw * 16; r < qw * 16 + 16; ++r)
      if (r < nIn) h[nodeS[r] * H + lane] = outF[r * 68 + lane];
  } else {
    for (int r = qw * 16; r < qw * 16 + 16; ++r)
      if (r < nIn) ab[nodeS[r] * 128 + 64 + lane] = f2b(outF[r * 68 + lane]);
  }
}

// ---------------- fused layernorm + residual + ground-node pool -------------
// 1024-thread blocks (R10: 256-thread blocks = 4 waves/CU = 9.6% occ,
// latency-bound at 408 GB/s). 16 waves/CU hides the load+shuffle latency.
__global__ __launch_bounds__(1024) void ln_pool_kernel(
    const float* __restrict__ h, const float* __restrict__ h0,
    const float* __restrict__ g, const float* __restrict__ b,
    const int* __restrict__ batch, float* __restrict__ pooled) {
  __shared__ float sm[NUM_GRAPHS * H];  // 32 KB
  int t = threadIdx.x;
  for (int i = t; i < NUM_GRAPHS * H; i += 1024) sm[i] = 0.f;
  __syncthreads();
  int lane = t & 63, w = t >> 6;  // 16 waves
  const int per = (G_NODES + POOL_BLOCKS - 1) / POOL_BLOCKS;
  int start = blockIdx.x * per;
  int end = min(start + per, G_NODES);
  for (int node = start + w; node < end; node += 16) {
    int idx = node * H + lane;
    float v = h[idx];
    float s = v;
#pragma unroll
    for (int off = 32; off > 0; off >>= 1) s += __shfl_xor(s, off, 64);
    float mu = s * (1.0f / H);
    float dv = v - mu;
    float q = dv * dv;
#pragma unroll
    for (int off = 32; off > 0; off >>= 1) q += __shfl_xor(q, off, 64);
    float inv = rsqrtf(q * (1.0f / H) + LN_EPS);
    float r = dv * inv * g[lane] + b[lane] + h0[idx];
    atomicAdd(&sm[batch[node] * H + lane], r);
  }
  __syncthreads();
  for (int i = t; i < NUM_GRAPHS * H; i += 1024) {
    float v = sm[i];
    if (v != 0.f) atomicAdd(&pooled[i], v);
  }
}

__global__ __launch_bounds__(64) void out_kernel(
    const float* __restrict__ pooled, const float* __restrict__ w,
    const float* __restrict__ b, float* __restrict__ out) {
  int gph = blockIdx.x;
  int c = threadIdx.x;
  float v = pooled[gph * H + c] * w[c];
#pragma unroll
  for (int off = 32; off > 0; off >>= 1) v += __shfl_xor(v, off, 64);
  if (c == 0) out[gph] = v + b[0];
}

extern "C" void kernel_launch(void* const* d_in, const int* in_sizes, int n_in,
                              void* d_out, int out_size, void* d_ws, size_t ws_size,
                              hipStream_t stream) {
  const float* x       = (const float*)d_in[0];
  const int*   ei_edge = (const int*)d_in[1];
  const int*   ei_sub  = (const int*)d_in[2];
  const int*   ei_ns   = (const int*)d_in[3];
  const int*   ei_sn   = (const int*)d_in[4];
  const int*   batch   = (const int*)d_in[7];
  const float* emb_w   = (const float*)d_in[8];
  const float* emb_b   = (const float*)d_in[9];
  const float* conv_wl = (const float*)d_in[10];
  const float* conv_bl = (const float*)d_in[11];
  const float* conv_wr = (const float*)d_in[12];
  const float* ln_g    = (const float*)d_in[13];
  const float* ln_b    = (const float*)d_in[14];
  const float* out_w   = (const float*)d_in[15];
  const float* out_b   = (const float*)d_in[16];
  float* out = (float*)d_out;

  const size_t HB = (size_t)N_NODES * H * sizeof(float);   // 25.6 MB
  char* ws = (char*)d_ws;
  float* h      = (float*)(ws);                        // fp32, written at j==3
  float* h0     = (float*)(ws + HB);                   // fp32 residual
  unsigned short* ab = (unsigned short*)(ws + 2 * HB); // [node][128] bf16 25.6MB
  // Build-phase overlays (dead once emb/gather run):
  unsigned* binned = (unsigned*)(ws);                            // 12.8 MB on h
  int*   cntT   = (int*)(ws + HB);                               // 1 MB on h0
  int*   offT   = (int*)(ws + HB + 0x100000);                    // 1 MB
  int*   bsumA  = (int*)(ws + HB + 0x300000);                    // 2 KB
  // Persistent:
  int*   deg4   = (int*)(ws + 3 * HB);                           // 1.6 MB
  int*   S      = (int*)(ws + 78400000);                         // 1.6 MB
  int*   slots  = (int*)(ws + 80000000);                         // 12.8 MB
  int*   bcnt   = (int*)(ws + 92800000);
  int*   boff   = (int*)(ws + 92800512);
  int*   bcur   = (int*)(ws + 92801024);
  int*   blist  = (int*)(ws + 92801536);                         // 1.6 MB
  float* pooled = (float*)(ws + 94401536);                       // 32 KB
  unsigned short* wbt = (unsigned short*)(ws + 94434304);        // 1.38 MB
  int*   tdesc  = (int*)(ws + 95810560);                         // 25.6 KB
  int*   ntiles = (int*)(ws + 95836160);                         // 16 B
  int*   toff   = (int*)(ws + 95836224);                         // 336 B

  const int* e0 = ei_edge, *e1 = ei_ns, *e2 = ei_sub, *e3 = ei_sn;
  const int MC = NBINS * NBINS;
  const int NB_MC = MC / 1024;              // 256
  const int NB_MK = (MKEYS + 1023) / 1024;  // 391

  hipMemsetAsync(bcnt, 0, 512, stream);

  // --- binned CSR build ---
  p1_bincount<<<NBINS, 256, 0, stream>>>(e0, e1, e2, e3, cntT);
  scan1<<<NB_MC, 256, 0, stream>>>(cntT, offT, bsumA, MC);
  scan2<<<1, 512, 0, stream>>>(bsumA, NB_MC);
  scan3<<<MC / 256, 256, 0, stream>>>(offT, bsumA, MC);
  p3_binscatter<<<NBINS, 256, 0, stream>>>(e0, e1, e2, e3, offT, binned);
  p4_deg<<<NBINS, 256, 0, stream>>>(binned, offT, deg4);
  scan1<<<NB_MK, 256, 0, stream>>>(deg4, S, bsumA, MKEYS);
  scan2<<<1, 512, 0, stream>>>(bsumA, NB_MK);
  scan3<<<(MKEYS + 255) / 256, 256, 0, stream>>>(S, bsumA, MKEYS);
  p6_slots<<<NBINS, 256, 0, stream>>>(binned, offT, S, slots);

  bucket_count<<<dim3((N_NODES + 255) / 256, 4), 256, 0, stream>>>(deg4, bcnt);
  bucket_scan<<<1, 128, 0, stream>>>(bcnt, boff, bcur, toff, ntiles);
  bucket_fill<<<dim3((N_NODES + 255) / 256, 4), 256, 0, stream>>>(deg4, bcur, blist);
  tile_fill<<<84, 256, 0, stream>>>(bcnt, boff, toff, tdesc);
  wconv_kernel<<<(84 * 64 * 128 + 255) / 256, 256, 0, stream>>>(conv_wl, conv_wr, wbt);

  // --- network ---
  emb_kernel<<<(N_NODES + 3) / 4, 256, 0, stream>>>(x, emb_w, emb_b, h0, ab);

  for (int j = 0; j < 4; ++j) {
    gather_kernel<<<(N_NODES + 3) / 4, 256, 0, stream>>>(
        S + j * N_NODES, deg4 + j * N_NODES, slots, ab);
    transform_kernel<<<MAX_TILES, 256, 0, stream>>>(
        h, ab, blist, tdesc, ntiles, wbt,
        conv_bl + (size_t)j * 21 * H, j, j < 3 ? 1 : 0, j == 3 ? 1 : 0);
  }

  hipMemsetAsync(pooled, 0, NUM_GRAPHS * H * sizeof(float), stream);
  ln_pool_kernel<<<POOL_BLOCKS, 1024, 0, stream>>>(h, h0, ln_g, ln_b, batch, pooled);
  out_kernel<<<NUM_GRAPHS, 64, 0, stream>>>(pooled, out_w, out_b, out);
}

// Round 12
// 521.323 us; speedup vs baseline: 1.6196x; 1.0177x over previous
//
#include <hip/hip_runtime.h>

#define N_NODES 100000
#define G_NODES 50000
#define N_EDGES 800000
#define H 64
#define F_IN 32
#define MAX_DEG 20
#define NUM_GRAPHS 128
#define LN_EPS 1e-5f
#define POOL_BLOCKS 256
#define MAX_TILES 1600

// Binned CSR build parameters: 512 bins over the 4*N key space.
#define NBINS 512
#define BPB 782            // keys per bin: 782*512 = 400384 >= 400000
#define CHUNK 6250         // edges per build block: 6250*512 = 3.2M
#define MKEYS (4 * N_NODES)
#define MEDGES (4 * N_EDGES)

typedef __attribute__((ext_vector_type(8))) short short8;
typedef __attribute__((ext_vector_type(4))) float float4v;

// bf16 helpers (RNE), no header dependency
static __device__ __forceinline__ unsigned short f2b(float f) {
  unsigned u = __float_as_uint(f);
  return (unsigned short)((u + 0x7fffu + ((u >> 16) & 1u)) >> 16);
}
static __device__ __forceinline__ float b2f(unsigned short b) {
  return __uint_as_float(((unsigned)b) << 16);
}

// ---------------- MFMA embedding: [64 x 32] @ [32 x 64] per tile ------------
// R11: shfl-chain emb was 42.7us (32-deep dependent ds_bpermute+fma). One
// K=32 MFMA step replaces it. Staging/out rows are wave-local -> no syncs.
// h0 written for ground nodes only (sole consumer ln_pool is ground-only).
__global__ __launch_bounds__(256) void emb_kernel(
    const float* __restrict__ x, const unsigned short* __restrict__ ewbt,
    const float* __restrict__ eb, float* __restrict__ h0,
    unsigned short* __restrict__ ab) {
  int base = blockIdx.x * 64;
  int nIn = min(64, N_NODES - base);
  int tid = threadIdx.x;
  int qw = tid >> 6, lane = tid & 63;
  __shared__ unsigned short aL[64 * 40];  // 5120 B, stride 40 breaks pow2 banks
  __shared__ float outF[64 * 68];         // 17408 B

  // stage: thread t -> node base + (t>>2), channels (t&3)*8 .. +8 (bf16)
  {
    int node = tid >> 2, chb = (tid & 3) * 8;
    unsigned short v8[8];
    if (node < nIn) {
      const float* xr = x + ((size_t)(base + node)) * F_IN + chb;
      float4 f0 = *(const float4*)(xr);
      float4 f1 = *(const float4*)(xr + 4);
      v8[0] = f2b(f0.x); v8[1] = f2b(f0.y); v8[2] = f2b(f0.z); v8[3] = f2b(f0.w);
      v8[4] = f2b(f1.x); v8[5] = f2b(f1.y); v8[6] = f2b(f1.z); v8[7] = f2b(f1.w);
    } else {
#pragma unroll
      for (int i = 0; i < 8; ++i) v8[i] = 0;
    }
    *(short8*)&aL[(tid >> 2) * 40 + chb] = *(short8*)v8;
  }
  // no __syncthreads: wave qw staged exactly rows [qw*16, qw*16+16)

  int m = lane & 15, quad = lane >> 4;
  short8 a = *(const short8*)&aL[(qw * 16 + m) * 40 + quad * 8];
  float4v acc[4];
#pragma unroll
  for (int t = 0; t < 4; ++t) {
    float bv = eb[t * 16 + m];
    acc[t] = (float4v){bv, bv, bv, bv};
  }
#pragma unroll
  for (int t = 0; t < 4; ++t) {
    short8 bf = *(const short8*)&ewbt[(t * 16 + m) * F_IN + quad * 8];
    acc[t] = __builtin_amdgcn_mfma_f32_16x16x32_bf16(a, bf, acc[t], 0, 0, 0);
  }
  // transpose via LDS (wave-local rows), then coalesced stores
#pragma unroll
  for (int t = 0; t < 4; ++t)
#pragma unroll
    for (int r = 0; r < 4; ++r)
      outF[(qw * 16 + quad * 4 + r) * 68 + t * 16 + m] = acc[t][r];
  for (int r = qw * 16; r < qw * 16 + 16; ++r) {
    if (r < nIn) {
      int node = base + r;
      float v = outF[r * 68 + lane];
      if (node < G_NODES) h0[node * H + lane] = v;
      ab[node * 128 + 64 + lane] = f2b(v);
    }
  }
}

// ---------------- weight preconvert: wbt[jb][ch][k] bf16, k = [WL | WR] ----
__global__ __launch_bounds__(256) void wconv_kernel(
    const float* __restrict__ wl, const float* __restrict__ wr,
    unsigned short* __restrict__ wbt) {
  int i = blockIdx.x * 256 + threadIdx.x;  // 84*64*128 = 688128
  if (i >= 84 * 64 * 128) return;
  int k = i & 127;
  int ch = (i >> 7) & 63;
  int jb = i >> 13;
  float v = (k < 64) ? wl[jb * 4096 + k * 64 + ch]
                     : wr[jb * 4096 + (k - 64) * 64 + ch];
  wbt[i] = f2b(v);
}

// emb weight preconvert: ewbt[ch][f] bf16 from emb_w[f][ch]
__global__ __launch_bounds__(256) void ewconv_kernel(
    const float* __restrict__ w, unsigned short* __restrict__ ewbt) {
  int i = blockIdx.x * 256 + threadIdx.x;
  if (i >= H * F_IN) return;
  int c = i >> 5, f = i & 31;
  ewbt[i] = f2b(w[f * H + c]);
}

// ---------------- binned CSR build (no scattered global atomics) ------------
__global__ __launch_bounds__(256) void p1_bincount(
    const int* __restrict__ e0, const int* __restrict__ e1,
    const int* __restrict__ e2, const int* __restrict__ e3,
    int* __restrict__ cntT) {
  __shared__ int hist[NBINS];
  int t = threadIdx.x, b = blockIdx.x;
  for (int i = t; i < NBINS; i += 256) hist[i] = 0;
  __syncthreads();
  int j = b >> 7;
  const int* ei = (j == 0) ? e0 : (j == 1) ? e1 : (j == 2) ? e2 : e3;
  int ebase = (b & 127) * CHUNK;
  for (int i = t; i < CHUNK; i += 256) {
    int dst = ei[N_EDGES + ebase + i];
    int key = j * N_NODES + dst;
    atomicAdd(&hist[key / BPB], 1);
  }
  __syncthreads();
  for (int i = t; i < NBINS; i += 256) cntT[i * NBINS + b] = hist[i];
}

__global__ __launch_bounds__(256) void p3_binscatter(
    const int* __restrict__ e0, const int* __restrict__ e1,
    const int* __restrict__ e2, const int* __restrict__ e3,
    const int* __restrict__ offT, unsigned* __restrict__ binned) {
  __shared__ int cur[NBINS];
  int t = threadIdx.x, b = blockIdx.x;
  for (int i = t; i < NBINS; i += 256) cur[i] = offT[i * NBINS + b];
  __syncthreads();
  int j = b >> 7;
  const int* ei = (j == 0) ? e0 : (j == 1) ? e1 : (j == 2) ? e2 : e3;
  int ebase = (b & 127) * CHUNK;
  for (int i = t; i < CHUNK; i += 256) {
    int src = ei[ebase + i];
    int dst = ei[N_EDGES + ebase + i];
    int key = j * N_NODES + dst;
    int bin = key / BPB;
    int pos = atomicAdd(&cur[bin], 1);
    binned[pos] = ((unsigned)(key - bin * BPB) << 17) | (unsigned)src;
  }
}

__global__ __launch_bounds__(256) void p4_deg(
    const unsigned* __restrict__ binned, const int* __restrict__ offT,
    int* __restrict__ deg4) {
  __shared__ int hist[BPB];
  int t = threadIdx.x, bin = blockIdx.x;
  for (int i = t; i < BPB; i += 256) hist[i] = 0;
  __syncthreads();
  int start = offT[bin * NBINS];
  int end = (bin == NBINS - 1) ? MEDGES : offT[(bin + 1) * NBINS];
  int kb = bin * BPB;
  for (int i = start + t; i < end; i += 256)
    atomicAdd(&hist[binned[i] >> 17], 1);
  __syncthreads();
  for (int i = t; i < BPB; i += 256)
    if (kb + i < MKEYS) deg4[kb + i] = hist[i];
}

__global__ __launch_bounds__(256) void p6_slots(
    const unsigned* __restrict__ binned, const int* __restrict__ offT,
    const int* __restrict__ S, int* __restrict__ slots) {
  __shared__ int cur[BPB];
  int t = threadIdx.x, bin = blockIdx.x;
  int kb = bin * BPB;
  for (int i = t; i < BPB; i += 256) cur[i] = (kb + i < MKEYS) ? S[kb + i] : 0;
  __syncthreads();
  int start = offT[bin * NBINS];
  int end = (bin == NBINS - 1) ? MEDGES : offT[(bin + 1) * NBINS];
  for (int i = start + t; i < end; i += 256) {
    unsigned v = binned[i];
    int pos = atomicAdd(&cur[v >> 17], 1);
    slots[pos] = (int)(v & 0x1ffffu);
  }
}

// ---------------- hierarchical exclusive scan (1024 elems/block) ------------
__global__ __launch_bounds__(256) void scan1(
    const int* __restrict__ in, int* __restrict__ S, int* __restrict__ bsum, int M) {
  int t = threadIdx.x;
  int base = blockIdx.x * 1024 + t * 4;
  int v0 = 0, v1 = 0, v2 = 0, v3 = 0;
  if (base + 3 < M) {
    int4 q = *(const int4*)(in + base);
    v0 = q.x; v1 = q.y; v2 = q.z; v3 = q.w;
  } else {
    if (base     < M) v0 = in[base];
    if (base + 1 < M) v1 = in[base + 1];
    if (base + 2 < M) v2 = in[base + 2];
    if (base + 3 < M) v3 = in[base + 3];
  }
  int s = v0 + v1 + v2 + v3;
  int incl = s;
#pragma unroll
  for (int off = 1; off < 64; off <<= 1) {
    int y = __shfl_up(incl, off, 64);
    if ((t & 63) >= off) incl += y;
  }
  __shared__ int wtot[4];
  if ((t & 63) == 63) wtot[t >> 6] = incl;
  __syncthreads();
  int wbase = 0;
  for (int w = 0; w < (t >> 6); ++w) wbase += wtot[w];
  int ex = wbase + incl - s;
  if (base < M) {
    int eo0 = ex, eo1 = ex + v0, eo2 = ex + v0 + v1, eo3 = ex + v0 + v1 + v2;
    if (base + 3 < M) {
      *(int4*)(S + base) = make_int4(eo0, eo1, eo2, eo3);
    } else {
      S[base] = eo0;
      if (base + 1 < M) S[base + 1] = eo1;
      if (base + 2 < M) S[base + 2] = eo2;
    }
  }
  if (t == 255) bsum[blockIdx.x] = wbase + incl;
}

__global__ __launch_bounds__(512) void scan2(int* __restrict__ bsum, int nb) {
  int t = threadIdx.x;
  int v = (t < nb) ? bsum[t] : 0;
  int incl = v;
#pragma unroll
  for (int off = 1; off < 64; off <<= 1) {
    int y = __shfl_up(incl, off, 64);
    if ((t & 63) >= off) incl += y;
  }
  __shared__ int wtot[8];
  if ((t & 63) == 63) wtot[t >> 6] = incl;
  __syncthreads();
  int wbase = 0;
  for (int w = 0; w < (t >> 6); ++w) wbase += wtot[w];
  if (t < nb) bsum[t] = wbase + incl - v;
}

__global__ __launch_bounds__(256) void scan3(
    int* __restrict__ S, const int* __restrict__ bsum, int M) {
  int i = blockIdx.x * 256 + threadIdx.x;
  if (i >= M) return;
  S[i] = S[i] + bsum[i >> 10];
}

// ---------------- degree-bucket lists (LDS-aggregated) ----------------------
__global__ __launch_bounds__(256) void bucket_count(
    const int* __restrict__ deg4, int* __restrict__ bcnt) {
  __shared__ int hist[21];
  int t = threadIdx.x;
  if (t < 21) hist[t] = 0;
  __syncthreads();
  int node = blockIdx.x * 256 + t;
  int j = blockIdx.y;
  if (node < N_NODES) {
    int d = deg4[j * N_NODES + node];
    int b = d < MAX_DEG ? d : MAX_DEG;
    atomicAdd(&hist[b], 1);
  }
  __syncthreads();
  if (t < 21 && hist[t]) atomicAdd(&bcnt[j * 21 + t], hist[t]);
}

// scan 84 bucket counts -> boff/bcur, AND per-set tile offsets -> toff/ntiles
__global__ __launch_bounds__(128) void bucket_scan(
    const int* __restrict__ bcnt, int* __restrict__ boff, int* __restrict__ bcur,
    int* __restrict__ toff, int* __restrict__ ntiles) {
  int t = threadIdx.x;
  int v = (t < 84) ? bcnt[t] : 0;
  int incl = v;
#pragma unroll
  for (int off = 1; off < 64; off <<= 1) {
    int y = __shfl_up(incl, off, 64);
    if ((t & 63) >= off) incl += y;
  }
  __shared__ int wt[2];
  __shared__ int nt[84];
  if ((t & 63) == 63) wt[t >> 6] = incl;
  if (t < 84) nt[t] = (v + 63) >> 6;
  __syncthreads();
  int wbase = (t >> 6) ? wt[0] : 0;
  if (t < 84) {
    int ex = wbase + incl - v;
    boff[t] = ex;
    bcur[t] = ex;
  }
  if (t < 4) {
    int acc = 0;
    for (int bb = 0; bb < 21; ++bb) {
      toff[t * 21 + bb] = acc;
      acc += nt[t * 21 + bb];
    }
    ntiles[t] = acc;
  }
}

__global__ __launch_bounds__(256) void bucket_fill(
    const int* __restrict__ deg4, int* __restrict__ bcur, int* __restrict__ blist) {
  __shared__ int hist[21];
  __shared__ int base[21];
  int t = threadIdx.x;
  if (t < 21) hist[t] = 0;
  __syncthreads();
  int node = blockIdx.x * 256 + t;
  int j = blockIdx.y;
  int b = 0, lpos = 0;
  bool valid = (node < N_NODES);
  if (valid) {
    int d = deg4[j * N_NODES + node];
    b = d < MAX_DEG ? d : MAX_DEG;
    lpos = atomicAdd(&hist[b], 1);
  }
  __syncthreads();
  if (t < 21 && hist[t]) base[t] = atomicAdd(&bcur[j * 21 + t], hist[t]);
  __syncthreads();
  if (valid) blist[base[b] + lpos] = node;
}

// tile_fill: one block per (j,b); desc = (blist_pos << 12) | (bucket << 7) | nIn
__global__ __launch_bounds__(256) void tile_fill(
    const int* __restrict__ bcnt, const int* __restrict__ boff,
    const int* __restrict__ toff, int* __restrict__ tdesc) {
  int jb = blockIdx.x;           // 0..83
  int j = jb / 21, b = jb % 21;
  int cnt = bcnt[jb];
  int off = boff[jb];
  int tb = toff[jb];
  int nt = (cnt + 63) >> 6;
  for (int i = threadIdx.x; i < nt; i += 256) {
    int s = i << 6;
    int nIn = min(64, cnt - s);
    tdesc[j * MAX_TILES + tb + i] = ((off + s) << 12) | (b << 7) | nIn;
  }
}

// ---------------- gather: ab hsum-half = sum of neighbor self-halves --------
// Quad-edge: quarter-wave (16 lanes) per edge parity, lane loads uint2 (4 ch).
__global__ __launch_bounds__(256) void gather_kernel(
    const int* __restrict__ S, const int* __restrict__ deg,
    const int* __restrict__ slots, unsigned short* __restrict__ ab) {
  int node = blockIdx.x * 4 + (threadIdx.x >> 6);
  int lane = threadIdx.x & 63;
  if (node >= N_NODES) return;
  int q = lane >> 4, cl = lane & 15;  // channels [4*cl, 4*cl+4)
  int off = S[node];
  int dg = deg[node];
  float c0 = 0.f, c1 = 0.f, c2 = 0.f, c3 = 0.f;
  int e = q;
  for (; e + 4 < dg; e += 8) {
    int n0 = slots[off + e];
    int n1 = slots[off + e + 4];
    uint2 p0 = *(const uint2*)&ab[n0 * 128 + 64 + 4 * cl];
    uint2 p1 = *(const uint2*)&ab[n1 * 128 + 64 + 4 * cl];
    c0 += b2f((unsigned short)p0.x) + b2f((unsigned short)p1.x);
    c1 += b2f((unsigned short)(p0.x >> 16)) + b2f((unsigned short)(p1.x >> 16));
    c2 += b2f((unsigned short)p0.y) + b2f((unsigned short)p1.y);
    c3 += b2f((unsigned short)(p0.y >> 16)) + b2f((unsigned short)(p1.y >> 16));
  }
  for (; e < dg; e += 4) {
    uint2 p0 = *(const uint2*)&ab[slots[off + e] * 128 + 64 + 4 * cl];
    c0 += b2f((unsigned short)p0.x);
    c1 += b2f((unsigned short)(p0.x >> 16));
    c2 += b2f((unsigned short)p0.y);
    c3 += b2f((unsigned short)(p0.y >> 16));
  }
  c0 += __shfl_xor(c0, 16, 64); c0 += __shfl_xor(c0, 32, 64);
  c1 += __shfl_xor(c1, 16, 64); c1 += __shfl_xor(c1, 32, 64);
  c2 += __shfl_xor(c2, 16, 64); c2 += __shfl_xor(c2, 32, 64);
  c3 += __shfl_xor(c3, 16, 64); c3 += __shfl_xor(c3, 32, 64);
  if (q == 0) {
    uint2 o;
    o.x = (unsigned)f2b(c0) | ((unsigned)f2b(c1) << 16);
    o.y = (unsigned)f2b(c2) | ((unsigned)f2b(c3) << 16);
    *(uint2*)&ab[node * 128 + 4 * cl] = o;
  }
}

// ---------------- MFMA transform: [64 x 128] @ [128 x 64] per tile ----------
// j<3: write bf16 self-half only; j==3: write fp32 h for GROUND nodes only
// (ln_pool is the sole consumer and reads nodes < G_NODES).
__global__ __launch_bounds__(256) void transform_kernel(
    float* __restrict__ h, unsigned short* __restrict__ ab,
    const int* __restrict__ blist, const int* __restrict__ tdesc,
    const int* __restrict__ ntiles, const unsigned short* __restrict__ wbt,
    const float* __restrict__ bl, int j, int do_relu, int last) {
  if ((int)blockIdx.x >= ntiles[j]) return;
  int d = tdesc[j * MAX_TILES + blockIdx.x];
  int nIn = d & 127;
  int b = (d >> 7) & 31;
  const int* lst = blist + (d >> 12);

  int tid = threadIdx.x;
  int qw = tid >> 6, lane = tid & 63;

  if (b == 0) {
    for (int r = qw * 16; r < qw * 16 + 16; ++r) {
      if (r < nIn) {
        int node = lst[r];
        float v = b2f(ab[node * 128 + 64 + lane]);
        if (do_relu) v = fmaxf(v, 0.f);
        if (last) {
          if (node < G_NODES) h[node * H + lane] = v;
        } else {
          ab[node * 128 + 64 + lane] = f2b(v);
        }
      }
    }
    return;
  }

  __shared__ unsigned short aL[64 * 136];  // 17408 B; reused as fp32[64*68]
  __shared__ int nodeS[64];

  for (int r = qw * 16; r < qw * 16 + 16; ++r) {
    int node = (r < nIn) ? lst[r] : -1;
    if (lane == 0) nodeS[r] = node;
    unsigned q = 0;
    if (node >= 0) q = *(const unsigned*)&ab[node * 128 + 2 * lane];
    *(unsigned*)&aL[r * 136 + 2 * lane] = q;
  }
  __syncthreads();

  int m = lane & 15, quad = lane >> 4;
  const unsigned short* wbase = wbt + (size_t)(j * 21 + b) * 64 * 128;
  float4v acc[4];
#pragma unroll
  for (int t = 0; t < 4; ++t) {
    float bv = bl[b * 64 + t * 16 + m];
    acc[t] = (float4v){bv, bv, bv, bv};
  }
#pragma unroll
  for (int ks = 0; ks < 4; ++ks) {
    short8 a = *(const short8*)&aL[(qw * 16 + m) * 136 + ks * 32 + quad * 8];
#pragma unroll
    for (int t = 0; t < 4; ++t) {
      short8 bf = *(const short8*)&wbase[(t * 16 + m) * 128 + ks * 32 + quad * 8];
      acc[t] = __builtin_amdgcn_mfma_f32_16x16x32_bf16(a, bf, acc[t], 0, 0, 0);
    }
  }
  if (do_relu) {
#pragma unroll
    for (int t = 0; t < 4; ++t)
#pragma unroll
      for (int r = 0; r < 4; ++r) acc[t][r] = fmaxf(acc[t][r], 0.f);
  }
  __syncthreads();
  float* outF = (float*)aL;
#pragma unroll
  for (int t = 0; t < 4; ++t)
#pragma unroll
    for (int r = 0; r < 4; ++r)
      outF[(qw * 16 + quad * 4 + r) * 68 + t * 16 + m] = acc[t][r];
  __syncthreads();
  if (last) {
    for (int r = qw * 16; r < qw * 16 + 16; ++r)
      if (r < nIn && nodeS[r] < G_NODES)
        h[nodeS[r] * H + lane] = outF[r * 68 + lane];
  } else {
    for (int r = qw * 16; r < qw * 16 + 16; ++r)
      if (r < nIn) ab[nodeS[r] * 128 + 64 + lane] = f2b(outF[r * 68 + lane]);
  }
}

// ---------------- fused layernorm + residual + ground-node pool -------------
__global__ __launch_bounds__(1024) void ln_pool_kernel(
    const float* __restrict__ h, const float* __restrict__ h0,
    const float* __restrict__ g, const float* __restrict__ b,
    const int* __restrict__ batch, float* __restrict__ pooled) {
  __shared__ float sm[NUM_GRAPHS * H];  // 32 KB
  int t = threadIdx.x;
  for (int i = t; i < NUM_GRAPHS * H; i += 1024) sm[i] = 0.f;
  __syncthreads();
  int lane = t & 63, w = t >> 6;  // 16 waves
  const int per = (G_NODES + POOL_BLOCKS - 1) / POOL_BLOCKS;
  int start = blockIdx.x * per;
  int end = min(start + per, G_NODES);
  for (int node = start + w; node < end; node += 16) {
    int idx = node * H + lane;
    float v = h[idx];
    float s = v;
#pragma unroll
    for (int off = 32; off > 0; off >>= 1) s += __shfl_xor(s, off, 64);
    float mu = s * (1.0f / H);
    float dv = v - mu;
    float q = dv * dv;
#pragma unroll
    for (int off = 32; off > 0; off >>= 1) q += __shfl_xor(q, off, 64);
    float inv = rsqrtf(q * (1.0f / H) + LN_EPS);
    float r = dv * inv * g[lane] + b[lane] + h0[idx];
    atomicAdd(&sm[batch[node] * H + lane], r);
  }
  __syncthreads();
  for (int i = t; i < NUM_GRAPHS * H; i += 1024) {
    float v = sm[i];
    if (v != 0.f) atomicAdd(&pooled[i], v);
  }
}

__global__ __launch_bounds__(64) void out_kernel(
    const float* __restrict__ pooled, const float* __restrict__ w,
    const float* __restrict__ b, float* __restrict__ out) {
  int gph = blockIdx.x;
  int c = threadIdx.x;
  float v = pooled[gph * H + c] * w[c];
#pragma unroll
  for (int off = 32; off > 0; off >>= 1) v += __shfl_xor(v, off, 64);
  if (c == 0) out[gph] = v + b[0];
}

extern "C" void kernel_launch(void* const* d_in, const int* in_sizes, int n_in,
                              void* d_out, int out_size, void* d_ws, size_t ws_size,
                              hipStream_t stream) {
  const float* x       = (const float*)d_in[0];
  const int*   ei_edge = (const int*)d_in[1];
  const int*   ei_sub  = (const int*)d_in[2];
  const int*   ei_ns   = (const int*)d_in[3];
  const int*   ei_sn   = (const int*)d_in[4];
  const int*   batch   = (const int*)d_in[7];
  const float* emb_w   = (const float*)d_in[8];
  const float* emb_b   = (const float*)d_in[9];
  const float* conv_wl = (const float*)d_in[10];
  const float* conv_bl = (const float*)d_in[11];
  const float* conv_wr = (const float*)d_in[12];
  const float* ln_g    = (const float*)d_in[13];
  const float* ln_b    = (const float*)d_in[14];
  const float* out_w   = (const float*)d_in[15];
  const float* out_b   = (const float*)d_in[16];
  float* out = (float*)d_out;

  const size_t HB = (size_t)N_NODES * H * sizeof(float);   // 25.6 MB
  char* ws = (char*)d_ws;
  float* h      = (float*)(ws);                        // fp32, ground, j==3
  float* h0     = (float*)(ws + HB);                   // fp32 residual (ground)
  unsigned short* ab = (unsigned short*)(ws + 2 * HB); // [node][128] bf16 25.6MB
  // Build-phase overlays (dead once emb/gather run):
  unsigned* binned = (unsigned*)(ws);                            // 12.8 MB on h
  int*   cntT   = (int*)(ws + HB);                               // 1 MB on h0
  int*   offT   = (int*)(ws + HB + 0x100000);                    // 1 MB
  int*   bsumA  = (int*)(ws + HB + 0x300000);                    // 2 KB
  // Persistent:
  int*   deg4   = (int*)(ws + 3 * HB);                           // 1.6 MB
  int*   S      = (int*)(ws + 78400000);                         // 1.6 MB
  int*   slots  = (int*)(ws + 80000000);                         // 12.8 MB
  int*   bcnt   = (int*)(ws + 92800000);
  int*   boff   = (int*)(ws + 92800512);
  int*   bcur   = (int*)(ws + 92801024);
  int*   blist  = (int*)(ws + 92801536);                         // 1.6 MB
  float* pooled = (float*)(ws + 94401536);                       // 32 KB
  unsigned short* wbt = (unsigned short*)(ws + 94434304);        // 1.38 MB
  int*   tdesc  = (int*)(ws + 95810560);                         // 25.6 KB
  int*   ntiles = (int*)(ws + 95836160);                         // 16 B
  int*   toff   = (int*)(ws + 95836224);                         // 336 B
  unsigned short* ewbt = (unsigned short*)(ws + 95836608);       // 4 KB

  const int* e0 = ei_edge, *e1 = ei_ns, *e2 = ei_sub, *e3 = ei_sn;
  const int MC = NBINS * NBINS;
  const int NB_MC = MC / 1024;              // 256
  const int NB_MK = (MKEYS + 1023) / 1024;  // 391

  hipMemsetAsync(bcnt, 0, 512, stream);

  // --- binned CSR build ---
  p1_bincount<<<NBINS, 256, 0, stream>>>(e0, e1, e2, e3, cntT);
  scan1<<<NB_MC, 256, 0, stream>>>(cntT, offT, bsumA, MC);
  scan2<<<1, 512, 0, stream>>>(bsumA, NB_MC);
  scan3<<<MC / 256, 256, 0, stream>>>(offT, bsumA, MC);
  p3_binscatter<<<NBINS, 256, 0, stream>>>(e0, e1, e2, e3, offT, binned);
  p4_deg<<<NBINS, 256, 0, stream>>>(binned, offT, deg4);
  scan1<<<NB_MK, 256, 0, stream>>>(deg4, S, bsumA, MKEYS);
  scan2<<<1, 512, 0, stream>>>(bsumA, NB_MK);
  scan3<<<(MKEYS + 255) / 256, 256, 0, stream>>>(S, bsumA, MKEYS);
  p6_slots<<<NBINS, 256, 0, stream>>>(binned, offT, S, slots);

  bucket_count<<<dim3((N_NODES + 255) / 256, 4), 256, 0, stream>>>(deg4, bcnt);
  bucket_scan<<<1, 128, 0, stream>>>(bcnt, boff, bcur, toff, ntiles);
  bucket_fill<<<dim3((N_NODES + 255) / 256, 4), 256, 0, stream>>>(deg4, bcur, blist);
  tile_fill<<<84, 256, 0, stream>>>(bcnt, boff, toff, tdesc);
  wconv_kernel<<<(84 * 64 * 128 + 255) / 256, 256, 0, stream>>>(conv_wl, conv_wr, wbt);
  ewconv_kernel<<<(H * F_IN + 255) / 256, 256, 0, stream>>>(emb_w, ewbt);

  // --- network ---
  emb_kernel<<<(N_NODES + 63) / 64, 256, 0, stream>>>(x, ewbt, emb_b, h0, ab);

  for (int j = 0; j < 4; ++j) {
    gather_kernel<<<(N_NODES + 3) / 4, 256, 0, stream>>>(
        S + j * N_NODES, deg4 + j * N_NODES, slots, ab);
    transform_kernel<<<MAX_TILES, 256, 0, stream>>>(
        h, ab, blist, tdesc, ntiles, wbt,
        conv_bl + (size_t)j * 21 * H, j, j < 3 ? 1 : 0, j == 3 ? 1 : 0);
  }

  hipMemsetAsync(pooled, 0, NUM_GRAPHS * H * sizeof(float), stream);
  ln_pool_kernel<<<POOL_BLOCKS, 1024, 0, stream>>>(h, h0, ln_g, ln_b, batch, pooled);
  out_kernel<<<NUM_GRAPHS, 64, 0, stream>>>(pooled, out_w, out_b, out);
}

// Round 13
// 501.929 us; speedup vs baseline: 1.6821x; 1.0386x over previous
//
#include <hip/hip_runtime.h>

#define N_NODES 100000
#define G_NODES 50000
#define N_EDGES 800000
#define H 64
#define F_IN 32
#define MAX_DEG 20
#define NUM_GRAPHS 128
#define LN_EPS 1e-5f
#define POOL_BLOCKS 256
#define MAX_TILES 1600

// Binned CSR build parameters: 512 bins over the 4*N key space.
#define NBINS 512
#define BPB 782            // keys per bin: 782*512 = 400384 >= 400000
#define CHUNK 6250         // edges per build block: 6250*512 = 3.2M
#define MKEYS (4 * N_NODES)
#define MEDGES (4 * N_EDGES)

typedef __attribute__((ext_vector_type(8))) short short8;
typedef __attribute__((ext_vector_type(4))) float float4v;

// bf16 helpers (RNE), no header dependency
static __device__ __forceinline__ unsigned short f2b(float f) {
  unsigned u = __float_as_uint(f);
  return (unsigned short)((u + 0x7fffu + ((u >> 16) & 1u)) >> 16);
}
static __device__ __forceinline__ float b2f(unsigned short b) {
  return __uint_as_float(((unsigned)b) << 16);
}

// ---------------- MFMA embedding + pooled zero-init -------------------------
__global__ __launch_bounds__(256) void emb_kernel(
    const float* __restrict__ x, const unsigned short* __restrict__ ewbt,
    const float* __restrict__ eb, float* __restrict__ h0,
    unsigned short* __restrict__ ab, float* __restrict__ pooled) {
  int tid = threadIdx.x;
  if (blockIdx.x == 0) {  // fold pooled memset (consumed much later by ln_pool)
    for (int i = tid; i < NUM_GRAPHS * H; i += 256) pooled[i] = 0.f;
  }
  int base = blockIdx.x * 64;
  int nIn = min(64, N_NODES - base);
  int qw = tid >> 6, lane = tid & 63;
  __shared__ unsigned short aL[64 * 40];  // stride 40 breaks pow2 banks
  __shared__ float outF[64 * 68];

  {
    int node = tid >> 2, chb = (tid & 3) * 8;
    unsigned short v8[8];
    if (node < nIn) {
      const float* xr = x + ((size_t)(base + node)) * F_IN + chb;
      float4 f0 = *(const float4*)(xr);
      float4 f1 = *(const float4*)(xr + 4);
      v8[0] = f2b(f0.x); v8[1] = f2b(f0.y); v8[2] = f2b(f0.z); v8[3] = f2b(f0.w);
      v8[4] = f2b(f1.x); v8[5] = f2b(f1.y); v8[6] = f2b(f1.z); v8[7] = f2b(f1.w);
    } else {
#pragma unroll
      for (int i = 0; i < 8; ++i) v8[i] = 0;
    }
    *(short8*)&aL[(tid >> 2) * 40 + chb] = *(short8*)v8;
  }
  // no __syncthreads: wave qw staged exactly rows [qw*16, qw*16+16)

  int m = lane & 15, quad = lane >> 4;
  short8 a = *(const short8*)&aL[(qw * 16 + m) * 40 + quad * 8];
  float4v acc[4];
#pragma unroll
  for (int t = 0; t < 4; ++t) {
    float bv = eb[t * 16 + m];
    acc[t] = (float4v){bv, bv, bv, bv};
  }
#pragma unroll
  for (int t = 0; t < 4; ++t) {
    short8 bf = *(const short8*)&ewbt[(t * 16 + m) * F_IN + quad * 8];
    acc[t] = __builtin_amdgcn_mfma_f32_16x16x32_bf16(a, bf, acc[t], 0, 0, 0);
  }
#pragma unroll
  for (int t = 0; t < 4; ++t)
#pragma unroll
    for (int r = 0; r < 4; ++r)
      outF[(qw * 16 + quad * 4 + r) * 68 + t * 16 + m] = acc[t][r];
  for (int r = qw * 16; r < qw * 16 + 16; ++r) {
    if (r < nIn) {
      int node = base + r;
      float v = outF[r * 68 + lane];
      if (node < G_NODES) h0[node * H + lane] = v;
      ab[node * 128 + 64 + lane] = f2b(v);
    }
  }
}

// ---------------- weight preconvert (conv + emb in one grid) ----------------
__global__ __launch_bounds__(256) void wconv_kernel(
    const float* __restrict__ wl, const float* __restrict__ wr,
    const float* __restrict__ ew, unsigned short* __restrict__ wbt,
    unsigned short* __restrict__ ewbt) {
  int i = blockIdx.x * 256 + threadIdx.x;
  if (i < 84 * 64 * 128) {
    int k = i & 127;
    int ch = (i >> 7) & 63;
    int jb = i >> 13;
    float v = (k < 64) ? wl[jb * 4096 + k * 64 + ch]
                       : wr[jb * 4096 + (k - 64) * 64 + ch];
    wbt[i] = f2b(v);
  } else if (i < 84 * 64 * 128 + H * F_IN) {
    int ii = i - 84 * 64 * 128;
    int c = ii >> 5, f = ii & 31;
    ewbt[ii] = f2b(ew[f * H + c]);
  }
}

// ---------------- binned CSR build (no scattered global atomics) ------------
__global__ __launch_bounds__(256) void p1_bincount(
    const int* __restrict__ e0, const int* __restrict__ e1,
    const int* __restrict__ e2, const int* __restrict__ e3,
    int* __restrict__ cntT) {
  __shared__ int hist[NBINS];
  int t = threadIdx.x, b = blockIdx.x;
  for (int i = t; i < NBINS; i += 256) hist[i] = 0;
  __syncthreads();
  int j = b >> 7;
  const int* ei = (j == 0) ? e0 : (j == 1) ? e1 : (j == 2) ? e2 : e3;
  int ebase = (b & 127) * CHUNK;
  for (int i = t; i < CHUNK; i += 256) {
    int dst = ei[N_EDGES + ebase + i];
    int key = j * N_NODES + dst;
    atomicAdd(&hist[key / BPB], 1);
  }
  __syncthreads();
  for (int i = t; i < NBINS; i += 256) cntT[i * NBINS + b] = hist[i];
}

// p3 with fused scan3-correction: offT raw + bsumA applied inline.
__global__ __launch_bounds__(256) void p3_binscatter(
    const int* __restrict__ e0, const int* __restrict__ e1,
    const int* __restrict__ e2, const int* __restrict__ e3,
    const int* __restrict__ offT, const int* __restrict__ bsumA,
    unsigned* __restrict__ binned) {
  __shared__ int cur[NBINS];
  int t = threadIdx.x, b = blockIdx.x;
  for (int i = t; i < NBINS; i += 256) {
    int idx = i * NBINS + b;
    cur[i] = offT[idx] + bsumA[idx >> 10];
  }
  __syncthreads();
  int j = b >> 7;
  const int* ei = (j == 0) ? e0 : (j == 1) ? e1 : (j == 2) ? e2 : e3;
  int ebase = (b & 127) * CHUNK;
  for (int i = t; i < CHUNK; i += 256) {
    int src = ei[ebase + i];
    int dst = ei[N_EDGES + ebase + i];
    int key = j * N_NODES + dst;
    int bin = key / BPB;
    int pos = atomicAdd(&cur[bin], 1);
    binned[pos] = ((unsigned)(key - bin * BPB) << 17) | (unsigned)src;
  }
}

// p46: per bin, fused deg4 + bucket-hist + LOCAL CSR scan (S[key] = binStart +
// local prefix — valid because slots is key-ordered and bins are contiguous
// key ranges) + slot scatter. Replaces p4, global MKEYS scan x3, p6, and
// bucket_count (R12: pipeline was dispatch-gap-bound, ~6us x 25 launches).
__global__ __launch_bounds__(256) void p46_kernel(
    const unsigned* __restrict__ binned, const int* __restrict__ offT,
    const int* __restrict__ bsumA, int* __restrict__ deg4,
    int* __restrict__ S, int* __restrict__ slots, int* __restrict__ bcnt) {
  __shared__ int hist[BPB];
  __shared__ int cur[BPB];
  __shared__ int bh[84];
  __shared__ int wtot[4];
  int t = threadIdx.x, bin = blockIdx.x;
  int kb = bin * BPB;
  for (int i = t; i < BPB; i += 256) hist[i] = 0;
  if (t < 84) bh[t] = 0;
  __syncthreads();
  int i0 = bin * NBINS;
  int start = offT[i0] + bsumA[i0 >> 10];
  int end;
  if (bin == NBINS - 1) {
    end = MEDGES;
  } else {
    int i1 = (bin + 1) * NBINS;
    end = offT[i1] + bsumA[i1 >> 10];
  }
  for (int i = start + t; i < end; i += 256)
    atomicAdd(&hist[binned[i] >> 17], 1);
  __syncthreads();
  // deg4 (coalesced) + per-(j,bucket) histogram
  for (int i = t; i < BPB; i += 256) {
    int key = kb + i;
    if (key < MKEYS) {
      int d = hist[i];
      deg4[key] = d;
      int j = key / N_NODES;
      int b = d < MAX_DEG ? d : MAX_DEG;
      atomicAdd(&bh[j * 21 + b], 1);
    }
  }
  // local exclusive scan of hist -> absolute slot cursors
  int base = t * 4;
  int v0 = 0, v1 = 0, v2 = 0, v3 = 0;
  if (base < BPB) {
    v0 = hist[base];
    v1 = (base + 1 < BPB) ? hist[base + 1] : 0;
    v2 = (base + 2 < BPB) ? hist[base + 2] : 0;
    v3 = (base + 3 < BPB) ? hist[base + 3] : 0;
  }
  int s = v0 + v1 + v2 + v3;
  int incl = s;
#pragma unroll
  for (int off = 1; off < 64; off <<= 1) {
    int y = __shfl_up(incl, off, 64);
    if ((t & 63) >= off) incl += y;
  }
  if ((t & 63) == 63) wtot[t >> 6] = incl;
  __syncthreads();
  int wbase = 0;
  for (int w = 0; w < (t >> 6); ++w) wbase += wtot[w];
  int ex = start + wbase + incl - s;
  if (base < BPB) {
    cur[base] = ex;
    if (base + 1 < BPB) cur[base + 1] = ex + v0;
    if (base + 2 < BPB) cur[base + 2] = ex + v0 + v1;
    if (base + 3 < BPB) cur[base + 3] = ex + v0 + v1 + v2;
  }
  __syncthreads();
  for (int i = t; i < BPB; i += 256)
    if (kb + i < MKEYS) S[kb + i] = cur[i];
  if (t < 84 && bh[t]) atomicAdd(&bcnt[t], bh[t]);
  __syncthreads();  // S reads of cur done before scatter mutates it
  for (int i = start + t; i < end; i += 256) {
    unsigned v = binned[i];
    int pos = atomicAdd(&cur[v >> 17], 1);
    slots[pos] = (int)(v & 0x1ffffu);
  }
}

// ---------------- hierarchical exclusive scan (MC only) ---------------------
__global__ __launch_bounds__(256) void scan1(
    const int* __restrict__ in, int* __restrict__ S, int* __restrict__ bsum, int M) {
  int t = threadIdx.x;
  int base = blockIdx.x * 1024 + t * 4;
  int v0 = 0, v1 = 0, v2 = 0, v3 = 0;
  if (base + 3 < M) {
    int4 q = *(const int4*)(in + base);
    v0 = q.x; v1 = q.y; v2 = q.z; v3 = q.w;
  } else {
    if (base     < M) v0 = in[base];
    if (base + 1 < M) v1 = in[base + 1];
    if (base + 2 < M) v2 = in[base + 2];
    if (base + 3 < M) v3 = in[base + 3];
  }
  int s = v0 + v1 + v2 + v3;
  int incl = s;
#pragma unroll
  for (int off = 1; off < 64; off <<= 1) {
    int y = __shfl_up(incl, off, 64);
    if ((t & 63) >= off) incl += y;
  }
  __shared__ int wtot[4];
  if ((t & 63) == 63) wtot[t >> 6] = incl;
  __syncthreads();
  int wbase = 0;
  for (int w = 0; w < (t >> 6); ++w) wbase += wtot[w];
  int ex = wbase + incl - s;
  if (base < M) {
    int eo0 = ex, eo1 = ex + v0, eo2 = ex + v0 + v1, eo3 = ex + v0 + v1 + v2;
    if (base + 3 < M) {
      *(int4*)(S + base) = make_int4(eo0, eo1, eo2, eo3);
    } else {
      S[base] = eo0;
      if (base + 1 < M) S[base + 1] = eo1;
      if (base + 2 < M) S[base + 2] = eo2;
    }
  }
  if (t == 255) bsum[blockIdx.x] = wbase + incl;
}

// scan2 also zero-inits bcnt (consumed later by p46's atomics).
__global__ __launch_bounds__(512) void scan2(
    int* __restrict__ bsum, int nb, int* __restrict__ bcnt) {
  int t = threadIdx.x;
  if (t < 84) bcnt[t] = 0;
  int v = (t < nb) ? bsum[t] : 0;
  int incl = v;
#pragma unroll
  for (int off = 1; off < 64; off <<= 1) {
    int y = __shfl_up(incl, off, 64);
    if ((t & 63) >= off) incl += y;
  }
  __shared__ int wtot[8];
  if ((t & 63) == 63) wtot[t >> 6] = incl;
  __syncthreads();
  int wbase = 0;
  for (int w = 0; w < (t >> 6); ++w) wbase += wtot[w];
  if (t < nb) bsum[t] = wbase + incl - v;
}

// ---------------- bucket scan + tile descriptors (one block) ----------------
__global__ __launch_bounds__(128) void bucket_scan(
    const int* __restrict__ bcnt, int* __restrict__ boff, int* __restrict__ bcur,
    int* __restrict__ ntiles, int* __restrict__ tdesc) {
  __shared__ int wt[2];
  __shared__ int exL[84], cntL[84], toffL[84];
  int t = threadIdx.x;
  int v = (t < 84) ? bcnt[t] : 0;
  int incl = v;
#pragma unroll
  for (int off = 1; off < 64; off <<= 1) {
    int y = __shfl_up(incl, off, 64);
    if ((t & 63) >= off) incl += y;
  }
  if ((t & 63) == 63) wt[t >> 6] = incl;
  __syncthreads();
  int wbase = (t >> 6) ? wt[0] : 0;
  if (t < 84) {
    int ex = wbase + incl - v;
    boff[t] = ex;
    bcur[t] = ex;
    exL[t] = ex;
    cntL[t] = v;
  }
  __syncthreads();
  if (t < 4) {
    int acc = 0;
    for (int bb = 0; bb < 21; ++bb) {
      toffL[t * 21 + bb] = acc;
      acc += (cntL[t * 21 + bb] + 63) >> 6;
    }
    ntiles[t] = acc;
  }
  __syncthreads();
  for (int jb = 0; jb < 84; ++jb) {
    int j = jb / 21, b = jb - j * 21;
    int cnt = cntL[jb], off = exL[jb], tb = toffL[jb];
    int nt = (cnt + 63) >> 6;
    for (int i = t; i < nt; i += 128) {
      int s2 = i << 6;
      int nIn = min(64, cnt - s2);
      tdesc[j * MAX_TILES + tb + i] = ((off + s2) << 12) | (b << 7) | nIn;
    }
  }
}

__global__ __launch_bounds__(256) void bucket_fill(
    const int* __restrict__ deg4, int* __restrict__ bcur, int* __restrict__ blist) {
  __shared__ int hist[21];
  __shared__ int base[21];
  int t = threadIdx.x;
  if (t < 21) hist[t] = 0;
  __syncthreads();
  int node = blockIdx.x * 256 + t;
  int j = blockIdx.y;
  int b = 0, lpos = 0;
  bool valid = (node < N_NODES);
  if (valid) {
    int d = deg4[j * N_NODES + node];
    b = d < MAX_DEG ? d : MAX_DEG;
    lpos = atomicAdd(&hist[b], 1);
  }
  __syncthreads();
  if (t < 21 && hist[t]) base[t] = atomicAdd(&bcur[j * 21 + t], hist[t]);
  __syncthreads();
  if (valid) blist[base[b] + lpos] = node;
}

// ---------------- gather: ab hsum-half = sum of neighbor self-halves --------
__global__ __launch_bounds__(256) void gather_kernel(
    const int* __restrict__ S, const int* __restrict__ deg,
    const int* __restrict__ slots, unsigned short* __restrict__ ab) {
  int node = blockIdx.x * 4 + (threadIdx.x >> 6);
  int lane = threadIdx.x & 63;
  if (node >= N_NODES) return;
  int q = lane >> 4, cl = lane & 15;  // channels [4*cl, 4*cl+4)
  int off = S[node];
  int dg = deg[node];
  float c0 = 0.f, c1 = 0.f, c2 = 0.f, c3 = 0.f;
  int e = q;
  for (; e + 4 < dg; e += 8) {
    int n0 = slots[off + e];
    int n1 = slots[off + e + 4];
    uint2 p0 = *(const uint2*)&ab[n0 * 128 + 64 + 4 * cl];
    uint2 p1 = *(const uint2*)&ab[n1 * 128 + 64 + 4 * cl];
    c0 += b2f((unsigned short)p0.x) + b2f((unsigned short)p1.x);
    c1 += b2f((unsigned short)(p0.x >> 16)) + b2f((unsigned short)(p1.x >> 16));
    c2 += b2f((unsigned short)p0.y) + b2f((unsigned short)p1.y);
    c3 += b2f((unsigned short)(p0.y >> 16)) + b2f((unsigned short)(p1.y >> 16));
  }
  for (; e < dg; e += 4) {
    uint2 p0 = *(const uint2*)&ab[slots[off + e] * 128 + 64 + 4 * cl];
    c0 += b2f((unsigned short)p0.x);
    c1 += b2f((unsigned short)(p0.x >> 16));
    c2 += b2f((unsigned short)p0.y);
    c3 += b2f((unsigned short)(p0.y >> 16));
  }
  c0 += __shfl_xor(c0, 16, 64); c0 += __shfl_xor(c0, 32, 64);
  c1 += __shfl_xor(c1, 16, 64); c1 += __shfl_xor(c1, 32, 64);
  c2 += __shfl_xor(c2, 16, 64); c2 += __shfl_xor(c2, 32, 64);
  c3 += __shfl_xor(c3, 16, 64); c3 += __shfl_xor(c3, 32, 64);
  if (q == 0) {
    uint2 o;
    o.x = (unsigned)f2b(c0) | ((unsigned)f2b(c1) << 16);
    o.y = (unsigned)f2b(c2) | ((unsigned)f2b(c3) << 16);
    *(uint2*)&ab[node * 128 + 4 * cl] = o;
  }
}

// ---------------- MFMA transform: [64 x 128] @ [128 x 64] per tile ----------
__global__ __launch_bounds__(256) void transform_kernel(
    float* __restrict__ h, unsigned short* __restrict__ ab,
    const int* __restrict__ blist, const int* __restrict__ tdesc,
    const int* __restrict__ ntiles, const unsigned short* __restrict__ wbt,
    const float* __restrict__ bl, int j, int do_relu, int last) {
  if ((int)blockIdx.x >= ntiles[j]) return;
  int d = tdesc[j * MAX_TILES + blockIdx.x];
  int nIn = d & 127;
  int b = (d >> 7) & 31;
  const int* lst = blist + (d >> 12);

  int tid = threadIdx.x;
  int qw = tid >> 6, lane = tid & 63;

  if (b == 0) {
    for (int r = qw * 16; r < qw * 16 + 16; ++r) {
      if (r < nIn) {
        int node = lst[r];
        float v = b2f(ab[node * 128 + 64 + lane]);
        if (do_relu) v = fmaxf(v, 0.f);
        if (last) {
          if (node < G_NODES) h[node * H + lane] = v;
        } else {
          ab[node * 128 + 64 + lane] = f2b(v);
        }
      }
    }
    return;
  }

  __shared__ unsigned short aL[64 * 136];  // 17408 B; reused as fp32[64*68]
  __shared__ int nodeS[64];

  for (int r = qw * 16; r < qw * 16 + 16; ++r) {
    int node = (r < nIn) ? lst[r] : -1;
    if (lane == 0) nodeS[r] = node;
    unsigned q = 0;
    if (node >= 0) q = *(const unsigned*)&ab[node * 128 + 2 * lane];
    *(unsigned*)&aL[r * 136 + 2 * lane] = q;
  }
  __syncthreads();

  int m = lane & 15, quad = lane >> 4;
  const unsigned short* wbase = wbt + (size_t)(j * 21 + b) * 64 * 128;
  float4v acc[4];
#pragma unroll
  for (int t = 0; t < 4; ++t) {
    float bv = bl[b * 64 + t * 16 + m];
    acc[t] = (float4v){bv, bv, bv, bv};
  }
#pragma unroll
  for (int ks = 0; ks < 4; ++ks) {
    short8 a = *(const short8*)&aL[(qw * 16 + m) * 136 + ks * 32 + quad * 8];
#pragma unroll
    for (int t = 0; t < 4; ++t) {
      short8 bf = *(const short8*)&wbase[(t * 16 + m) * 128 + ks * 32 + quad * 8];
      acc[t] = __builtin_amdgcn_mfma_f32_16x16x32_bf16(a, bf, acc[t], 0, 0, 0);
    }
  }
  if (do_relu) {
#pragma unroll
    for (int t = 0; t < 4; ++t)
#pragma unroll
      for (int r = 0; r < 4; ++r) acc[t][r] = fmaxf(acc[t][r], 0.f);
  }
  __syncthreads();
  float* outF = (float*)aL;
#pragma unroll
  for (int t = 0; t < 4; ++t)
#pragma unroll
    for (int r = 0; r < 4; ++r)
      outF[(qw * 16 + quad * 4 + r) * 68 + t * 16 + m] = acc[t][r];
  __syncthreads();
  if (last) {
    for (int r = qw * 16; r < qw * 16 + 16; ++r)
      if (r < nIn && nodeS[r] < G_NODES)
        h[nodeS[r] * H + lane] = outF[r * 68 + lane];
  } else {
    for (int r = qw * 16; r < qw * 16 + 16; ++r)
      if (r < nIn) ab[nodeS[r] * 128 + 64 + lane] = f2b(outF[r * 68 + lane]);
  }
}

// ---------------- fused layernorm + residual + ground-node pool -------------
__global__ __launch_bounds__(1024) void ln_pool_kernel(
    const float* __restrict__ h, const float* __restrict__ h0,
    const float* __restrict__ g, const float* __restrict__ b,
    const int* __restrict__ batch, float* __restrict__ pooled) {
  __shared__ float sm[NUM_GRAPHS * H];  // 32 KB
  int t = threadIdx.x;
  for (int i = t; i < NUM_GRAPHS * H; i += 1024) sm[i] = 0.f;
  __syncthreads();
  int lane = t & 63, w = t >> 6;  // 16 waves
  const int per = (G_NODES + POOL_BLOCKS - 1) / POOL_BLOCKS;
  int start = blockIdx.x * per;
  int end = min(start + per, G_NODES);
  for (int node = start + w; node < end; node += 16) {
    int idx = node * H + lane;
    float v = h[idx];
    float s = v;
#pragma unroll
    for (int off = 32; off > 0; off >>= 1) s += __shfl_xor(s, off, 64);
    float mu = s * (1.0f / H);
    float dv = v - mu;
    float q = dv * dv;
#pragma unroll
    for (int off = 32; off > 0; off >>= 1) q += __shfl_xor(q, off, 64);
    float inv = rsqrtf(q * (1.0f / H) + LN_EPS);
    float r = dv * inv * g[lane] + b[lane] + h0[idx];
    atomicAdd(&sm[batch[node] * H + lane], r);
  }
  __syncthreads();
  for (int i = t; i < NUM_GRAPHS * H; i += 1024) {
    float v = sm[i];
    if (v != 0.f) atomicAdd(&pooled[i], v);
  }
}

__global__ __launch_bounds__(64) void out_kernel(
    const float* __restrict__ pooled, const float* __restrict__ w,
    const float* __restrict__ b, float* __restrict__ out) {
  int gph = blockIdx.x;
  int c = threadIdx.x;
  float v = pooled[gph * H + c] * w[c];
#pragma unroll
  for (int off = 32; off > 0; off >>= 1) v += __shfl_xor(v, off, 64);
  if (c == 0) out[gph] = v + b[0];
}

extern "C" void kernel_launch(void* const* d_in, const int* in_sizes, int n_in,
                              void* d_out, int out_size, void* d_ws, size_t ws_size,
                              hipStream_t stream) {
  const float* x       = (const float*)d_in[0];
  const int*   ei_edge = (const int*)d_in[1];
  const int*   ei_sub  = (const int*)d_in[2];
  const int*   ei_ns   = (const int*)d_in[3];
  const int*   ei_sn   = (const int*)d_in[4];
  const int*   batch   = (const int*)d_in[7];
  const float* emb_w   = (const float*)d_in[8];
  const float* emb_b   = (const float*)d_in[9];
  const float* conv_wl = (const float*)d_in[10];
  const float* conv_bl = (const float*)d_in[11];
  const float* conv_wr = (const float*)d_in[12];
  const float* ln_g    = (const float*)d_in[13];
  const float* ln_b    = (const float*)d_in[14];
  const float* out_w   = (const float*)d_in[15];
  const float* out_b   = (const float*)d_in[16];
  float* out = (float*)d_out;

  const size_t HB = (size_t)N_NODES * H * sizeof(float);   // 25.6 MB
  char* ws = (char*)d_ws;
  float* h      = (float*)(ws);                        // fp32, ground, j==3
  float* h0     = (float*)(ws + HB);                   // fp32 residual (ground)
  unsigned short* ab = (unsigned short*)(ws + 2 * HB); // [node][128] bf16 25.6MB
  // Build-phase overlays (dead once emb/gather run):
  unsigned* binned = (unsigned*)(ws);                            // 12.8 MB on h
  int*   cntT   = (int*)(ws + HB);                               // 1 MB on h0
  int*   offT   = (int*)(ws + HB + 0x100000);                    // 1 MB
  int*   bsumA  = (int*)(ws + HB + 0x300000);                    // 2 KB
  // Persistent:
  int*   deg4   = (int*)(ws + 3 * HB);                           // 1.6 MB
  int*   S      = (int*)(ws + 78400000);                         // 1.6 MB
  int*   slots  = (int*)(ws + 80000000);                         // 12.8 MB
  int*   bcnt   = (int*)(ws + 92800000);
  int*   boff   = (int*)(ws + 92800512);
  int*   bcur   = (int*)(ws + 92801024);
  int*   blist  = (int*)(ws + 92801536);                         // 1.6 MB
  float* pooled = (float*)(ws + 94401536);                       // 32 KB
  unsigned short* wbt = (unsigned short*)(ws + 94434304);        // 1.38 MB
  int*   tdesc  = (int*)(ws + 95810560);                         // 25.6 KB
  int*   ntiles = (int*)(ws + 95836160);                         // 16 B
  unsigned short* ewbt = (unsigned short*)(ws + 95836608);       // 4 KB

  const int* e0 = ei_edge, *e1 = ei_ns, *e2 = ei_sub, *e3 = ei_sn;
  const int MC = NBINS * NBINS;
  const int NB_MC = MC / 1024;              // 256

  // --- binned CSR build (19 total dispatches, down from 25) ---
  p1_bincount<<<NBINS, 256, 0, stream>>>(e0, e1, e2, e3, cntT);
  scan1<<<NB_MC, 256, 0, stream>>>(cntT, offT, bsumA, MC);
  scan2<<<1, 512, 0, stream>>>(bsumA, NB_MC, bcnt);
  p3_binscatter<<<NBINS, 256, 0, stream>>>(e0, e1, e2, e3, offT, bsumA, binned);
  p46_kernel<<<NBINS, 256, 0, stream>>>(binned, offT, bsumA, deg4, S, slots, bcnt);
  bucket_scan<<<1, 128, 0, stream>>>(bcnt, boff, bcur, ntiles, tdesc);
  bucket_fill<<<dim3((N_NODES + 255) / 256, 4), 256, 0, stream>>>(deg4, bcur, blist);
  wconv_kernel<<<(84 * 64 * 128 + H * F_IN + 255) / 256, 256, 0, stream>>>(
      conv_wl, conv_wr, emb_w, wbt, ewbt);

  // --- network ---
  emb_kernel<<<(N_NODES + 63) / 64, 256, 0, stream>>>(x, ewbt, emb_b, h0, ab, pooled);

  for (int j = 0; j < 4; ++j) {
    gather_kernel<<<(N_NODES + 3) / 4, 256, 0, stream>>>(
        S + j * N_NODES, deg4 + j * N_NODES, slots, ab);
    transform_kernel<<<MAX_TILES, 256, 0, stream>>>(
        h, ab, blist, tdesc, ntiles, wbt,
        conv_bl + (size_t)j * 21 * H, j, j < 3 ? 1 : 0, j == 3 ? 1 : 0);
  }

  ln_pool_kernel<<<POOL_BLOCKS, 1024, 0, stream>>>(h, h0, ln_g, ln_b, batch, pooled);
  out_kernel<<<NUM_GRAPHS, 64, 0, stream>>>(pooled, out_w, out_b, out);
}

// Round 14
// 479.620 us; speedup vs baseline: 1.7604x; 1.0465x over previous
//
#include <hip/hip_runtime.h>

#define N_NODES 100000
#define G_NODES 50000
#define N_EDGES 800000
#define H 64
#define F_IN 32
#define MAX_DEG 20
#define NUM_GRAPHS 128
#define LN_EPS 1e-5f
#define POOL_BLOCKS 256
#define MAX_TILES 1600

// Binned CSR build parameters: 512 bins over the 4*N key space.
#define NBINS 512
#define BPB 782            // keys per bin: 782*512 = 400384 >= 400000
#define CHUNK 6250         // edges per build block: 6250*512 = 3.2M
#define MKEYS (4 * N_NODES)
#define MEDGES (4 * N_EDGES)

typedef __attribute__((ext_vector_type(8))) short short8;
typedef __attribute__((ext_vector_type(4))) float float4v;

// bf16 helpers (RNE), no header dependency
static __device__ __forceinline__ unsigned short f2b(float f) {
  unsigned u = __float_as_uint(f);
  return (unsigned short)((u + 0x7fffu + ((u >> 16) & 1u)) >> 16);
}
static __device__ __forceinline__ float b2f(unsigned short b) {
  return __uint_as_float(((unsigned)b) << 16);
}

// ---------------- MFMA embedding + pooled zero-init -------------------------
// Writes initial self-half at ab[node][64:128] (conv0 reads inoff=64).
__global__ __launch_bounds__(256) void emb_kernel(
    const float* __restrict__ x, const unsigned short* __restrict__ ewbt,
    const float* __restrict__ eb, float* __restrict__ h0,
    unsigned short* __restrict__ ab, float* __restrict__ pooled) {
  int tid = threadIdx.x;
  if (blockIdx.x == 0) {
    for (int i = tid; i < NUM_GRAPHS * H; i += 256) pooled[i] = 0.f;
  }
  int base = blockIdx.x * 64;
  int nIn = min(64, N_NODES - base);
  int qw = tid >> 6, lane = tid & 63;
  __shared__ unsigned short aL[64 * 40];  // stride 40 breaks pow2 banks
  __shared__ float outF[64 * 68];

  {
    int node = tid >> 2, chb = (tid & 3) * 8;
    unsigned short v8[8];
    if (node < nIn) {
      const float* xr = x + ((size_t)(base + node)) * F_IN + chb;
      float4 f0 = *(const float4*)(xr);
      float4 f1 = *(const float4*)(xr + 4);
      v8[0] = f2b(f0.x); v8[1] = f2b(f0.y); v8[2] = f2b(f0.z); v8[3] = f2b(f0.w);
      v8[4] = f2b(f1.x); v8[5] = f2b(f1.y); v8[6] = f2b(f1.z); v8[7] = f2b(f1.w);
    } else {
#pragma unroll
      for (int i = 0; i < 8; ++i) v8[i] = 0;
    }
    *(short8*)&aL[(tid >> 2) * 40 + chb] = *(short8*)v8;
  }
  // no __syncthreads: wave qw staged exactly rows [qw*16, qw*16+16)

  int m = lane & 15, quad = lane >> 4;
  short8 a = *(const short8*)&aL[(qw * 16 + m) * 40 + quad * 8];
  float4v acc[4];
#pragma unroll
  for (int t = 0; t < 4; ++t) {
    float bv = eb[t * 16 + m];
    acc[t] = (float4v){bv, bv, bv, bv};
  }
#pragma unroll
  for (int t = 0; t < 4; ++t) {
    short8 bf = *(const short8*)&ewbt[(t * 16 + m) * F_IN + quad * 8];
    acc[t] = __builtin_amdgcn_mfma_f32_16x16x32_bf16(a, bf, acc[t], 0, 0, 0);
  }
#pragma unroll
  for (int t = 0; t < 4; ++t)
#pragma unroll
    for (int r = 0; r < 4; ++r)
      outF[(qw * 16 + quad * 4 + r) * 68 + t * 16 + m] = acc[t][r];
  for (int r = qw * 16; r < qw * 16 + 16; ++r) {
    if (r < nIn) {
      int node = base + r;
      float v = outF[r * 68 + lane];
      if (node < G_NODES) h0[node * H + lane] = v;
      ab[node * 128 + 64 + lane] = f2b(v);
    }
  }
}

// ---------------- weight preconvert (conv + emb in one grid) ----------------
__global__ __launch_bounds__(256) void wconv_kernel(
    const float* __restrict__ wl, const float* __restrict__ wr,
    const float* __restrict__ ew, unsigned short* __restrict__ wbt,
    unsigned short* __restrict__ ewbt) {
  int i = blockIdx.x * 256 + threadIdx.x;
  if (i < 84 * 64 * 128) {
    int k = i & 127;
    int ch = (i >> 7) & 63;
    int jb = i >> 13;
    float v = (k < 64) ? wl[jb * 4096 + k * 64 + ch]
                       : wr[jb * 4096 + (k - 64) * 64 + ch];
    wbt[i] = f2b(v);
  } else if (i < 84 * 64 * 128 + H * F_IN) {
    int ii = i - 84 * 64 * 128;
    int c = ii >> 5, f = ii & 31;
    ewbt[ii] = f2b(ew[f * H + c]);
  }
}

// ---------------- binned CSR build (no scattered global atomics) ------------
__global__ __launch_bounds__(256) void p1_bincount(
    const int* __restrict__ e0, const int* __restrict__ e1,
    const int* __restrict__ e2, const int* __restrict__ e3,
    int* __restrict__ cntT) {
  __shared__ int hist[NBINS];
  int t = threadIdx.x, b = blockIdx.x;
  for (int i = t; i < NBINS; i += 256) hist[i] = 0;
  __syncthreads();
  int j = b >> 7;
  const int* ei = (j == 0) ? e0 : (j == 1) ? e1 : (j == 2) ? e2 : e3;
  int ebase = (b & 127) * CHUNK;
  for (int i = t; i < CHUNK; i += 256) {
    int dst = ei[N_EDGES + ebase + i];
    int key = j * N_NODES + dst;
    atomicAdd(&hist[key / BPB], 1);
  }
  __syncthreads();
  for (int i = t; i < NBINS; i += 256) cntT[i * NBINS + b] = hist[i];
}

__global__ __launch_bounds__(256) void p3_binscatter(
    const int* __restrict__ e0, const int* __restrict__ e1,
    const int* __restrict__ e2, const int* __restrict__ e3,
    const int* __restrict__ offT, const int* __restrict__ bsumA,
    unsigned* __restrict__ binned) {
  __shared__ int cur[NBINS];
  int t = threadIdx.x, b = blockIdx.x;
  for (int i = t; i < NBINS; i += 256) {
    int idx = i * NBINS + b;
    cur[i] = offT[idx] + bsumA[idx >> 10];
  }
  __syncthreads();
  int j = b >> 7;
  const int* ei = (j == 0) ? e0 : (j == 1) ? e1 : (j == 2) ? e2 : e3;
  int ebase = (b & 127) * CHUNK;
  for (int i = t; i < CHUNK; i += 256) {
    int src = ei[ebase + i];
    int dst = ei[N_EDGES + ebase + i];
    int key = j * N_NODES + dst;
    int bin = key / BPB;
    int pos = atomicAdd(&cur[bin], 1);
    binned[pos] = ((unsigned)(key - bin * BPB) << 17) | (unsigned)src;
  }
}

// p46: per bin, fused deg4 + bucket-hist + local CSR scan + slot scatter.
__global__ __launch_bounds__(256) void p46_kernel(
    const unsigned* __restrict__ binned, const int* __restrict__ offT,
    const int* __restrict__ bsumA, int* __restrict__ deg4,
    int* __restrict__ S, int* __restrict__ slots, int* __restrict__ bcnt) {
  __shared__ int hist[BPB];
  __shared__ int cur[BPB];
  __shared__ int bh[84];
  __shared__ int wtot[4];
  int t = threadIdx.x, bin = blockIdx.x;
  int kb = bin * BPB;
  for (int i = t; i < BPB; i += 256) hist[i] = 0;
  if (t < 84) bh[t] = 0;
  __syncthreads();
  int i0 = bin * NBINS;
  int start = offT[i0] + bsumA[i0 >> 10];
  int end;
  if (bin == NBINS - 1) {
    end = MEDGES;
  } else {
    int i1 = (bin + 1) * NBINS;
    end = offT[i1] + bsumA[i1 >> 10];
  }
  for (int i = start + t; i < end; i += 256)
    atomicAdd(&hist[binned[i] >> 17], 1);
  __syncthreads();
  for (int i = t; i < BPB; i += 256) {
    int key = kb + i;
    if (key < MKEYS) {
      int d = hist[i];
      deg4[key] = d;
      int j = key / N_NODES;
      int b = d < MAX_DEG ? d : MAX_DEG;
      atomicAdd(&bh[j * 21 + b], 1);
    }
  }
  int base = t * 4;
  int v0 = 0, v1 = 0, v2 = 0, v3 = 0;
  if (base < BPB) {
    v0 = hist[base];
    v1 = (base + 1 < BPB) ? hist[base + 1] : 0;
    v2 = (base + 2 < BPB) ? hist[base + 2] : 0;
    v3 = (base + 3 < BPB) ? hist[base + 3] : 0;
  }
  int s = v0 + v1 + v2 + v3;
  int incl = s;
#pragma unroll
  for (int off = 1; off < 64; off <<= 1) {
    int y = __shfl_up(incl, off, 64);
    if ((t & 63) >= off) incl += y;
  }
  if ((t & 63) == 63) wtot[t >> 6] = incl;
  __syncthreads();
  int wbase = 0;
  for (int w = 0; w < (t >> 6); ++w) wbase += wtot[w];
  int ex = start + wbase + incl - s;
  if (base < BPB) {
    cur[base] = ex;
    if (base + 1 < BPB) cur[base + 1] = ex + v0;
    if (base + 2 < BPB) cur[base + 2] = ex + v0 + v1;
    if (base + 3 < BPB) cur[base + 3] = ex + v0 + v1 + v2;
  }
  __syncthreads();
  for (int i = t; i < BPB; i += 256)
    if (kb + i < MKEYS) S[kb + i] = cur[i];
  if (t < 84 && bh[t]) atomicAdd(&bcnt[t], bh[t]);
  __syncthreads();
  for (int i = start + t; i < end; i += 256) {
    unsigned v = binned[i];
    int pos = atomicAdd(&cur[v >> 17], 1);
    slots[pos] = (int)(v & 0x1ffffu);
  }
}

// ---------------- hierarchical exclusive scan (MC only) ---------------------
__global__ __launch_bounds__(256) void scan1(
    const int* __restrict__ in, int* __restrict__ S, int* __restrict__ bsum, int M) {
  int t = threadIdx.x;
  int base = blockIdx.x * 1024 + t * 4;
  int v0 = 0, v1 = 0, v2 = 0, v3 = 0;
  if (base + 3 < M) {
    int4 q = *(const int4*)(in + base);
    v0 = q.x; v1 = q.y; v2 = q.z; v3 = q.w;
  } else {
    if (base     < M) v0 = in[base];
    if (base + 1 < M) v1 = in[base + 1];
    if (base + 2 < M) v2 = in[base + 2];
    if (base + 3 < M) v3 = in[base + 3];
  }
  int s = v0 + v1 + v2 + v3;
  int incl = s;
#pragma unroll
  for (int off = 1; off < 64; off <<= 1) {
    int y = __shfl_up(incl, off, 64);
    if ((t & 63) >= off) incl += y;
  }
  __shared__ int wtot[4];
  if ((t & 63) == 63) wtot[t >> 6] = incl;
  __syncthreads();
  int wbase = 0;
  for (int w = 0; w < (t >> 6); ++w) wbase += wtot[w];
  int ex = wbase + incl - s;
  if (base < M) {
    int eo0 = ex, eo1 = ex + v0, eo2 = ex + v0 + v1, eo3 = ex + v0 + v1 + v2;
    if (base + 3 < M) {
      *(int4*)(S + base) = make_int4(eo0, eo1, eo2, eo3);
    } else {
      S[base] = eo0;
      if (base + 1 < M) S[base + 1] = eo1;
      if (base + 2 < M) S[base + 2] = eo2;
    }
  }
  if (t == 255) bsum[blockIdx.x] = wbase + incl;
}

__global__ __launch_bounds__(512) void scan2(
    int* __restrict__ bsum, int nb, int* __restrict__ bcnt) {
  int t = threadIdx.x;
  if (t < 84) bcnt[t] = 0;
  int v = (t < nb) ? bsum[t] : 0;
  int incl = v;
#pragma unroll
  for (int off = 1; off < 64; off <<= 1) {
    int y = __shfl_up(incl, off, 64);
    if ((t & 63) >= off) incl += y;
  }
  __shared__ int wtot[8];
  if ((t & 63) == 63) wtot[t >> 6] = incl;
  __syncthreads();
  int wbase = 0;
  for (int w = 0; w < (t >> 6); ++w) wbase += wtot[w];
  if (t < nb) bsum[t] = wbase + incl - v;
}

// ---------------- bucket scan + tile descriptors (one block) ----------------
__global__ __launch_bounds__(128) void bucket_scan(
    const int* __restrict__ bcnt, int* __restrict__ boff, int* __restrict__ bcur,
    int* __restrict__ ntiles, int* __restrict__ tdesc) {
  __shared__ int wt[2];
  __shared__ int exL[84], cntL[84], toffL[84];
  int t = threadIdx.x;
  int v = (t < 84) ? bcnt[t] : 0;
  int incl = v;
#pragma unroll
  for (int off = 1; off < 64; off <<= 1) {
    int y = __shfl_up(incl, off, 64);
    if ((t & 63) >= off) incl += y;
  }
  if ((t & 63) == 63) wt[t >> 6] = incl;
  __syncthreads();
  int wbase = (t >> 6) ? wt[0] : 0;
  if (t < 84) {
    int ex = wbase + incl - v;
    boff[t] = ex;
    bcur[t] = ex;
    exL[t] = ex;
    cntL[t] = v;
  }
  __syncthreads();
  if (t < 4) {
    int acc = 0;
    for (int bb = 0; bb < 21; ++bb) {
      toffL[t * 21 + bb] = acc;
      acc += (cntL[t * 21 + bb] + 63) >> 6;
    }
    ntiles[t] = acc;
  }
  __syncthreads();
  for (int jb = 0; jb < 84; ++jb) {
    int j = jb / 21, b = jb - j * 21;
    int cnt = cntL[jb], off = exL[jb], tb = toffL[jb];
    int nt = (cnt + 63) >> 6;
    for (int i = t; i < nt; i += 128) {
      int s2 = i << 6;
      int nIn = min(64, cnt - s2);
      tdesc[j * MAX_TILES + tb + i] = ((off + s2) << 12) | (b << 7) | nIn;
    }
  }
}

__global__ __launch_bounds__(256) void bucket_fill(
    const int* __restrict__ deg4, int* __restrict__ bcur, int* __restrict__ blist) {
  __shared__ int hist[21];
  __shared__ int base[21];
  int t = threadIdx.x;
  if (t < 21) hist[t] = 0;
  __syncthreads();
  int node = blockIdx.x * 256 + t;
  int j = blockIdx.y;
  int b = 0, lpos = 0;
  bool valid = (node < N_NODES);
  if (valid) {
    int d = deg4[j * N_NODES + node];
    b = d < MAX_DEG ? d : MAX_DEG;
    lpos = atomicAdd(&hist[b], 1);
  }
  __syncthreads();
  if (t < 21 && hist[t]) base[t] = atomicAdd(&bcur[j * 21 + t], hist[t]);
  __syncthreads();
  if (valid) blist[base[b] + lpos] = node;
}

// ---------------- FUSED conv: gather + MFMA transform, zero barriers --------
// Half ping-pong (R5 race fix without extra buffers): conv j reads neighbor
// self-values from ab[.][inoff:inoff+64], writes outputs to the OTHER half —
// no reader/writer overlap within a conv. LDS staging always places hsum at
// k0:64 and self at k64:128, so weights stay [WL|WR]. Each wave stages,
// MFMAs, and stores only its own 16 rows -> no __syncthreads anywhere;
// LDS 17.4KB -> 8 blocks/CU (vs R6 fused's 4 at 33.8KB — why R6 regressed).
__global__ __launch_bounds__(256) void conv_kernel(
    float* __restrict__ h, unsigned short* __restrict__ ab,
    const int* __restrict__ S, const int* __restrict__ deg,
    const int* __restrict__ slots,
    const int* __restrict__ blist, const int* __restrict__ tdesc,
    const int* __restrict__ ntiles, const unsigned short* __restrict__ wbt,
    const float* __restrict__ bl, int j, int inoff, int do_relu, int last) {
  if ((int)blockIdx.x >= ntiles[j]) return;
  int d = tdesc[j * MAX_TILES + blockIdx.x];
  int nIn = d & 127;
  int b = (d >> 7) & 31;
  const int* lst = blist + (d >> 12);
  int outoff = 64 - inoff;

  int tid = threadIdx.x;
  int qw = tid >> 6, lane = tid & 63;

  if (b == 0) {
    // deg==0 masking: carry self (bf16-rounded); ReLU when j<3
    for (int r = qw * 16; r < qw * 16 + 16; ++r) {
      if (r < nIn) {
        int node = lst[r];
        float v = b2f(ab[node * 128 + inoff + lane]);
        if (do_relu) v = fmaxf(v, 0.f);
        if (last) {
          if (node < G_NODES) h[node * H + lane] = v;
        } else {
          ab[node * 128 + outoff + lane] = f2b(v);
        }
      }
    }
    return;
  }

  __shared__ unsigned short aL[64 * 136];  // 17408 B; reused as fp32[64*68]
  __shared__ int nodeS[64];
  int q = lane >> 4, cl = lane & 15;  // quad-edge gather layout

  // staging: per row, gather neighbor sum (4 edge parities x uint2) + self
  for (int r = qw * 16; r < qw * 16 + 16; ++r) {
    int node = (r < nIn) ? lst[r] : -1;
    if (lane == 0) nodeS[r] = node;
    uint2 selfv = make_uint2(0u, 0u);
    float c0 = 0.f, c1 = 0.f, c2 = 0.f, c3 = 0.f;
    if (node >= 0) {
      if (q == 1) selfv = *(const uint2*)&ab[node * 128 + inoff + 4 * cl];
      int off = S[node];
      int dg = (b < MAX_DEG) ? b : deg[node];
      int e = q;
      for (; e + 4 < dg; e += 8) {
        int n0 = slots[off + e];
        int n1 = slots[off + e + 4];
        uint2 p0 = *(const uint2*)&ab[n0 * 128 + inoff + 4 * cl];
        uint2 p1 = *(const uint2*)&ab[n1 * 128 + inoff + 4 * cl];
        c0 += b2f((unsigned short)p0.x) + b2f((unsigned short)p1.x);
        c1 += b2f((unsigned short)(p0.x >> 16)) + b2f((unsigned short)(p1.x >> 16));
        c2 += b2f((unsigned short)p0.y) + b2f((unsigned short)p1.y);
        c3 += b2f((unsigned short)(p0.y >> 16)) + b2f((unsigned short)(p1.y >> 16));
      }
      for (; e < dg; e += 4) {
        uint2 p0 = *(const uint2*)&ab[slots[off + e] * 128 + inoff + 4 * cl];
        c0 += b2f((unsigned short)p0.x);
        c1 += b2f((unsigned short)(p0.x >> 16));
        c2 += b2f((unsigned short)p0.y);
        c3 += b2f((unsigned short)(p0.y >> 16));
      }
    }
    c0 += __shfl_xor(c0, 16, 64); c0 += __shfl_xor(c0, 32, 64);
    c1 += __shfl_xor(c1, 16, 64); c1 += __shfl_xor(c1, 32, 64);
    c2 += __shfl_xor(c2, 16, 64); c2 += __shfl_xor(c2, 32, 64);
    c3 += __shfl_xor(c3, 16, 64); c3 += __shfl_xor(c3, 32, 64);
    if (q == 0) {
      uint2 o;
      o.x = (unsigned)f2b(c0) | ((unsigned)f2b(c1) << 16);
      o.y = (unsigned)f2b(c2) | ((unsigned)f2b(c3) << 16);
      *(uint2*)&aL[r * 136 + 4 * cl] = o;          // hsum -> k 0:64
    }
    if (q == 1) {
      *(uint2*)&aL[r * 136 + 64 + 4 * cl] = selfv;  // self -> k 64:128
    }
  }
  // no barrier: wave reads only its own rows below

  int m = lane & 15, quad = lane >> 4;
  const unsigned short* wbase = wbt + (size_t)(j * 21 + b) * 64 * 128;
  float4v acc[4];
#pragma unroll
  for (int t = 0; t < 4; ++t) {
    float bv = bl[b * 64 + t * 16 + m];
    acc[t] = (float4v){bv, bv, bv, bv};
  }
#pragma unroll
  for (int ks = 0; ks < 4; ++ks) {
    short8 a = *(const short8*)&aL[(qw * 16 + m) * 136 + ks * 32 + quad * 8];
#pragma unroll
    for (int t = 0; t < 4; ++t) {
      short8 bf = *(const short8*)&wbase[(t * 16 + m) * 128 + ks * 32 + quad * 8];
      acc[t] = __builtin_amdgcn_mfma_f32_16x16x32_bf16(a, bf, acc[t], 0, 0, 0);
    }
  }
  if (do_relu) {
#pragma unroll
    for (int t = 0; t < 4; ++t)
#pragma unroll
      for (int r = 0; r < 4; ++r) acc[t][r] = fmaxf(acc[t][r], 0.f);
  }
  // transpose via LDS reuse (same wave-local byte rows: 136*2B == 68*4B == 272B)
  float* outF = (float*)aL;
#pragma unroll
  for (int t = 0; t < 4; ++t)
#pragma unroll
    for (int r = 0; r < 4; ++r)
      outF[(qw * 16 + quad * 4 + r) * 68 + t * 16 + m] = acc[t][r];
  if (last) {
    for (int r = qw * 16; r < qw * 16 + 16; ++r)
      if (r < nIn && nodeS[r] < G_NODES)
        h[nodeS[r] * H + lane] = outF[r * 68 + lane];
  } else {
    for (int r = qw * 16; r < qw * 16 + 16; ++r)
      if (r < nIn) ab[nodeS[r] * 128 + outoff + lane] = f2b(outF[r * 68 + lane]);
  }
}

// ---------------- fused layernorm + residual + ground-node pool -------------
__global__ __launch_bounds__(1024) void ln_pool_kernel(
    const float* __restrict__ h, const float* __restrict__ h0,
    const float* __restrict__ g, const float* __restrict__ b,
    const int* __restrict__ batch, float* __restrict__ pooled) {
  __shared__ float sm[NUM_GRAPHS * H];  // 32 KB
  int t = threadIdx.x;
  for (int i = t; i < NUM_GRAPHS * H; i += 1024) sm[i] = 0.f;
  __syncthreads();
  int lane = t & 63, w = t >> 6;  // 16 waves
  const int per = (G_NODES + POOL_BLOCKS - 1) / POOL_BLOCKS;
  int start = blockIdx.x * per;
  int end = min(start + per, G_NODES);
  for (int node = start + w; node < end; node += 16) {
    int idx = node * H + lane;
    float v = h[idx];
    float s = v;
#pragma unroll
    for (int off = 32; off > 0; off >>= 1) s += __shfl_xor(s, off, 64);
    float mu = s * (1.0f / H);
    float dv = v - mu;
    float q = dv * dv;
#pragma unroll
    for (int off = 32; off > 0; off >>= 1) q += __shfl_xor(q, off, 64);
    float inv = rsqrtf(q * (1.0f / H) + LN_EPS);
    float r = dv * inv * g[lane] + b[lane] + h0[idx];
    atomicAdd(&sm[batch[node] * H + lane], r);
  }
  __syncthreads();
  for (int i = t; i < NUM_GRAPHS * H; i += 1024) {
    float v = sm[i];
    if (v != 0.f) atomicAdd(&pooled[i], v);
  }
}

__global__ __launch_bounds__(64) void out_kernel(
    const float* __restrict__ pooled, const float* __restrict__ w,
    const float* __restrict__ b, float* __restrict__ out) {
  int gph = blockIdx.x;
  int c = threadIdx.x;
  float v = pooled[gph * H + c] * w[c];
#pragma unroll
  for (int off = 32; off > 0; off >>= 1) v += __shfl_xor(v, off, 64);
  if (c == 0) out[gph] = v + b[0];
}

extern "C" void kernel_launch(void* const* d_in, const int* in_sizes, int n_in,
                              void* d_out, int out_size, void* d_ws, size_t ws_size,
                              hipStream_t stream) {
  const float* x       = (const float*)d_in[0];
  const int*   ei_edge = (const int*)d_in[1];
  const int*   ei_sub  = (const int*)d_in[2];
  const int*   ei_ns   = (const int*)d_in[3];
  const int*   ei_sn   = (const int*)d_in[4];
  const int*   batch   = (const int*)d_in[7];
  const float* emb_w   = (const float*)d_in[8];
  const float* emb_b   = (const float*)d_in[9];
  const float* conv_wl = (const float*)d_in[10];
  const float* conv_bl = (const float*)d_in[11];
  const float* conv_wr = (const float*)d_in[12];
  const float* ln_g    = (const float*)d_in[13];
  const float* ln_b    = (const float*)d_in[14];
  const float* out_w   = (const float*)d_in[15];
  const float* out_b   = (const float*)d_in[16];
  float* out = (float*)d_out;

  const size_t HB = (size_t)N_NODES * H * sizeof(float);   // 25.6 MB
  char* ws = (char*)d_ws;
  float* h      = (float*)(ws);                        // fp32, ground, j==3
  float* h0     = (float*)(ws + HB);                   // fp32 residual (ground)
  unsigned short* ab = (unsigned short*)(ws + 2 * HB); // [node][128] bf16 25.6MB
  // Build-phase overlays (dead once emb/conv run):
  unsigned* binned = (unsigned*)(ws);                            // 12.8 MB on h
  int*   cntT   = (int*)(ws + HB);                               // 1 MB on h0
  int*   offT   = (int*)(ws + HB + 0x100000);                    // 1 MB
  int*   bsumA  = (int*)(ws + HB + 0x300000);                    // 2 KB
  // Persistent:
  int*   deg4   = (int*)(ws + 3 * HB);                           // 1.6 MB
  int*   S      = (int*)(ws + 78400000);                         // 1.6 MB
  int*   slots  = (int*)(ws + 80000000);                         // 12.8 MB
  int*   bcnt   = (int*)(ws + 92800000);
  int*   boff   = (int*)(ws + 92800512);
  int*   bcur   = (int*)(ws + 92801024);
  int*   blist  = (int*)(ws + 92801536);                         // 1.6 MB
  float* pooled = (float*)(ws + 94401536);                       // 32 KB
  unsigned short* wbt = (unsigned short*)(ws + 94434304);        // 1.38 MB
  int*   tdesc  = (int*)(ws + 95810560);                         // 25.6 KB
  int*   ntiles = (int*)(ws + 95836160);                         // 16 B
  unsigned short* ewbt = (unsigned short*)(ws + 95836608);       // 4 KB

  const int* e0 = ei_edge, *e1 = ei_ns, *e2 = ei_sub, *e3 = ei_sn;
  const int MC = NBINS * NBINS;
  const int NB_MC = MC / 1024;              // 256

  // --- binned CSR build (12 total dispatches) ---
  p1_bincount<<<NBINS, 256, 0, stream>>>(e0, e1, e2, e3, cntT);
  scan1<<<NB_MC, 256, 0, stream>>>(cntT, offT, bsumA, MC);
  scan2<<<1, 512, 0, stream>>>(bsumA, NB_MC, bcnt);
  p3_binscatter<<<NBINS, 256, 0, stream>>>(e0, e1, e2, e3, offT, bsumA, binned);
  p46_kernel<<<NBINS, 256, 0, stream>>>(binned, offT, bsumA, deg4, S, slots, bcnt);
  bucket_scan<<<1, 128, 0, stream>>>(bcnt, boff, bcur, ntiles, tdesc);
  bucket_fill<<<dim3((N_NODES + 255) / 256, 4), 256, 0, stream>>>(deg4, bcur, blist);
  wconv_kernel<<<(84 * 64 * 128 + H * F_IN + 255) / 256, 256, 0, stream>>>(
      conv_wl, conv_wr, emb_w, wbt, ewbt);

  // --- network (self half ping-pongs 64 -> 0 -> 64 -> 0 -> h) ---
  emb_kernel<<<(N_NODES + 63) / 64, 256, 0, stream>>>(x, ewbt, emb_b, h0, ab, pooled);

  for (int j = 0; j < 4; ++j) {
    conv_kernel<<<MAX_TILES, 256, 0, stream>>>(
        h, ab, S + j * N_NODES, deg4 + j * N_NODES, slots,
        blist, tdesc, ntiles, wbt,
        conv_bl + (size_t)j * 21 * H, j,
        (j & 1) ? 0 : 64,          // inoff
        j < 3 ? 1 : 0, j == 3 ? 1 : 0);
  }

  ln_pool_kernel<<<POOL_BLOCKS, 1024, 0, stream>>>(h, h0, ln_g, ln_b, batch, pooled);
  out_kernel<<<NUM_GRAPHS, 64, 0, stream>>>(pooled, out_w, out_b, out);
}

// Round 15
// 393.451 us; speedup vs baseline: 2.1459x; 1.2190x over previous
//
#include <hip/hip_runtime.h>

#define N_NODES 100000
#define G_NODES 50000
#define N_EDGES 800000
#define H 64
#define F_IN 32
#define MAX_DEG 20
#define NUM_GRAPHS 128
#define LN_EPS 1e-5f
#define POOL_BLOCKS 256
#define MAX_TILES 1600

// Binned CSR build parameters: 512 bins over the 4*N key space.
#define NBINS 512
#define BPB 782            // keys per bin: 782*512 = 400384 >= 400000
#define CHUNK 6250         // edges per build block: 6250*512 = 3.2M
#define MKEYS (4 * N_NODES)
#define MEDGES (4 * N_EDGES)

typedef __attribute__((ext_vector_type(8))) short short8;
typedef __attribute__((ext_vector_type(4))) float float4v;

// bf16 helpers (RNE), no header dependency
static __device__ __forceinline__ unsigned short f2b(float f) {
  unsigned u = __float_as_uint(f);
  return (unsigned short)((u + 0x7fffu + ((u >> 16) & 1u)) >> 16);
}
static __device__ __forceinline__ float b2f(unsigned short b) {
  return __uint_as_float(((unsigned)b) << 16);
}

// ---------------- MFMA embedding + pooled zero-init -------------------------
// Writes initial self-half at ab[node][64:128] (conv0 reads inoff=64).
__global__ __launch_bounds__(256) void emb_kernel(
    const float* __restrict__ x, const unsigned short* __restrict__ ewbt,
    const float* __restrict__ eb, float* __restrict__ h0,
    unsigned short* __restrict__ ab, float* __restrict__ pooled) {
  int tid = threadIdx.x;
  if (blockIdx.x == 0) {
    for (int i = tid; i < NUM_GRAPHS * H; i += 256) pooled[i] = 0.f;
  }
  int base = blockIdx.x * 64;
  int nIn = min(64, N_NODES - base);
  int qw = tid >> 6, lane = tid & 63;
  __shared__ unsigned short aL[64 * 40];  // stride 40 breaks pow2 banks
  __shared__ float outF[64 * 68];

  {
    int node = tid >> 2, chb = (tid & 3) * 8;
    unsigned short v8[8];
    if (node < nIn) {
      const float* xr = x + ((size_t)(base + node)) * F_IN + chb;
      float4 f0 = *(const float4*)(xr);
      float4 f1 = *(const float4*)(xr + 4);
      v8[0] = f2b(f0.x); v8[1] = f2b(f0.y); v8[2] = f2b(f0.z); v8[3] = f2b(f0.w);
      v8[4] = f2b(f1.x); v8[5] = f2b(f1.y); v8[6] = f2b(f1.z); v8[7] = f2b(f1.w);
    } else {
#pragma unroll
      for (int i = 0; i < 8; ++i) v8[i] = 0;
    }
    *(short8*)&aL[(tid >> 2) * 40 + chb] = *(short8*)v8;
  }
  // no __syncthreads: wave qw staged exactly rows [qw*16, qw*16+16)

  int m = lane & 15, quad = lane >> 4;
  short8 a = *(const short8*)&aL[(qw * 16 + m) * 40 + quad * 8];
  float4v acc[4];
#pragma unroll
  for (int t = 0; t < 4; ++t) {
    float bv = eb[t * 16 + m];
    acc[t] = (float4v){bv, bv, bv, bv};
  }
#pragma unroll
  for (int t = 0; t < 4; ++t) {
    short8 bf = *(const short8*)&ewbt[(t * 16 + m) * F_IN + quad * 8];
    acc[t] = __builtin_amdgcn_mfma_f32_16x16x32_bf16(a, bf, acc[t], 0, 0, 0);
  }
#pragma unroll
  for (int t = 0; t < 4; ++t)
#pragma unroll
    for (int r = 0; r < 4; ++r)
      outF[(qw * 16 + quad * 4 + r) * 68 + t * 16 + m] = acc[t][r];
  for (int r = qw * 16; r < qw * 16 + 16; ++r) {
    if (r < nIn) {
      int node = base + r;
      float v = outF[r * 68 + lane];
      if (node < G_NODES) h0[node * H + lane] = v;
      ab[node * 128 + 64 + lane] = f2b(v);
    }
  }
}

// ---------------- weight preconvert (conv + emb in one grid) ----------------
__global__ __launch_bounds__(256) void wconv_kernel(
    const float* __restrict__ wl, const float* __restrict__ wr,
    const float* __restrict__ ew, unsigned short* __restrict__ wbt,
    unsigned short* __restrict__ ewbt) {
  int i = blockIdx.x * 256 + threadIdx.x;
  if (i < 84 * 64 * 128) {
    int k = i & 127;
    int ch = (i >> 7) & 63;
    int jb = i >> 13;
    float v = (k < 64) ? wl[jb * 4096 + k * 64 + ch]
                       : wr[jb * 4096 + (k - 64) * 64 + ch];
    wbt[i] = f2b(v);
  } else if (i < 84 * 64 * 128 + H * F_IN) {
    int ii = i - 84 * 64 * 128;
    int c = ii >> 5, f = ii & 31;
    ewbt[ii] = f2b(ew[f * H + c]);
  }
}

// ---------------- binned CSR build (no scattered global atomics) ------------
__global__ __launch_bounds__(256) void p1_bincount(
    const int* __restrict__ e0, const int* __restrict__ e1,
    const int* __restrict__ e2, const int* __restrict__ e3,
    int* __restrict__ cntT) {
  __shared__ int hist[NBINS];
  int t = threadIdx.x, b = blockIdx.x;
  for (int i = t; i < NBINS; i += 256) hist[i] = 0;
  __syncthreads();
  int j = b >> 7;
  const int* ei = (j == 0) ? e0 : (j == 1) ? e1 : (j == 2) ? e2 : e3;
  int ebase = (b & 127) * CHUNK;
  for (int i = t; i < CHUNK; i += 256) {
    int dst = ei[N_EDGES + ebase + i];
    int key = j * N_NODES + dst;
    atomicAdd(&hist[key / BPB], 1);
  }
  __syncthreads();
  for (int i = t; i < NBINS; i += 256) cntT[i * NBINS + b] = hist[i];
}

__global__ __launch_bounds__(256) void p3_binscatter(
    const int* __restrict__ e0, const int* __restrict__ e1,
    const int* __restrict__ e2, const int* __restrict__ e3,
    const int* __restrict__ offT, const int* __restrict__ bsumA,
    unsigned* __restrict__ binned) {
  __shared__ int cur[NBINS];
  int t = threadIdx.x, b = blockIdx.x;
  for (int i = t; i < NBINS; i += 256) {
    int idx = i * NBINS + b;
    cur[i] = offT[idx] + bsumA[idx >> 10];
  }
  __syncthreads();
  int j = b >> 7;
  const int* ei = (j == 0) ? e0 : (j == 1) ? e1 : (j == 2) ? e2 : e3;
  int ebase = (b & 127) * CHUNK;
  for (int i = t; i < CHUNK; i += 256) {
    int src = ei[ebase + i];
    int dst = ei[N_EDGES + ebase + i];
    int key = j * N_NODES + dst;
    int bin = key / BPB;
    int pos = atomicAdd(&cur[bin], 1);
    binned[pos] = ((unsigned)(key - bin * BPB) << 17) | (unsigned)src;
  }
}

// p46: per bin, fused deg4 + bucket-hist + local CSR scan + slot scatter.
__global__ __launch_bounds__(256) void p46_kernel(
    const unsigned* __restrict__ binned, const int* __restrict__ offT,
    const int* __restrict__ bsumA, int* __restrict__ deg4,
    int* __restrict__ S, int* __restrict__ slots, int* __restrict__ bcnt) {
  __shared__ int hist[BPB];
  __shared__ int cur[BPB];
  __shared__ int bh[84];
  __shared__ int wtot[4];
  int t = threadIdx.x, bin = blockIdx.x;
  int kb = bin * BPB;
  for (int i = t; i < BPB; i += 256) hist[i] = 0;
  if (t < 84) bh[t] = 0;
  __syncthreads();
  int i0 = bin * NBINS;
  int start = offT[i0] + bsumA[i0 >> 10];
  int end;
  if (bin == NBINS - 1) {
    end = MEDGES;
  } else {
    int i1 = (bin + 1) * NBINS;
    end = offT[i1] + bsumA[i1 >> 10];
  }
  for (int i = start + t; i < end; i += 256)
    atomicAdd(&hist[binned[i] >> 17], 1);
  __syncthreads();
  for (int i = t; i < BPB; i += 256) {
    int key = kb + i;
    if (key < MKEYS) {
      int d = hist[i];
      deg4[key] = d;
      int j = key / N_NODES;
      int b = d < MAX_DEG ? d : MAX_DEG;
      atomicAdd(&bh[j * 21 + b], 1);
    }
  }
  int base = t * 4;
  int v0 = 0, v1 = 0, v2 = 0, v3 = 0;
  if (base < BPB) {
    v0 = hist[base];
    v1 = (base + 1 < BPB) ? hist[base + 1] : 0;
    v2 = (base + 2 < BPB) ? hist[base + 2] : 0;
    v3 = (base + 3 < BPB) ? hist[base + 3] : 0;
  }
  int s = v0 + v1 + v2 + v3;
  int incl = s;
#pragma unroll
  for (int off = 1; off < 64; off <<= 1) {
    int y = __shfl_up(incl, off, 64);
    if ((t & 63) >= off) incl += y;
  }
  if ((t & 63) == 63) wtot[t >> 6] = incl;
  __syncthreads();
  int wbase = 0;
  for (int w = 0; w < (t >> 6); ++w) wbase += wtot[w];
  int ex = start + wbase + incl - s;
  if (base < BPB) {
    cur[base] = ex;
    if (base + 1 < BPB) cur[base + 1] = ex + v0;
    if (base + 2 < BPB) cur[base + 2] = ex + v0 + v1;
    if (base + 3 < BPB) cur[base + 3] = ex + v0 + v1 + v2;
  }
  __syncthreads();
  for (int i = t; i < BPB; i += 256)
    if (kb + i < MKEYS) S[kb + i] = cur[i];
  if (t < 84 && bh[t]) atomicAdd(&bcnt[t], bh[t]);
  __syncthreads();
  for (int i = start + t; i < end; i += 256) {
    unsigned v = binned[i];
    int pos = atomicAdd(&cur[v >> 17], 1);
    slots[pos] = (int)(v & 0x1ffffu);
  }
}

// ---------------- hierarchical exclusive scan (MC only) ---------------------
__global__ __launch_bounds__(256) void scan1(
    const int* __restrict__ in, int* __restrict__ S, int* __restrict__ bsum, int M) {
  int t = threadIdx.x;
  int base = blockIdx.x * 1024 + t * 4;
  int v0 = 0, v1 = 0, v2 = 0, v3 = 0;
  if (base + 3 < M) {
    int4 q = *(const int4*)(in + base);
    v0 = q.x; v1 = q.y; v2 = q.z; v3 = q.w;
  } else {
    if (base     < M) v0 = in[base];
    if (base + 1 < M) v1 = in[base + 1];
    if (base + 2 < M) v2 = in[base + 2];
    if (base + 3 < M) v3 = in[base + 3];
  }
  int s = v0 + v1 + v2 + v3;
  int incl = s;
#pragma unroll
  for (int off = 1; off < 64; off <<= 1) {
    int y = __shfl_up(incl, off, 64);
    if ((t & 63) >= off) incl += y;
  }
  __shared__ int wtot[4];
  if ((t & 63) == 63) wtot[t >> 6] = incl;
  __syncthreads();
  int wbase = 0;
  for (int w = 0; w < (t >> 6); ++w) wbase += wtot[w];
  int ex = wbase + incl - s;
  if (base < M) {
    int eo0 = ex, eo1 = ex + v0, eo2 = ex + v0 + v1, eo3 = ex + v0 + v1 + v2;
    if (base + 3 < M) {
      *(int4*)(S + base) = make_int4(eo0, eo1, eo2, eo3);
    } else {
      S[base] = eo0;
      if (base + 1 < M) S[base + 1] = eo1;
      if (base + 2 < M) S[base + 2] = eo2;
    }
  }
  if (t == 255) bsum[blockIdx.x] = wbase + incl;
}

__global__ __launch_bounds__(512) void scan2(
    int* __restrict__ bsum, int nb, int* __restrict__ bcnt) {
  int t = threadIdx.x;
  if (t < 84) bcnt[t] = 0;
  int v = (t < nb) ? bsum[t] : 0;
  int incl = v;
#pragma unroll
  for (int off = 1; off < 64; off <<= 1) {
    int y = __shfl_up(incl, off, 64);
    if ((t & 63) >= off) incl += y;
  }
  __shared__ int wtot[8];
  if ((t & 63) == 63) wtot[t >> 6] = incl;
  __syncthreads();
  int wbase = 0;
  for (int w = 0; w < (t >> 6); ++w) wbase += wtot[w];
  if (t < nb) bsum[t] = wbase + incl - v;
}

// ---------------- bucket scan + tile descriptors (one block) ----------------
__global__ __launch_bounds__(128) void bucket_scan(
    const int* __restrict__ bcnt, int* __restrict__ boff, int* __restrict__ bcur,
    int* __restrict__ ntiles, int* __restrict__ tdesc) {
  __shared__ int wt[2];
  __shared__ int exL[84], cntL[84], toffL[84];
  int t = threadIdx.x;
  int v = (t < 84) ? bcnt[t] : 0;
  int incl = v;
#pragma unroll
  for (int off = 1; off < 64; off <<= 1) {
    int y = __shfl_up(incl, off, 64);
    if ((t & 63) >= off) incl += y;
  }
  if ((t & 63) == 63) wt[t >> 6] = incl;
  __syncthreads();
  int wbase = (t >> 6) ? wt[0] : 0;
  if (t < 84) {
    int ex = wbase + incl - v;
    boff[t] = ex;
    bcur[t] = ex;
    exL[t] = ex;
    cntL[t] = v;
  }
  __syncthreads();
  if (t < 4) {
    int acc = 0;
    for (int bb = 0; bb < 21; ++bb) {
      toffL[t * 21 + bb] = acc;
      acc += (cntL[t * 21 + bb] + 63) >> 6;
    }
    ntiles[t] = acc;
  }
  __syncthreads();
  for (int jb = 0; jb < 84; ++jb) {
    int j = jb / 21, b = jb - j * 21;
    int cnt = cntL[jb], off = exL[jb], tb = toffL[jb];
    int nt = (cnt + 63) >> 6;
    for (int i = t; i < nt; i += 128) {
      int s2 = i << 6;
      int nIn = min(64, cnt - s2);
      tdesc[j * MAX_TILES + tb + i] = ((off + s2) << 12) | (b << 7) | nIn;
    }
  }
}

__global__ __launch_bounds__(256) void bucket_fill(
    const int* __restrict__ deg4, int* __restrict__ bcur, int* __restrict__ blist) {
  __shared__ int hist[21];
  __shared__ int base[21];
  int t = threadIdx.x;
  if (t < 21) hist[t] = 0;
  __syncthreads();
  int node = blockIdx.x * 256 + t;
  int j = blockIdx.y;
  int b = 0, lpos = 0;
  bool valid = (node < N_NODES);
  if (valid) {
    int d = deg4[j * N_NODES + node];
    b = d < MAX_DEG ? d : MAX_DEG;
    lpos = atomicAdd(&hist[b], 1);
  }
  __syncthreads();
  if (t < 21 && hist[t]) base[t] = atomicAdd(&bcur[j * 21 + t], hist[t]);
  __syncthreads();
  if (valid) blist[base[b] + lpos] = node;
}

// ---------------- FUSED conv: quad-per-row gather + MFMA, zero barriers -----
// R14: wave-per-row staging was latency-bound (16 serial rows, 8 shfl_xor
// each, 2 loads in flight). A full edge-row = 64ch x 2B = 128B = 16 lanes x
// uint2, so one QUARTER-wave owns a row: 4 rows concurrent per wave, 4-deep
// edge unroll -> ~16 loads in flight, zero cross-lane reductions.
// Half ping-pong: read ab[.][inoff:+64], write other half. Wave-local rows
// throughout -> no __syncthreads.
__global__ __launch_bounds__(256) void conv_kernel(
    float* __restrict__ h, unsigned short* __restrict__ ab,
    const int* __restrict__ S, const int* __restrict__ deg,
    const int* __restrict__ slots,
    const int* __restrict__ blist, const int* __restrict__ tdesc,
    const int* __restrict__ ntiles, const unsigned short* __restrict__ wbt,
    const float* __restrict__ bl, int j, int inoff, int do_relu, int last) {
  if ((int)blockIdx.x >= ntiles[j]) return;
  int d = tdesc[j * MAX_TILES + blockIdx.x];
  int nIn = d & 127;
  int b = (d >> 7) & 31;
  const int* lst = blist + (d >> 12);
  int outoff = 64 - inoff;

  int tid = threadIdx.x;
  int qw = tid >> 6, lane = tid & 63;

  if (b == 0) {
    // deg==0 masking: carry self (bf16-rounded); ReLU when j<3
    for (int r = qw * 16; r < qw * 16 + 16; ++r) {
      if (r < nIn) {
        int node = lst[r];
        float v = b2f(ab[node * 128 + inoff + lane]);
        if (do_relu) v = fmaxf(v, 0.f);
        if (last) {
          if (node < G_NODES) h[node * H + lane] = v;
        } else {
          ab[node * 128 + outoff + lane] = f2b(v);
        }
      }
    }
    return;
  }

  __shared__ unsigned short aL[64 * 136];  // 17408 B; reused as fp32[64*68]
  __shared__ int nodeS[64];
  int q = lane >> 4, cl = lane & 15;  // quad q, lane-in-quad cl -> ch 4*cl..+4

  // staging: quad q of wave qw owns rows qw*16 + q*4 + i (i=0..3)
  for (int i = 0; i < 4; ++i) {
    int r = qw * 16 + q * 4 + i;
    int node = (r < nIn) ? lst[r] : -1;
    if (cl == 0) nodeS[r] = node;
    uint2 selfv = make_uint2(0u, 0u);
    float s0a = 0.f, s1a = 0.f, s2a = 0.f, s3a = 0.f;
    float s0b = 0.f, s1b = 0.f, s2b = 0.f, s3b = 0.f;
    if (node >= 0) {
      selfv = *(const uint2*)&ab[node * 128 + inoff + 4 * cl];
      int off = S[node];
      int dg = (b < MAX_DEG) ? b : deg[node];
      int e = 0;
      for (; e + 3 < dg; e += 4) {
        int n0 = slots[off + e];
        int n1 = slots[off + e + 1];
        int n2 = slots[off + e + 2];
        int n3 = slots[off + e + 3];
        uint2 p0 = *(const uint2*)&ab[n0 * 128 + inoff + 4 * cl];
        uint2 p1 = *(const uint2*)&ab[n1 * 128 + inoff + 4 * cl];
        uint2 p2 = *(const uint2*)&ab[n2 * 128 + inoff + 4 * cl];
        uint2 p3 = *(const uint2*)&ab[n3 * 128 + inoff + 4 * cl];
        s0a += b2f((unsigned short)p0.x) + b2f((unsigned short)p1.x);
        s0b += b2f((unsigned short)p2.x) + b2f((unsigned short)p3.x);
        s1a += b2f((unsigned short)(p0.x >> 16)) + b2f((unsigned short)(p1.x >> 16));
        s1b += b2f((unsigned short)(p2.x >> 16)) + b2f((unsigned short)(p3.x >> 16));
        s2a += b2f((unsigned short)p0.y) + b2f((unsigned short)p1.y);
        s2b += b2f((unsigned short)p2.y) + b2f((unsigned short)p3.y);
        s3a += b2f((unsigned short)(p0.y >> 16)) + b2f((unsigned short)(p1.y >> 16));
        s3b += b2f((unsigned short)(p2.y >> 16)) + b2f((unsigned short)(p3.y >> 16));
      }
      for (; e < dg; ++e) {
        uint2 p0 = *(const uint2*)&ab[slots[off + e] * 128 + inoff + 4 * cl];
        s0a += b2f((unsigned short)p0.x);
        s1a += b2f((unsigned short)(p0.x >> 16));
        s2a += b2f((unsigned short)p0.y);
        s3a += b2f((unsigned short)(p0.y >> 16));
      }
    }
    uint2 o;
    o.x = (unsigned)f2b(s0a + s0b) | ((unsigned)f2b(s1a + s1b) << 16);
    o.y = (unsigned)f2b(s2a + s2b) | ((unsigned)f2b(s3a + s3b) << 16);
    *(uint2*)&aL[r * 136 + 4 * cl] = o;           // hsum -> k 0:64
    *(uint2*)&aL[r * 136 + 64 + 4 * cl] = selfv;  // self -> k 64:128
  }
  // no barrier: wave reads only its own rows below

  int m = lane & 15, quad = lane >> 4;
  const unsigned short* wbase = wbt + (size_t)(j * 21 + b) * 64 * 128;
  float4v acc[4];
#pragma unroll
  for (int t = 0; t < 4; ++t) {
    float bv = bl[b * 64 + t * 16 + m];
    acc[t] = (float4v){bv, bv, bv, bv};
  }
#pragma unroll
  for (int ks = 0; ks < 4; ++ks) {
    short8 a = *(const short8*)&aL[(qw * 16 + m) * 136 + ks * 32 + quad * 8];
#pragma unroll
    for (int t = 0; t < 4; ++t) {
      short8 bf = *(const short8*)&wbase[(t * 16 + m) * 128 + ks * 32 + quad * 8];
      acc[t] = __builtin_amdgcn_mfma_f32_16x16x32_bf16(a, bf, acc[t], 0, 0, 0);
    }
  }
  if (do_relu) {
#pragma unroll
    for (int t = 0; t < 4; ++t)
#pragma unroll
      for (int r = 0; r < 4; ++r) acc[t][r] = fmaxf(acc[t][r], 0.f);
  }
  // transpose via LDS reuse (wave-local byte rows: 136*2B == 68*4B == 272B)
  float* outF = (float*)aL;
#pragma unroll
  for (int t = 0; t < 4; ++t)
#pragma unroll
    for (int r = 0; r < 4; ++r)
      outF[(qw * 16 + quad * 4 + r) * 68 + t * 16 + m] = acc[t][r];
  if (last) {
    for (int r = qw * 16; r < qw * 16 + 16; ++r)
      if (r < nIn && nodeS[r] < G_NODES)
        h[nodeS[r] * H + lane] = outF[r * 68 + lane];
  } else {
    for (int r = qw * 16; r < qw * 16 + 16; ++r)
      if (r < nIn) ab[nodeS[r] * 128 + outoff + lane] = f2b(outF[r * 68 + lane]);
  }
}

// ---------------- fused layernorm + residual + ground-node pool -------------
__global__ __launch_bounds__(1024) void ln_pool_kernel(
    const float* __restrict__ h, const float* __restrict__ h0,
    const float* __restrict__ g, const float* __restrict__ b,
    const int* __restrict__ batch, float* __restrict__ pooled) {
  __shared__ float sm[NUM_GRAPHS * H];  // 32 KB
  int t = threadIdx.x;
  for (int i = t; i < NUM_GRAPHS * H; i += 1024) sm[i] = 0.f;
  __syncthreads();
  int lane = t & 63, w = t >> 6;  // 16 waves
  const int per = (G_NODES + POOL_BLOCKS - 1) / POOL_BLOCKS;
  int start = blockIdx.x * per;
  int end = min(start + per, G_NODES);
  for (int node = start + w; node < end; node += 16) {
    int idx = node * H + lane;
    float v = h[idx];
    float s = v;
#pragma unroll
    for (int off = 32; off > 0; off >>= 1) s += __shfl_xor(s, off, 64);
    float mu = s * (1.0f / H);
    float dv = v - mu;
    float q = dv * dv;
#pragma unroll
    for (int off = 32; off > 0; off >>= 1) q += __shfl_xor(q, off, 64);
    float inv = rsqrtf(q * (1.0f / H) + LN_EPS);
    float r = dv * inv * g[lane] + b[lane] + h0[idx];
    atomicAdd(&sm[batch[node] * H + lane], r);
  }
  __syncthreads();
  for (int i = t; i < NUM_GRAPHS * H; i += 1024) {
    float v = sm[i];
    if (v != 0.f) atomicAdd(&pooled[i], v);
  }
}

__global__ __launch_bounds__(64) void out_kernel(
    const float* __restrict__ pooled, const float* __restrict__ w,
    const float* __restrict__ b, float* __restrict__ out) {
  int gph = blockIdx.x;
  int c = threadIdx.x;
  float v = pooled[gph * H + c] * w[c];
#pragma unroll
  for (int off = 32; off > 0; off >>= 1) v += __shfl_xor(v, off, 64);
  if (c == 0) out[gph] = v + b[0];
}

extern "C" void kernel_launch(void* const* d_in, const int* in_sizes, int n_in,
                              void* d_out, int out_size, void* d_ws, size_t ws_size,
                              hipStream_t stream) {
  const float* x       = (const float*)d_in[0];
  const int*   ei_edge = (const int*)d_in[1];
  const int*   ei_sub  = (const int*)d_in[2];
  const int*   ei_ns   = (const int*)d_in[3];
  const int*   ei_sn   = (const int*)d_in[4];
  const int*   batch   = (const int*)d_in[7];
  const float* emb_w   = (const float*)d_in[8];
  const float* emb_b   = (const float*)d_in[9];
  const float* conv_wl = (const float*)d_in[10];
  const float* conv_bl = (const float*)d_in[11];
  const float* conv_wr = (const float*)d_in[12];
  const float* ln_g    = (const float*)d_in[13];
  const float* ln_b    = (const float*)d_in[14];
  const float* out_w   = (const float*)d_in[15];
  const float* out_b   = (const float*)d_in[16];
  float* out = (float*)d_out;

  const size_t HB = (size_t)N_NODES * H * sizeof(float);   // 25.6 MB
  char* ws = (char*)d_ws;
  float* h      = (float*)(ws);                        // fp32, ground, j==3
  float* h0     = (float*)(ws + HB);                   // fp32 residual (ground)
  unsigned short* ab = (unsigned short*)(ws + 2 * HB); // [node][128] bf16 25.6MB
  // Build-phase overlays (dead once emb/conv run):
  unsigned* binned = (unsigned*)(ws);                            // 12.8 MB on h
  int*   cntT   = (int*)(ws + HB);                               // 1 MB on h0
  int*   offT   = (int*)(ws + HB + 0x100000);                    // 1 MB
  int*   bsumA  = (int*)(ws + HB + 0x300000);                    // 2 KB
  // Persistent:
  int*   deg4   = (int*)(ws + 3 * HB);                           // 1.6 MB
  int*   S      = (int*)(ws + 78400000);                         // 1.6 MB
  int*   slots  = (int*)(ws + 80000000);                         // 12.8 MB
  int*   bcnt   = (int*)(ws + 92800000);
  int*   boff   = (int*)(ws + 92800512);
  int*   bcur   = (int*)(ws + 92801024);
  int*   blist  = (int*)(ws + 92801536);                         // 1.6 MB
  float* pooled = (float*)(ws + 94401536);                       // 32 KB
  unsigned short* wbt = (unsigned short*)(ws + 94434304);        // 1.38 MB
  int*   tdesc  = (int*)(ws + 95810560);                         // 25.6 KB
  int*   ntiles = (int*)(ws + 95836160);                         // 16 B
  unsigned short* ewbt = (unsigned short*)(ws + 95836608);       // 4 KB

  const int* e0 = ei_edge, *e1 = ei_ns, *e2 = ei_sub, *e3 = ei_sn;
  const int MC = NBINS * NBINS;
  const int NB_MC = MC / 1024;              // 256

  // --- binned CSR build (12 total dispatches) ---
  p1_bincount<<<NBINS, 256, 0, stream>>>(e0, e1, e2, e3, cntT);
  scan1<<<NB_MC, 256, 0, stream>>>(cntT, offT, bsumA, MC);
  scan2<<<1, 512, 0, stream>>>(bsumA, NB_MC, bcnt);
  p3_binscatter<<<NBINS, 256, 0, stream>>>(e0, e1, e2, e3, offT, bsumA, binned);
  p46_kernel<<<NBINS, 256, 0, stream>>>(binned, offT, bsumA, deg4, S, slots, bcnt);
  bucket_scan<<<1, 128, 0, stream>>>(bcnt, boff, bcur, ntiles, tdesc);
  bucket_fill<<<dim3((N_NODES + 255) / 256, 4), 256, 0, stream>>>(deg4, bcur, blist);
  wconv_kernel<<<(84 * 64 * 128 + H * F_IN + 255) / 256, 256, 0, stream>>>(
      conv_wl, conv_wr, emb_w, wbt, ewbt);

  // --- network (self half ping-pongs 64 -> 0 -> 64 -> 0 -> h) ---
  emb_kernel<<<(N_NODES + 63) / 64, 256, 0, stream>>>(x, ewbt, emb_b, h0, ab, pooled);

  for (int j = 0; j < 4; ++j) {
    conv_kernel<<<MAX_TILES, 256, 0, stream>>>(
        h, ab, S + j * N_NODES, deg4 + j * N_NODES, slots,
        blist, tdesc, ntiles, wbt,
        conv_bl + (size_t)j * 21 * H, j,
        (j & 1) ? 0 : 64,          // inoff
        j < 3 ? 1 : 0, j == 3 ? 1 : 0);
  }

  ln_pool_kernel<<<POOL_BLOCKS, 1024, 0, stream>>>(h, h0, ln_g, ln_b, batch, pooled);
  out_kernel<<<NUM_GRAPHS, 64, 0, stream>>>(pooled, out_w, out_b, out);
}

// Round 16
// 382.287 us; speedup vs baseline: 2.2086x; 1.0292x over previous
//
#include <hip/hip_runtime.h>

#define N_NODES 100000
#define G_NODES 50000
#define N_EDGES 800000
#define H 64
#define F_IN 32
#define MAX_DEG 20
#define NUM_GRAPHS 128
#define LN_EPS 1e-5f
#define POOL_BLOCKS 256
#define MAX_TILES 1600

// Binned CSR build: 512 bins over the 4*N key space, FIXED 8192-entry
// capacity per bin (mean 6250, sigma~79 -> +24 sigma, unreachable).
#define NBINS 512
#define BPB 782            // keys per bin: 782*512 = 400384 >= 400000
#define BINCAP_LOG 13      // 8192 entries per bin
#define CHUNK 6250         // edges per build block: 6250*512 = 3.2M
#define MKEYS (4 * N_NODES)
#define MEDGES (4 * N_EDGES)

typedef __attribute__((ext_vector_type(8))) short short8;
typedef __attribute__((ext_vector_type(4))) float float4v;

// bf16 helpers (RNE), no header dependency
static __device__ __forceinline__ unsigned short f2b(float f) {
  unsigned u = __float_as_uint(f);
  return (unsigned short)((u + 0x7fffu + ((u >> 16) & 1u)) >> 16);
}
static __device__ __forceinline__ float b2f(unsigned short b) {
  return __uint_as_float(((unsigned)b) << 16);
}

// ---------------- weight preconvert + cursor/bcnt init (runs FIRST) ---------
__global__ __launch_bounds__(256) void wconv_kernel(
    const float* __restrict__ wl, const float* __restrict__ wr,
    const float* __restrict__ ew, unsigned short* __restrict__ wbt,
    unsigned short* __restrict__ ewbt, int* __restrict__ bincur,
    int* __restrict__ bcnt) {
  int i = blockIdx.x * 256 + threadIdx.x;
  if (blockIdx.x == 0) {
    for (int k = threadIdx.x; k < NBINS; k += 256) bincur[k] = k << BINCAP_LOG;
    if (threadIdx.x < 84) bcnt[threadIdx.x] = 0;
  }
  if (i < 84 * 64 * 128) {
    int k = i & 127;
    int ch = (i >> 7) & 63;
    int jb = i >> 13;
    float v = (k < 64) ? wl[jb * 4096 + k * 64 + ch]
                       : wr[jb * 4096 + (k - 64) * 64 + ch];
    wbt[i] = f2b(v);
  } else if (i < 84 * 64 * 128 + H * F_IN) {
    int ii = i - 84 * 64 * 128;
    int c = ii >> 5, f = ii & 31;
    ewbt[ii] = f2b(ew[f * H + c]);
  }
}

// ---------------- MFMA embedding + pooled zero-init -------------------------
// Writes initial self-half at ab[node][64:128] (conv0 reads inoff=64).
__global__ __launch_bounds__(256) void emb_kernel(
    const float* __restrict__ x, const unsigned short* __restrict__ ewbt,
    const float* __restrict__ eb, float* __restrict__ h0,
    unsigned short* __restrict__ ab, float* __restrict__ pooled) {
  int tid = threadIdx.x;
  if (blockIdx.x == 0) {
    for (int i = tid; i < NUM_GRAPHS * H; i += 256) pooled[i] = 0.f;
  }
  int base = blockIdx.x * 64;
  int nIn = min(64, N_NODES - base);
  int qw = tid >> 6, lane = tid & 63;
  __shared__ unsigned short aL[64 * 40];  // stride 40 breaks pow2 banks
  __shared__ float outF[64 * 68];

  {
    int node = tid >> 2, chb = (tid & 3) * 8;
    unsigned short v8[8];
    if (node < nIn) {
      const float* xr = x + ((size_t)(base + node)) * F_IN + chb;
      float4 f0 = *(const float4*)(xr);
      float4 f1 = *(const float4*)(xr + 4);
      v8[0] = f2b(f0.x); v8[1] = f2b(f0.y); v8[2] = f2b(f0.z); v8[3] = f2b(f0.w);
      v8[4] = f2b(f1.x); v8[5] = f2b(f1.y); v8[6] = f2b(f1.z); v8[7] = f2b(f1.w);
    } else {
#pragma unroll
      for (int i = 0; i < 8; ++i) v8[i] = 0;
    }
    *(short8*)&aL[(tid >> 2) * 40 + chb] = *(short8*)v8;
  }
  // no __syncthreads: wave qw staged exactly rows [qw*16, qw*16+16)

  int m = lane & 15, quad = lane >> 4;
  short8 a = *(const short8*)&aL[(qw * 16 + m) * 40 + quad * 8];
  float4v acc[4];
#pragma unroll
  for (int t = 0; t < 4; ++t) {
    float bv = eb[t * 16 + m];
    acc[t] = (float4v){bv, bv, bv, bv};
  }
#pragma unroll
  for (int t = 0; t < 4; ++t) {
    short8 bf = *(const short8*)&ewbt[(t * 16 + m) * F_IN + quad * 8];
    acc[t] = __builtin_amdgcn_mfma_f32_16x16x32_bf16(a, bf, acc[t], 0, 0, 0);
  }
#pragma unroll
  for (int t = 0; t < 4; ++t)
#pragma unroll
    for (int r = 0; r < 4; ++r)
      outF[(qw * 16 + quad * 4 + r) * 68 + t * 16 + m] = acc[t][r];
  for (int r = qw * 16; r < qw * 16 + 16; ++r) {
    if (r < nIn) {
      int node = base + r;
      float v = outF[r * 68 + lane];
      if (node < G_NODES) h0[node * H + lane] = v;
      ab[node * 128 + 64 + lane] = f2b(v);
    }
  }
}

// ---------------- single-pass binning (replaces p1 + scan1 + scan2 + p3) ----
// Per block: LDS histogram of its 6250-edge chunk, ONE global atomic per
// touched bin to reserve a range in the bin's fixed-capacity region, then
// scatter. Removes the global 262k scan chain (R15: 3 dispatches + ~28us).
__global__ __launch_bounds__(256) void p3_binscatter(
    const int* __restrict__ e0, const int* __restrict__ e1,
    const int* __restrict__ e2, const int* __restrict__ e3,
    int* __restrict__ bincur, unsigned* __restrict__ binned) {
  __shared__ int hist[NBINS];
  __shared__ int cur[NBINS];
  int t = threadIdx.x, b = blockIdx.x;
  for (int i = t; i < NBINS; i += 256) hist[i] = 0;
  __syncthreads();
  int j = b >> 7;
  const int* ei = (j == 0) ? e0 : (j == 1) ? e1 : (j == 2) ? e2 : e3;
  int ebase = (b & 127) * CHUNK;
  for (int i = t; i < CHUNK; i += 256) {
    int dst = ei[N_EDGES + ebase + i];
    atomicAdd(&hist[(j * N_NODES + dst) / BPB], 1);
  }
  __syncthreads();
  for (int i = t; i < NBINS; i += 256) {
    int c = hist[i];
    cur[i] = c ? atomicAdd(&bincur[i], c) : 0;
  }
  __syncthreads();
  for (int i = t; i < CHUNK; i += 256) {
    int src = ei[ebase + i];
    int dst = ei[N_EDGES + ebase + i];
    int key = j * N_NODES + dst;
    int bin = key / BPB;
    int pos = atomicAdd(&cur[bin], 1);
    binned[pos] = ((unsigned)(key - bin * BPB) << 17) | (unsigned)src;
  }
}

// p46: per bin, fused deg4 + bucket-hist + local CSR scan + slot scatter.
// start = bin's fixed region base; end = bincur[bin] (cursor after p3).
// S/slots live in the same fixed-capacity layout.
__global__ __launch_bounds__(256) void p46_kernel(
    const unsigned* __restrict__ binned, const int* __restrict__ bincur,
    int* __restrict__ deg4, int* __restrict__ S, int* __restrict__ slots,
    int* __restrict__ bcnt) {
  __shared__ int hist[BPB];
  __shared__ int cur[BPB];
  __shared__ int bh[84];
  __shared__ int wtot[4];
  int t = threadIdx.x, bin = blockIdx.x;
  int kb = bin * BPB;
  for (int i = t; i < BPB; i += 256) hist[i] = 0;
  if (t < 84) bh[t] = 0;
  __syncthreads();
  int start = bin << BINCAP_LOG;
  int end = bincur[bin];
  for (int i = start + t; i < end; i += 256)
    atomicAdd(&hist[binned[i] >> 17], 1);
  __syncthreads();
  for (int i = t; i < BPB; i += 256) {
    int key = kb + i;
    if (key < MKEYS) {
      int d = hist[i];
      deg4[key] = d;
      int j = key / N_NODES;
      int b = d < MAX_DEG ? d : MAX_DEG;
      atomicAdd(&bh[j * 21 + b], 1);
    }
  }
  int base = t * 4;
  int v0 = 0, v1 = 0, v2 = 0, v3 = 0;
  if (base < BPB) {
    v0 = hist[base];
    v1 = (base + 1 < BPB) ? hist[base + 1] : 0;
    v2 = (base + 2 < BPB) ? hist[base + 2] : 0;
    v3 = (base + 3 < BPB) ? hist[base + 3] : 0;
  }
  int s = v0 + v1 + v2 + v3;
  int incl = s;
#pragma unroll
  for (int off = 1; off < 64; off <<= 1) {
    int y = __shfl_up(incl, off, 64);
    if ((t & 63) >= off) incl += y;
  }
  if ((t & 63) == 63) wtot[t >> 6] = incl;
  __syncthreads();
  int wbase = 0;
  for (int w = 0; w < (t >> 6); ++w) wbase += wtot[w];
  int ex = start + wbase + incl - s;
  if (base < BPB) {
    cur[base] = ex;
    if (base + 1 < BPB) cur[base + 1] = ex + v0;
    if (base + 2 < BPB) cur[base + 2] = ex + v0 + v1;
    if (base + 3 < BPB) cur[base + 3] = ex + v0 + v1 + v2;
  }
  __syncthreads();
  for (int i = t; i < BPB; i += 256)
    if (kb + i < MKEYS) S[kb + i] = cur[i];
  if (t < 84 && bh[t]) atomicAdd(&bcnt[t], bh[t]);
  __syncthreads();
  for (int i = start + t; i < end; i += 256) {
    unsigned v = binned[i];
    int pos = atomicAdd(&cur[v >> 17], 1);
    slots[pos] = (int)(v & 0x1ffffu);
  }
}

// ---------------- bucket scan + tile descriptors (one block) ----------------
__global__ __launch_bounds__(128) void bucket_scan(
    const int* __restrict__ bcnt, int* __restrict__ boff, int* __restrict__ bcur,
    int* __restrict__ ntiles, int* __restrict__ tdesc) {
  __shared__ int wt[2];
  __shared__ int exL[84], cntL[84], toffL[84];
  int t = threadIdx.x;
  int v = (t < 84) ? bcnt[t] : 0;
  int incl = v;
#pragma unroll
  for (int off = 1; off < 64; off <<= 1) {
    int y = __shfl_up(incl, off, 64);
    if ((t & 63) >= off) incl += y;
  }
  if ((t & 63) == 63) wt[t >> 6] = incl;
  __syncthreads();
  int wbase = (t >> 6) ? wt[0] : 0;
  if (t < 84) {
    int ex = wbase + incl - v;
    boff[t] = ex;
    bcur[t] = ex;
    exL[t] = ex;
    cntL[t] = v;
  }
  __syncthreads();
  if (t < 4) {
    int acc = 0;
    for (int bb = 0; bb < 21; ++bb) {
      toffL[t * 21 + bb] = acc;
      acc += (cntL[t * 21 + bb] + 63) >> 6;
    }
    ntiles[t] = acc;
  }
  __syncthreads();
  for (int jb = 0; jb < 84; ++jb) {
    int j = jb / 21, b = jb - j * 21;
    int cnt = cntL[jb], off = exL[jb], tb = toffL[jb];
    int nt = (cnt + 63) >> 6;
    for (int i = t; i < nt; i += 128) {
      int s2 = i << 6;
      int nIn = min(64, cnt - s2);
      tdesc[j * MAX_TILES + tb + i] = ((off + s2) << 12) | (b << 7) | nIn;
    }
  }
}

__global__ __launch_bounds__(256) void bucket_fill(
    const int* __restrict__ deg4, int* __restrict__ bcur, int* __restrict__ blist) {
  __shared__ int hist[21];
  __shared__ int base[21];
  int t = threadIdx.x;
  if (t < 21) hist[t] = 0;
  __syncthreads();
  int node = blockIdx.x * 256 + t;
  int j = blockIdx.y;
  int b = 0, lpos = 0;
  bool valid = (node < N_NODES);
  if (valid) {
    int d = deg4[j * N_NODES + node];
    b = d < MAX_DEG ? d : MAX_DEG;
    lpos = atomicAdd(&hist[b], 1);
  }
  __syncthreads();
  if (t < 21 && hist[t]) base[t] = atomicAdd(&bcur[j * 21 + t], hist[t]);
  __syncthreads();
  if (valid) blist[base[b] + lpos] = node;
}

// ---------------- FUSED conv: quad-per-row gather + MFMA, zero barriers -----
// Quarter-wave per row: 4 rows concurrent per wave, 4-deep edge unroll,
// zero cross-lane reductions. Half ping-pong: read ab[.][inoff:+64], write
// other half. Wave-local rows throughout -> no __syncthreads.
__global__ __launch_bounds__(256) void conv_kernel(
    float* __restrict__ h, unsigned short* __restrict__ ab,
    const int* __restrict__ S, const int* __restrict__ deg,
    const int* __restrict__ slots,
    const int* __restrict__ blist, const int* __restrict__ tdesc,
    const int* __restrict__ ntiles, const unsigned short* __restrict__ wbt,
    const float* __restrict__ bl, int j, int inoff, int do_relu, int last) {
  if ((int)blockIdx.x >= ntiles[j]) return;
  int d = tdesc[j * MAX_TILES + blockIdx.x];
  int nIn = d & 127;
  int b = (d >> 7) & 31;
  const int* lst = blist + (d >> 12);
  int outoff = 64 - inoff;

  int tid = threadIdx.x;
  int qw = tid >> 6, lane = tid & 63;

  if (b == 0) {
    for (int r = qw * 16; r < qw * 16 + 16; ++r) {
      if (r < nIn) {
        int node = lst[r];
        float v = b2f(ab[node * 128 + inoff + lane]);
        if (do_relu) v = fmaxf(v, 0.f);
        if (last) {
          if (node < G_NODES) h[node * H + lane] = v;
        } else {
          ab[node * 128 + outoff + lane] = f2b(v);
        }
      }
    }
    return;
  }

  __shared__ unsigned short aL[64 * 136];  // 17408 B; reused as fp32[64*68]
  __shared__ int nodeS[64];
  int q = lane >> 4, cl = lane & 15;

  for (int i = 0; i < 4; ++i) {
    int r = qw * 16 + q * 4 + i;
    int node = (r < nIn) ? lst[r] : -1;
    if (cl == 0) nodeS[r] = node;
    uint2 selfv = make_uint2(0u, 0u);
    float s0a = 0.f, s1a = 0.f, s2a = 0.f, s3a = 0.f;
    float s0b = 0.f, s1b = 0.f, s2b = 0.f, s3b = 0.f;
    if (node >= 0) {
      selfv = *(const uint2*)&ab[node * 128 + inoff + 4 * cl];
      int off = S[node];
      int dg = (b < MAX_DEG) ? b : deg[node];
      int e = 0;
      for (; e + 3 < dg; e += 4) {
        int n0 = slots[off + e];
        int n1 = slots[off + e + 1];
        int n2 = slots[off + e + 2];
        int n3 = slots[off + e + 3];
        uint2 p0 = *(const uint2*)&ab[n0 * 128 + inoff + 4 * cl];
        uint2 p1 = *(const uint2*)&ab[n1 * 128 + inoff + 4 * cl];
        uint2 p2 = *(const uint2*)&ab[n2 * 128 + inoff + 4 * cl];
        uint2 p3 = *(const uint2*)&ab[n3 * 128 + inoff + 4 * cl];
        s0a += b2f((unsigned short)p0.x) + b2f((unsigned short)p1.x);
        s0b += b2f((unsigned short)p2.x) + b2f((unsigned short)p3.x);
        s1a += b2f((unsigned short)(p0.x >> 16)) + b2f((unsigned short)(p1.x >> 16));
        s1b += b2f((unsigned short)(p2.x >> 16)) + b2f((unsigned short)(p3.x >> 16));
        s2a += b2f((unsigned short)p0.y) + b2f((unsigned short)p1.y);
        s2b += b2f((unsigned short)p2.y) + b2f((unsigned short)p3.y);
        s3a += b2f((unsigned short)(p0.y >> 16)) + b2f((unsigned short)(p1.y >> 16));
        s3b += b2f((unsigned short)(p2.y >> 16)) + b2f((unsigned short)(p3.y >> 16));
      }
      for (; e < dg; ++e) {
        uint2 p0 = *(const uint2*)&ab[slots[off + e] * 128 + inoff + 4 * cl];
        s0a += b2f((unsigned short)p0.x);
        s1a += b2f((unsigned short)(p0.x >> 16));
        s2a += b2f((unsigned short)p0.y);
        s3a += b2f((unsigned short)(p0.y >> 16));
      }
    }
    uint2 o;
    o.x = (unsigned)f2b(s0a + s0b) | ((unsigned)f2b(s1a + s1b) << 16);
    o.y = (unsigned)f2b(s2a + s2b) | ((unsigned)f2b(s3a + s3b) << 16);
    *(uint2*)&aL[r * 136 + 4 * cl] = o;           // hsum -> k 0:64
    *(uint2*)&aL[r * 136 + 64 + 4 * cl] = selfv;  // self -> k 64:128
  }
  // no barrier: wave reads only its own rows below

  int m = lane & 15, quad = lane >> 4;
  const unsigned short* wbase = wbt + (size_t)(j * 21 + b) * 64 * 128;
  float4v acc[4];
#pragma unroll
  for (int t = 0; t < 4; ++t) {
    float bv = bl[b * 64 + t * 16 + m];
    acc[t] = (float4v){bv, bv, bv, bv};
  }
#pragma unroll
  for (int ks = 0; ks < 4; ++ks) {
    short8 a = *(const short8*)&aL[(qw * 16 + m) * 136 + ks * 32 + quad * 8];
#pragma unroll
    for (int t = 0; t < 4; ++t) {
      short8 bf = *(const short8*)&wbase[(t * 16 + m) * 128 + ks * 32 + quad * 8];
      acc[t] = __builtin_amdgcn_mfma_f32_16x16x32_bf16(a, bf, acc[t], 0, 0, 0);
    }
  }
  if (do_relu) {
#pragma unroll
    for (int t = 0; t < 4; ++t)
#pragma unroll
      for (int r = 0; r < 4; ++r) acc[t][r] = fmaxf(acc[t][r], 0.f);
  }
  float* outF = (float*)aL;
#pragma unroll
  for (int t = 0; t < 4; ++t)
#pragma unroll
    for (int r = 0; r < 4; ++r)
      outF[(qw * 16 + quad * 4 + r) * 68 + t * 16 + m] = acc[t][r];
  if (last) {
    for (int r = qw * 16; r < qw * 16 + 16; ++r)
      if (r < nIn && nodeS[r] < G_NODES)
        h[nodeS[r] * H + lane] = outF[r * 68 + lane];
  } else {
    for (int r = qw * 16; r < qw * 16 + 16; ++r)
      if (r < nIn) ab[nodeS[r] * 128 + outoff + lane] = f2b(outF[r * 68 + lane]);
  }
}

// ---------------- fused layernorm + residual + ground-node pool -------------
__global__ __launch_bounds__(1024) void ln_pool_kernel(
    const float* __restrict__ h, const float* __restrict__ h0,
    const float* __restrict__ g, const float* __restrict__ b,
    const int* __restrict__ batch, float* __restrict__ pooled) {
  __shared__ float sm[NUM_GRAPHS * H];  // 32 KB
  int t = threadIdx.x;
  for (int i = t; i < NUM_GRAPHS * H; i += 1024) sm[i] = 0.f;
  __syncthreads();
  int lane = t & 63, w = t >> 6;  // 16 waves
  const int per = (G_NODES + POOL_BLOCKS - 1) / POOL_BLOCKS;
  int start = blockIdx.x * per;
  int end = min(start + per, G_NODES);
  for (int node = start + w; node < end; node += 16) {
    int idx = node * H + lane;
    float v = h[idx];
    float s = v;
#pragma unroll
    for (int off = 32; off > 0; off >>= 1) s += __shfl_xor(s, off, 64);
    float mu = s * (1.0f / H);
    float dv = v - mu;
    float q = dv * dv;
#pragma unroll
    for (int off = 32; off > 0; off >>= 1) q += __shfl_xor(q, off, 64);
    float inv = rsqrtf(q * (1.0f / H) + LN_EPS);
    float r = dv * inv * g[lane] + b[lane] + h0[idx];
    atomicAdd(&sm[batch[node] * H + lane], r);
  }
  __syncthreads();
  for (int i = t; i < NUM_GRAPHS * H; i += 1024) {
    float v = sm[i];
    if (v != 0.f) atomicAdd(&pooled[i], v);
  }
}

__global__ __launch_bounds__(64) void out_kernel(
    const float* __restrict__ pooled, const float* __restrict__ w,
    const float* __restrict__ b, float* __restrict__ out) {
  int gph = blockIdx.x;
  int c = threadIdx.x;
  float v = pooled[gph * H + c] * w[c];
#pragma unroll
  for (int off = 32; off > 0; off >>= 1) v += __shfl_xor(v, off, 64);
  if (c == 0) out[gph] = v + b[0];
}

extern "C" void kernel_launch(void* const* d_in, const int* in_sizes, int n_in,
                              void* d_out, int out_size, void* d_ws, size_t ws_size,
                              hipStream_t stream) {
  const float* x       = (const float*)d_in[0];
  const int*   ei_edge = (const int*)d_in[1];
  const int*   ei_sub  = (const int*)d_in[2];
  const int*   ei_ns   = (const int*)d_in[3];
  const int*   ei_sn   = (const int*)d_in[4];
  const int*   batch   = (const int*)d_in[7];
  const float* emb_w   = (const float*)d_in[8];
  const float* emb_b   = (const float*)d_in[9];
  const float* conv_wl = (const float*)d_in[10];
  const float* conv_bl = (const float*)d_in[11];
  const float* conv_wr = (const float*)d_in[12];
  const float* ln_g    = (const float*)d_in[13];
  const float* ln_b    = (const float*)d_in[14];
  const float* out_w   = (const float*)d_in[15];
  const float* out_b   = (const float*)d_in[16];
  float* out = (float*)d_out;

  const size_t HB = (size_t)N_NODES * H * sizeof(float);   // 25.6 MB
  char* ws = (char*)d_ws;
  float* h      = (float*)(ws);                        // fp32, ground, j==3
  float* h0     = (float*)(ws + HB);                   // fp32 residual (ground)
  unsigned short* ab = (unsigned short*)(ws + 2 * HB); // [node][128] bf16 25.6MB
  // Persistent build outputs:
  int*   deg4   = (int*)(ws + 3 * HB);                           // 1.6 MB
  int*   S      = (int*)(ws + 78400000);                         // 1.6 MB
  int*   bcnt   = (int*)(ws + 92800000);
  int*   boff   = (int*)(ws + 92800512);
  int*   bcur   = (int*)(ws + 92801024);
  int*   blist  = (int*)(ws + 92801536);                         // 1.6 MB
  float* pooled = (float*)(ws + 94401536);                       // 32 KB
  unsigned short* wbt = (unsigned short*)(ws + 94434304);        // 1.38 MB
  int*   tdesc  = (int*)(ws + 95810560);                         // 25.6 KB
  int*   ntiles = (int*)(ws + 95836160);                         // 16 B
  unsigned short* ewbt = (unsigned short*)(ws + 95836608);       // 4 KB
  int*   bincur = (int*)(ws + 95841024);                         // 2 KB
  // Fixed-capacity bin regions (ws_size ~= 256 MiB, plenty of headroom):
  unsigned* binned = (unsigned*)(ws + 100000000);                // 16.8 MB
  int*   slots  = (int*)(ws + 117000000);                        // 16.8 MB

  const int* e0 = ei_edge, *e1 = ei_ns, *e2 = ei_sub, *e3 = ei_sn;

  // --- build (12 total dispatches; p1/scan1/scan2 eliminated) ---
  wconv_kernel<<<(84 * 64 * 128 + H * F_IN + 255) / 256, 256, 0, stream>>>(
      conv_wl, conv_wr, emb_w, wbt, ewbt, bincur, bcnt);
  p3_binscatter<<<NBINS, 256, 0, stream>>>(e0, e1, e2, e3, bincur, binned);
  p46_kernel<<<NBINS, 256, 0, stream>>>(binned, bincur, deg4, S, slots, bcnt);
  bucket_scan<<<1, 128, 0, stream>>>(bcnt, boff, bcur, ntiles, tdesc);
  bucket_fill<<<dim3((N_NODES + 255) / 256, 4), 256, 0, stream>>>(deg4, bcur, blist);

  // --- network (self half ping-pongs 64 -> 0 -> 64 -> 0 -> h) ---
  emb_kernel<<<(N_NODES + 63) / 64, 256, 0, stream>>>(x, ewbt, emb_b, h0, ab, pooled);

  for (int j = 0; j < 4; ++j) {
    conv_kernel<<<MAX_TILES, 256, 0, stream>>>(
        h, ab, S + j * N_NODES, deg4 + j * N_NODES, slots,
        blist, tdesc, ntiles, wbt,
        conv_bl + (size_t)j * 21 * H, j,
        (j & 1) ? 0 : 64,          // inoff
        j < 3 ? 1 : 0, j == 3 ? 1 : 0);
  }

  ln_pool_kernel<<<POOL_BLOCKS, 1024, 0, stream>>>(h, h0, ln_g, ln_b, batch, pooled);
  out_kernel<<<NUM_GRAPHS, 64, 0, stream>>>(pooled, out_w, out_b, out);
}